// Round 1
// baseline (13615.689 us; speedup 1.0000x reference)
//
#include <hip/hip_runtime.h>
#include <hip/hip_bf16.h>
#include <math.h>

#define VOCAB 1500
#define NE    208
#define TT    256
#define NHD   4
#define HD    52
#define NL    8
#define BBATCH 256
#define NTOK  (BBATCH * TT)   // 65536

// ---------------- embedding: x = tok_emb[idx] + pos_emb ----------------
__global__ __launch_bounds__(256) void k_embed(const int* __restrict__ idx,
                                               const float* __restrict__ tok,
                                               const float* __restrict__ pos,
                                               float* __restrict__ x) {
  int i = blockIdx.x * 256 + threadIdx.x;          // over NTOK*NE, exact grid
  int n = i / NE, c = i - n * NE;
  int t = n & (TT - 1);
  x[i] = tok[idx[n] * NE + c] + pos[t * NE + c];
}

// ---------------- pack Wq/Wk/Wv -> [NL][NE][624] (cols: q|k|v, each h*52+d) --
__global__ __launch_bounds__(256) void k_pack_qkv(const float* __restrict__ Wq,
                                                  const float* __restrict__ Wk,
                                                  const float* __restrict__ Wv,
                                                  float* __restrict__ Bq) {
  int i = blockIdx.x * 256 + threadIdx.x;          // over NL*NE*624, exact grid
  int j = i % 624;
  int lc = i / 624;                                 // l*NE + c
  int c = lc % NE, l = lc / NE;
  int sel = j / NE;                                 // 0=q 1=k 2=v
  int hd = j - sel * NE;
  int h = hd / HD, d = hd - h * HD;
  const float* W = (sel == 0) ? Wq : (sel == 1) ? Wk : Wv;
  Bq[i] = W[(((size_t)l * NHD + h) * NE + c) * HD + d];
}

// ---------------- layernorm: one wave per row ----------------
__global__ __launch_bounds__(256) void k_ln(const float* __restrict__ x,
                                            const float* __restrict__ g,
                                            const float* __restrict__ b,
                                            float* __restrict__ h) {
  int r = blockIdx.x * 4 + (threadIdx.x >> 6);
  int lane = threadIdx.x & 63;
  const float* row = x + (size_t)r * NE;
  float v[4];
  int cnt = 0;
  float s = 0.f;
  for (int c = lane; c < NE; c += 64) { v[cnt] = row[c]; s += v[cnt]; cnt++; }
  #pragma unroll
  for (int o = 32; o; o >>= 1) s += __shfl_xor(s, o);
  float mu = s * (1.f / NE);
  float q = 0.f;
  for (int i = 0; i < cnt; i++) { float d = v[i] - mu; q += d * d; }
  #pragma unroll
  for (int o = 32; o; o >>= 1) q += __shfl_xor(q, o);
  float inv = rsqrtf(q * (1.f / NE) + 1e-5f);
  float* out = h + (size_t)r * NE;
  int c = lane;
  for (int i = 0; i < cnt; i++, c += 64) out[c] = (v[i] - mu) * inv * g[c] + b[c];
}

// ---------------- generic f32 GEMM: C = [resid +] A@B [+bias] [relu] --------
// BM=128 BN=64 BK=16, 256 threads, 8x4 micro-tile. K % 16 == 0, M % 128 == 0.
template <bool RELU, bool RESID, bool BIAS>
__global__ __launch_bounds__(256) void k_gemm(const float* __restrict__ A,
                                              const float* __restrict__ B,
                                              const float* __restrict__ bias,
                                              const float* __restrict__ resid,
                                              float* __restrict__ C,
                                              int M, int N, int K) {
  __shared__ float As[16][132];   // [k][m], padded
  __shared__ float Bs[16][68];    // [k][n], padded
  const int bm = blockIdx.y * 128, bn = blockIdx.x * 64;
  const int tid = threadIdx.x;
  const int tr = tid >> 4, tc = tid & 15;
  const int am = tid >> 1, ak = (tid & 1) * 8;
  const int bk = tid >> 6, bc = tid & 63;
  float acc[8][4] = {};
  for (int k0 = 0; k0 < K; k0 += 16) {
    const float* ap = A + (size_t)(bm + am) * K + k0 + ak;
    float4 a0 = *(const float4*)(ap);
    float4 a1 = *(const float4*)(ap + 4);
    As[ak + 0][am] = a0.x; As[ak + 1][am] = a0.y;
    As[ak + 2][am] = a0.z; As[ak + 3][am] = a0.w;
    As[ak + 4][am] = a1.x; As[ak + 5][am] = a1.y;
    As[ak + 6][am] = a1.z; As[ak + 7][am] = a1.w;
    int col = bn + bc;
    #pragma unroll
    for (int i = 0; i < 4; i++) {
      int kk = bk + i * 4;
      Bs[kk][bc] = (col < N) ? B[(size_t)(k0 + kk) * N + col] : 0.f;
    }
    __syncthreads();
    #pragma unroll
    for (int kk = 0; kk < 16; kk++) {
      float av[8], bv[4];
      #pragma unroll
      for (int i = 0; i < 8; i++) av[i] = As[kk][tr * 8 + i];
      #pragma unroll
      for (int j = 0; j < 4; j++) bv[j] = Bs[kk][tc * 4 + j];
      #pragma unroll
      for (int i = 0; i < 8; i++)
        #pragma unroll
        for (int j = 0; j < 4; j++) acc[i][j] += av[i] * bv[j];
    }
    __syncthreads();
  }
  #pragma unroll
  for (int i = 0; i < 8; i++) {
    int row = bm + tr * 8 + i;
    #pragma unroll
    for (int j = 0; j < 4; j++) {
      int col = bn + tc * 4 + j;
      if (col < N) {
        float v = acc[i][j];
        if (BIAS) v += bias[col];
        if (RELU) v = fmaxf(v, 0.f);
        size_t off = (size_t)row * N + col;
        if (RESID) v += resid[off];
        C[off] = v;
      }
    }
  }
}

// ---------------- fused causal attention: one block per (b,h) --------------
// qkv layout: [b,t, (q|k|v), h, d] i.e. row n=(b*TT+t), 624 cols.
// out: [b,t, h*HD+d] (NE cols).
__global__ __launch_bounds__(256) void k_attn(const float* __restrict__ qkv,
                                              float* __restrict__ o) {
  __shared__ __hip_bfloat16 Ks[TT * 53];
  __shared__ __hip_bfloat16 Vs[TT * 53];
  __shared__ float pbuf[4][TT];
  const int bh = blockIdx.x;
  const int b = bh >> 2, h = bh & 3;
  const float* base = qkv + (size_t)b * TT * 624;
  for (int i = threadIdx.x; i < TT * HD; i += 256) {
    int t = i / HD, d = i - t * HD;
    const float* src = base + t * 624 + h * HD + d;
    Ks[t * 53 + d] = __float2bfloat16(src[NE]);
    Vs[t * 53 + d] = __float2bfloat16(src[2 * NE]);
  }
  __syncthreads();
  const int wave = threadIdx.x >> 6, lane = threadIdx.x & 63;
  const float scale = 0.06933752453f;  // NE**-0.5 (reference scales by n_embed!)
  for (int t = wave; t < TT; t += 4) {
    const float* qrow = base + t * 624 + h * HD;
    float acc4[4] = {0.f, 0.f, 0.f, 0.f};
    for (int d = 0; d < HD; d++) {
      float qd = qrow[d];
      #pragma unroll
      for (int jj = 0; jj < 4; jj++)
        acc4[jj] += qd * __bfloat162float(Ks[(lane + jj * 64) * 53 + d]);
    }
    float p[4];
    float m = -1e30f;
    #pragma unroll
    for (int jj = 0; jj < 4; jj++) {
      int j = lane + jj * 64;
      p[jj] = (j <= t) ? acc4[jj] * scale : -1e30f;
      m = fmaxf(m, p[jj]);
    }
    #pragma unroll
    for (int off = 32; off; off >>= 1) m = fmaxf(m, __shfl_xor(m, off));
    float sum = 0.f;
    #pragma unroll
    for (int jj = 0; jj < 4; jj++) {
      float e = (p[jj] <= -1e29f) ? 0.f : __expf(p[jj] - m);
      p[jj] = e;
      sum += e;
      pbuf[wave][lane + jj * 64] = e;
    }
    #pragma unroll
    for (int off = 32; off; off >>= 1) sum += __shfl_xor(sum, off);
    float inv = 1.f / sum;
    if (lane < HD) {
      float acc = 0.f;
      for (int j = 0; j <= t; j++)
        acc += pbuf[wave][j] * __bfloat162float(Vs[j * 53 + lane]);
      o[((size_t)(b * TT + t)) * NE + h * HD + lane] = acc * inv;
    }
  }
}

// ---------------- loss: per-row LSE - logit[target] ----------------
__global__ __launch_bounds__(256) void k_loss_rows(const float* __restrict__ logits,
                                                   const int* __restrict__ targets,
                                                   float* __restrict__ row_loss) {
  int r = blockIdx.x * 4 + (threadIdx.x >> 6);
  int lane = threadIdx.x & 63;
  const float* row = logits + (size_t)r * VOCAB;
  float vals[24];
  int cnt = 0;
  float m = -1e30f;
  for (int c = lane; c < VOCAB; c += 64) { float v = row[c]; vals[cnt++] = v; m = fmaxf(m, v); }
  #pragma unroll
  for (int o = 32; o; o >>= 1) m = fmaxf(m, __shfl_xor(m, o));
  float sum = 0.f;
  for (int i = 0; i < cnt; i++) sum += __expf(vals[i] - m);
  #pragma unroll
  for (int o = 32; o; o >>= 1) sum += __shfl_xor(sum, o);
  if (lane == 0) row_loss[r] = (__logf(sum) + m) - row[targets[r]];
}

// deterministic final mean (no atomics: bit-stable across replays)
__global__ __launch_bounds__(256) void k_loss_reduce(const float* __restrict__ row_loss,
                                                     float* __restrict__ out_loss) {
  __shared__ float sh[256];
  float s = 0.f;
  for (int i = threadIdx.x; i < NTOK; i += 256) s += row_loss[i];
  sh[threadIdx.x] = s;
  __syncthreads();
  for (int k = 128; k; k >>= 1) {
    if (threadIdx.x < k) sh[threadIdx.x] += sh[threadIdx.x + k];
    __syncthreads();
  }
  if (threadIdx.x == 0) *out_loss = sh[0] * (1.f / NTOK);
}

extern "C" void kernel_launch(void* const* d_in, const int* in_sizes, int n_in,
                              void* d_out, int out_size, void* d_ws, size_t ws_size,
                              hipStream_t stream) {
  const int*   idx     = (const int*)d_in[0];
  const int*   targets = (const int*)d_in[1];
  const float* tok     = (const float*)d_in[2];
  const float* pos     = (const float*)d_in[3];
  const float* Wq      = (const float*)d_in[4];
  const float* Wk      = (const float*)d_in[5];
  const float* Wv      = (const float*)d_in[6];
  const float* Wo      = (const float*)d_in[7];
  const float* bo      = (const float*)d_in[8];
  const float* ln1g    = (const float*)d_in[9];
  const float* ln1b    = (const float*)d_in[10];
  const float* W1      = (const float*)d_in[11];
  const float* b1      = (const float*)d_in[12];
  const float* W2      = (const float*)d_in[13];
  const float* b2      = (const float*)d_in[14];
  const float* ln2g    = (const float*)d_in[15];
  const float* ln2b    = (const float*)d_in[16];
  const float* lnfg    = (const float*)d_in[17];
  const float* lnfb    = (const float*)d_in[18];
  const float* Wlm     = (const float*)d_in[19];
  const float* blm     = (const float*)d_in[20];
  float* out = (float*)d_out;

  // workspace layout (all f32): x | h | big(65536x832) | Bqkv | row_loss
  float* x        = (float*)d_ws;
  float* h        = x + (size_t)NTOK * NE;
  float* big      = h + (size_t)NTOK * NE;
  float* Bq       = big + (size_t)NTOK * (4 * NE);
  float* row_loss = Bq + (size_t)NL * NE * 624;

  k_pack_qkv<<<(NL * NE * 624) / 256, 256, 0, stream>>>(Wq, Wk, Wv, Bq);
  k_embed<<<((size_t)NTOK * NE) / 256, 256, 0, stream>>>(idx, tok, pos, x);

  for (int l = 0; l < NL; l++) {
    k_ln<<<NTOK / 4, 256, 0, stream>>>(x, ln1g + l * NE, ln1b + l * NE, h);
    k_gemm<false, false, false><<<dim3(10, 512), 256, 0, stream>>>(
        h, Bq + (size_t)l * NE * 624, nullptr, nullptr, big, NTOK, 624, NE);
    k_attn<<<BBATCH * NHD, 256, 0, stream>>>(big, h);
    k_gemm<false, true, true><<<dim3(4, 512), 256, 0, stream>>>(
        h, Wo + (size_t)l * NE * NE, bo + l * NE, x, x, NTOK, NE, NE);
    k_ln<<<NTOK / 4, 256, 0, stream>>>(x, ln2g + l * NE, ln2b + l * NE, h);
    k_gemm<true, false, true><<<dim3(13, 512), 256, 0, stream>>>(
        h, W1 + (size_t)l * NE * (4 * NE), b1 + l * (4 * NE), nullptr, big,
        NTOK, 4 * NE, NE);
    k_gemm<false, true, true><<<dim3(4, 512), 256, 0, stream>>>(
        big, W2 + (size_t)l * (4 * NE) * NE, b2 + l * NE, x, x, NTOK, NE, 4 * NE);
  }

  k_ln<<<NTOK / 4, 256, 0, stream>>>(x, lnfg, lnfb, h);
  k_gemm<false, false, true><<<dim3(24, 512), 256, 0, stream>>>(
      h, Wlm, blm, nullptr, out, NTOK, VOCAB, NE);

  k_loss_rows<<<NTOK / 4, 256, 0, stream>>>(out, targets, row_loss);
  k_loss_reduce<<<1, 256, 0, stream>>>(row_loss, out + (out_size - 1));
}

// Round 2
// 7160.671 us; speedup vs baseline: 1.9015x; 1.9015x over previous
//
#include <hip/hip_runtime.h>
#include <hip/hip_bf16.h>
#include <math.h>

#define VOCAB 1500
#define NE    208
#define TT    256
#define NHD   4
#define HD    52
#define NL    8
#define BBATCH 256
#define NTOK  (BBATCH * TT)   // 65536
#define KP    224             // NE padded to multiple of 32

typedef __attribute__((ext_vector_type(8))) short bf16x8;
typedef __attribute__((ext_vector_type(4))) float f32x4;
typedef __attribute__((ext_vector_type(4))) int i32x4;

// ---------------- embedding: x = tok_emb[idx] + pos_emb ----------------
__global__ __launch_bounds__(256) void k_embed(const int* __restrict__ idx,
                                               const float* __restrict__ tok,
                                               const float* __restrict__ pos,
                                               float* __restrict__ x) {
  int i = blockIdx.x * 256 + threadIdx.x;          // over NTOK*NE, exact grid
  int n = i / NE, c = i - n * NE;
  int t = n & (TT - 1);
  x[i] = tok[idx[n] * NE + c] + pos[t * NE + c];
}

// ---------- weight prep: transposed + K-padded bf16 copies ----------
// WqkvT: [NL][640][224]  (row n = output col j (624 valid), col = input c)
__global__ __launch_bounds__(256) void k_prep_qkvT(const float* __restrict__ Wq,
                                                   const float* __restrict__ Wk,
                                                   const float* __restrict__ Wv,
                                                   __hip_bfloat16* __restrict__ o) {
  int i = blockIdx.x * 256 + threadIdx.x;          // NL*640*224 exact
  int c = i % KP;
  int jl = i / KP;
  int j = jl % 640, l = jl / 640;
  float v = 0.f;
  if (j < 624 && c < NE) {
    int sel = j / NE, hd = j - sel * NE;
    int h = hd / HD, d = hd - h * HD;
    const float* W = (sel == 0) ? Wq : (sel == 1) ? Wk : Wv;
    v = W[(((size_t)l * NHD + h) * NE + c) * HD + d];
  }
  o[i] = __float2bfloat16(v);
}

// WoT: [NL][256][224]
__global__ __launch_bounds__(256) void k_prep_oT(const float* __restrict__ Wo,
                                                 __hip_bfloat16* __restrict__ o) {
  int i = blockIdx.x * 256 + threadIdx.x;          // NL*256*224 exact
  int c = i % KP;
  int jl = i / KP;
  int j = jl % 256, l = jl / 256;
  float v = (j < NE && c < NE) ? Wo[((size_t)l * NE + c) * NE + j] : 0.f;
  o[i] = __float2bfloat16(v);
}

// W1T: [NL][896][224]
__global__ __launch_bounds__(256) void k_prep_1T(const float* __restrict__ W1,
                                                 __hip_bfloat16* __restrict__ o) {
  int i = blockIdx.x * 256 + threadIdx.x;          // NL*896*224 exact
  int c = i % KP;
  int jl = i / KP;
  int j = jl % 896, l = jl / 896;
  float v = (j < 832 && c < NE) ? W1[((size_t)l * NE + c) * 832 + j] : 0.f;
  o[i] = __float2bfloat16(v);
}

// W2T: [NL][256][832]
__global__ __launch_bounds__(256) void k_prep_2T(const float* __restrict__ W2,
                                                 __hip_bfloat16* __restrict__ o) {
  int i = blockIdx.x * 256 + threadIdx.x;          // NL*256*832 exact
  int c = i % 832;
  int jl = i / 832;
  int j = jl % 256, l = jl / 256;
  float v = (j < NE) ? W2[((size_t)l * 832 + c) * NE + j] : 0.f;
  o[i] = __float2bfloat16(v);
}

// WlmT: [1536][224]
__global__ __launch_bounds__(256) void k_prep_lmT(const float* __restrict__ Wlm,
                                                  __hip_bfloat16* __restrict__ o) {
  int i = blockIdx.x * 256 + threadIdx.x;          // 1536*224 exact
  int c = i % KP;
  int j = i / KP;
  float v = (j < VOCAB && c < NE) ? Wlm[(size_t)c * VOCAB + j] : 0.f;
  o[i] = __float2bfloat16(v);
}

// ---------------- layernorm: one wave per row, bf16 out (ld 224, pads=0) ----
__global__ __launch_bounds__(256) void k_ln_bf(const float* __restrict__ x,
                                               const float* __restrict__ g,
                                               const float* __restrict__ b,
                                               __hip_bfloat16* __restrict__ h) {
  int r = blockIdx.x * 4 + (threadIdx.x >> 6);
  int lane = threadIdx.x & 63;
  const float* row = x + (size_t)r * NE;
  float v[4];
  int cnt = 0;
  float s = 0.f;
  for (int c = lane; c < NE; c += 64) { v[cnt] = row[c]; s += v[cnt]; cnt++; }
  #pragma unroll
  for (int o = 32; o; o >>= 1) s += __shfl_xor(s, o);
  float mu = s * (1.f / NE);
  float q = 0.f;
  for (int i = 0; i < cnt; i++) { float d = v[i] - mu; q += d * d; }
  #pragma unroll
  for (int o = 32; o; o >>= 1) q += __shfl_xor(q, o);
  float inv = rsqrtf(q * (1.f / NE) + 1e-5f);
  __hip_bfloat16* out = h + (size_t)r * KP;
  int i = 0;
  for (int c = lane; c < KP; c += 64, i++) {
    float o = (c < NE) ? (v[i] - mu) * inv * g[c] + b[c] : 0.f;
    out[c] = __float2bfloat16(o);
  }
}

// ---------------- bf16 MFMA GEMM ----------------
// A [M x K] bf16 row-major (lda), BT [>=N x K] bf16 row-major (ldb),
// C = A@B (+bias)(relu)(+resid), out f32 or bf16 (ldc). K % 32 == 0, M % 128 == 0.
// 128x128 tile, 4 waves of 64x64, 16x16x32 MFMA (m93-verified structure).
template <bool RELU, bool RESID, bool BIAS, bool OUTBF>
__global__ __launch_bounds__(256) void k_mgemm(const __hip_bfloat16* __restrict__ A, int lda,
                                               const __hip_bfloat16* __restrict__ BT, int ldb,
                                               const float* __restrict__ bias,
                                               const float* __restrict__ resid,
                                               void* __restrict__ Cout, int ldc,
                                               int N, int K) {
  __shared__ __hip_bfloat16 As[128][40];   // 40: 16B-aligned rows, conflict-breaking pad
  __shared__ __hip_bfloat16 Bs[128][40];
  const int bm = blockIdx.y * 128, bn = blockIdx.x * 128;
  const int tid = threadIdx.x;
  const int wave = tid >> 6, lane = tid & 63;
  const int wr = (wave >> 1) * 64, wc = (wave & 1) * 64;
  const int l15 = lane & 15, l4 = lane >> 4;
  f32x4 acc[4][4] = {};
  const int sr = tid >> 2, sg = (tid & 3) * 8;
  for (int k0 = 0; k0 < K; k0 += 32) {
    #pragma unroll
    for (int p = 0; p < 2; p++) {
      int row = sr + p * 64;
      i32x4 av = *(const i32x4*)(A + (size_t)(bm + row) * lda + k0 + sg);
      *(i32x4*)&As[row][sg] = av;
      i32x4 bv = *(const i32x4*)(BT + (size_t)(bn + row) * ldb + k0 + sg);
      *(i32x4*)&Bs[row][sg] = bv;
    }
    __syncthreads();
    bf16x8 af[4], bfr[4];
    #pragma unroll
    for (int m = 0; m < 4; m++)
      af[m] = *(const bf16x8*)&As[wr + m * 16 + l15][l4 * 8];
    #pragma unroll
    for (int n = 0; n < 4; n++)
      bfr[n] = *(const bf16x8*)&Bs[wc + n * 16 + l15][l4 * 8];
    #pragma unroll
    for (int m = 0; m < 4; m++)
      #pragma unroll
      for (int n = 0; n < 4; n++)
        acc[m][n] = __builtin_amdgcn_mfma_f32_16x16x32_bf16(af[m], bfr[n], acc[m][n], 0, 0, 0);
    __syncthreads();
  }
  #pragma unroll
  for (int m = 0; m < 4; m++) {
    #pragma unroll
    for (int n = 0; n < 4; n++) {
      int col = bn + wc + n * 16 + l15;
      if (col < N) {
        float bv = BIAS ? bias[col] : 0.f;
        #pragma unroll
        for (int j = 0; j < 4; j++) {
          int row = bm + wr + m * 16 + l4 * 4 + j;
          float v = acc[m][n][j] + bv;
          if (RELU) v = fmaxf(v, 0.f);
          size_t off = (size_t)row * ldc + col;
          if (RESID) v += resid[off];
          if (OUTBF) ((__hip_bfloat16*)Cout)[off] = __float2bfloat16(v);
          else       ((float*)Cout)[off] = v;
        }
      }
    }
  }
}

// ---------------- fused causal attention: one block per (b,h) --------------
// qkv (bf16) layout: row n=(b*TT+t), 624 cols: [q|k|v] each h*HD+d.
// out: bf16 h-buffer ld 224 (pad cols untouched; LN wrote them zero).
__global__ __launch_bounds__(256) void k_attn(const __hip_bfloat16* __restrict__ qkv,
                                              __hip_bfloat16* __restrict__ o) {
  __shared__ __hip_bfloat16 Ks[TT * 53];
  __shared__ __hip_bfloat16 Vs[TT * 53];
  __shared__ float pbuf[4][TT];
  const int bh = blockIdx.x;
  const int b = bh >> 2, h = bh & 3;
  const __hip_bfloat16* base = qkv + (size_t)b * TT * 624;
  for (int i = threadIdx.x; i < TT * HD; i += 256) {
    int t = i / HD, d = i - t * HD;
    const __hip_bfloat16* src = base + t * 624 + h * HD + d;
    Ks[t * 53 + d] = src[NE];
    Vs[t * 53 + d] = src[2 * NE];
  }
  __syncthreads();
  const int wave = threadIdx.x >> 6, lane = threadIdx.x & 63;
  const float scale = 0.06933752453f;  // NE**-0.5 (reference scales by n_embed!)
  for (int t = wave; t < TT; t += 4) {
    const __hip_bfloat16* qrow = base + t * 624 + h * HD;
    float acc4[4] = {0.f, 0.f, 0.f, 0.f};
    for (int d = 0; d < HD; d++) {
      float qd = __bfloat162float(qrow[d]);
      #pragma unroll
      for (int jj = 0; jj < 4; jj++)
        acc4[jj] += qd * __bfloat162float(Ks[(lane + jj * 64) * 53 + d]);
    }
    float p[4];
    float m = -1e30f;
    #pragma unroll
    for (int jj = 0; jj < 4; jj++) {
      int j = lane + jj * 64;
      p[jj] = (j <= t) ? acc4[jj] * scale : -1e30f;
      m = fmaxf(m, p[jj]);
    }
    #pragma unroll
    for (int off = 32; off; off >>= 1) m = fmaxf(m, __shfl_xor(m, off));
    float sum = 0.f;
    #pragma unroll
    for (int jj = 0; jj < 4; jj++) {
      float e = (p[jj] <= -1e29f) ? 0.f : __expf(p[jj] - m);
      p[jj] = e;
      sum += e;
      pbuf[wave][lane + jj * 64] = e;
    }
    #pragma unroll
    for (int off = 32; off; off >>= 1) sum += __shfl_xor(sum, off);
    float inv = 1.f / sum;
    if (lane < HD) {
      float acc = 0.f;
      for (int j = 0; j <= t; j++)
        acc += pbuf[wave][j] * __bfloat162float(Vs[j * 53 + lane]);
      o[((size_t)(b * TT + t)) * KP + h * HD + lane] = __float2bfloat16(acc * inv);
    }
  }
}

// ---------------- loss: per-row LSE - logit[target] ----------------
__global__ __launch_bounds__(256) void k_loss_rows(const float* __restrict__ logits,
                                                   const int* __restrict__ targets,
                                                   float* __restrict__ row_loss) {
  int r = blockIdx.x * 4 + (threadIdx.x >> 6);
  int lane = threadIdx.x & 63;
  const float* row = logits + (size_t)r * VOCAB;
  float vals[24];
  int cnt = 0;
  float m = -1e30f;
  for (int c = lane; c < VOCAB; c += 64) { float v = row[c]; vals[cnt++] = v; m = fmaxf(m, v); }
  #pragma unroll
  for (int o = 32; o; o >>= 1) m = fmaxf(m, __shfl_xor(m, o));
  float sum = 0.f;
  for (int i = 0; i < cnt; i++) sum += __expf(vals[i] - m);
  #pragma unroll
  for (int o = 32; o; o >>= 1) sum += __shfl_xor(sum, o);
  if (lane == 0) row_loss[r] = (__logf(sum) + m) - row[targets[r]];
}

// deterministic final mean (no atomics: bit-stable across replays)
__global__ __launch_bounds__(256) void k_loss_reduce(const float* __restrict__ row_loss,
                                                     float* __restrict__ out_loss) {
  __shared__ float sh[256];
  float s = 0.f;
  for (int i = threadIdx.x; i < NTOK; i += 256) s += row_loss[i];
  sh[threadIdx.x] = s;
  __syncthreads();
  for (int k = 128; k; k >>= 1) {
    if (threadIdx.x < k) sh[threadIdx.x] += sh[threadIdx.x + k];
    __syncthreads();
  }
  if (threadIdx.x == 0) *out_loss = sh[0] * (1.f / NTOK);
}

extern "C" void kernel_launch(void* const* d_in, const int* in_sizes, int n_in,
                              void* d_out, int out_size, void* d_ws, size_t ws_size,
                              hipStream_t stream) {
  const int*   idx     = (const int*)d_in[0];
  const int*   targets = (const int*)d_in[1];
  const float* tok     = (const float*)d_in[2];
  const float* pos     = (const float*)d_in[3];
  const float* Wq      = (const float*)d_in[4];
  const float* Wk      = (const float*)d_in[5];
  const float* Wv      = (const float*)d_in[6];
  const float* Wo      = (const float*)d_in[7];
  const float* bo      = (const float*)d_in[8];
  const float* ln1g    = (const float*)d_in[9];
  const float* ln1b    = (const float*)d_in[10];
  const float* W1      = (const float*)d_in[11];
  const float* b1      = (const float*)d_in[12];
  const float* W2      = (const float*)d_in[13];
  const float* b2      = (const float*)d_in[14];
  const float* ln2g    = (const float*)d_in[15];
  const float* ln2b    = (const float*)d_in[16];
  const float* lnfg    = (const float*)d_in[17];
  const float* lnfb    = (const float*)d_in[18];
  const float* Wlm     = (const float*)d_in[19];
  const float* blm     = (const float*)d_in[20];
  float* out = (float*)d_out;

  // workspace layout (~285 MB)
  char* w = (char*)d_ws;
  float* x = (float*)w;                    w += (size_t)NTOK * NE * 4;
  __hip_bfloat16* qkv = (__hip_bfloat16*)w; w += (size_t)NTOK * 624 * 2;
  __hip_bfloat16* hbf = (__hip_bfloat16*)w; w += (size_t)NTOK * KP * 2;
  __hip_bfloat16* act = (__hip_bfloat16*)w; w += (size_t)NTOK * 832 * 2;
  __hip_bfloat16* WqkvT = (__hip_bfloat16*)w; w += (size_t)NL * 640 * KP * 2;
  __hip_bfloat16* WoT   = (__hip_bfloat16*)w; w += (size_t)NL * 256 * KP * 2;
  __hip_bfloat16* W1T   = (__hip_bfloat16*)w; w += (size_t)NL * 896 * KP * 2;
  __hip_bfloat16* W2T   = (__hip_bfloat16*)w; w += (size_t)NL * 256 * 832 * 2;
  __hip_bfloat16* WlmT  = (__hip_bfloat16*)w; w += (size_t)1536 * KP * 2;
  float* row_loss = (float*)w;

  k_prep_qkvT<<<NL * 640 * KP / 256, 256, 0, stream>>>(Wq, Wk, Wv, WqkvT);
  k_prep_oT<<<NL * 256 * KP / 256, 256, 0, stream>>>(Wo, WoT);
  k_prep_1T<<<NL * 896 * KP / 256, 256, 0, stream>>>(W1, W1T);
  k_prep_2T<<<NL * 256 * 832 / 256, 256, 0, stream>>>(W2, W2T);
  k_prep_lmT<<<1536 * KP / 256, 256, 0, stream>>>(Wlm, WlmT);
  k_embed<<<NTOK * NE / 256, 256, 0, stream>>>(idx, tok, pos, x);

  for (int l = 0; l < NL; l++) {
    k_ln_bf<<<NTOK / 4, 256, 0, stream>>>(x, ln1g + l * NE, ln1b + l * NE, hbf);
    k_mgemm<false, false, false, true><<<dim3(5, 512), 256, 0, stream>>>(
        hbf, KP, WqkvT + (size_t)l * 640 * KP, KP, nullptr, nullptr, qkv, 624, 624, KP);
    k_attn<<<BBATCH * NHD, 256, 0, stream>>>(qkv, hbf);
    k_mgemm<false, true, true, false><<<dim3(2, 512), 256, 0, stream>>>(
        hbf, KP, WoT + (size_t)l * 256 * KP, KP, bo + l * NE, x, x, NE, NE, KP);
    k_ln_bf<<<NTOK / 4, 256, 0, stream>>>(x, ln2g + l * NE, ln2b + l * NE, hbf);
    k_mgemm<true, false, true, true><<<dim3(7, 512), 256, 0, stream>>>(
        hbf, KP, W1T + (size_t)l * 896 * KP, KP, b1 + l * 832, nullptr, act, 832, 832, KP);
    k_mgemm<false, true, true, false><<<dim3(2, 512), 256, 0, stream>>>(
        act, 832, W2T + (size_t)l * 256 * 832, 832, b2 + l * NE, x, x, NE, NE, 832);
  }

  k_ln_bf<<<NTOK / 4, 256, 0, stream>>>(x, lnfg, lnfb, hbf);
  k_mgemm<false, false, true, false><<<dim3(12, 512), 256, 0, stream>>>(
      hbf, KP, WlmT, KP, blm, nullptr, out, VOCAB, VOCAB, KP);

  k_loss_rows<<<NTOK / 4, 256, 0, stream>>>(out, targets, row_loss);
  k_loss_reduce<<<1, 256, 0, stream>>>(row_loss, out + ((size_t)out_size - 1));
}

// Round 3
// 3780.491 us; speedup vs baseline: 3.6016x; 1.8941x over previous
//
#include <hip/hip_runtime.h>
#include <hip/hip_bf16.h>
#include <math.h>

#define VOCAB 1500
#define NE    208
#define TT    256
#define NHD   4
#define HD    52
#define NL    8
#define BBATCH 256
#define NTOK  (BBATCH * TT)   // 65536
#define KP    224             // NE padded to multiple of 32

typedef __attribute__((ext_vector_type(8))) short bf16x8;
typedef __attribute__((ext_vector_type(4))) short s16x4;
typedef __attribute__((ext_vector_type(4))) float f32x4;
typedef __attribute__((ext_vector_type(4))) int i32x4;
typedef __attribute__((ext_vector_type(4))) _Float16 f16x4;

// ---------------- embedding: x = tok_emb[idx] + pos_emb ----------------
__global__ __launch_bounds__(256) void k_embed(const int* __restrict__ idx,
                                               const float* __restrict__ tok,
                                               const float* __restrict__ pos,
                                               float* __restrict__ x) {
  int i = blockIdx.x * 256 + threadIdx.x;          // over NTOK*NE, exact grid
  int n = i / NE, c = i - n * NE;
  int t = n & (TT - 1);
  x[i] = tok[idx[n] * NE + c] + pos[t * NE + c];
}

// ---------- weight prep: transposed + K-padded bf16 copies ----------
__global__ __launch_bounds__(256) void k_prep_qkvT(const float* __restrict__ Wq,
                                                   const float* __restrict__ Wk,
                                                   const float* __restrict__ Wv,
                                                   __hip_bfloat16* __restrict__ o) {
  int i = blockIdx.x * 256 + threadIdx.x;          // NL*640*224 exact
  int c = i % KP;
  int jl = i / KP;
  int j = jl % 640, l = jl / 640;
  float v = 0.f;
  if (j < 624 && c < NE) {
    int sel = j / NE, hd = j - sel * NE;
    int h = hd / HD, d = hd - h * HD;
    const float* W = (sel == 0) ? Wq : (sel == 1) ? Wk : Wv;
    v = W[(((size_t)l * NHD + h) * NE + c) * HD + d];
  }
  o[i] = __float2bfloat16(v);
}

__global__ __launch_bounds__(256) void k_prep_oT(const float* __restrict__ Wo,
                                                 __hip_bfloat16* __restrict__ o) {
  int i = blockIdx.x * 256 + threadIdx.x;          // NL*256*224 exact
  int c = i % KP;
  int jl = i / KP;
  int j = jl % 256, l = jl / 256;
  float v = (j < NE && c < NE) ? Wo[((size_t)l * NE + c) * NE + j] : 0.f;
  o[i] = __float2bfloat16(v);
}

__global__ __launch_bounds__(256) void k_prep_1T(const float* __restrict__ W1,
                                                 __hip_bfloat16* __restrict__ o) {
  int i = blockIdx.x * 256 + threadIdx.x;          // NL*896*224 exact
  int c = i % KP;
  int jl = i / KP;
  int j = jl % 896, l = jl / 896;
  float v = (j < 832 && c < NE) ? W1[((size_t)l * NE + c) * 832 + j] : 0.f;
  o[i] = __float2bfloat16(v);
}

__global__ __launch_bounds__(256) void k_prep_2T(const float* __restrict__ W2,
                                                 __hip_bfloat16* __restrict__ o) {
  int i = blockIdx.x * 256 + threadIdx.x;          // NL*256*832 exact
  int c = i % 832;
  int jl = i / 832;
  int j = jl % 256, l = jl / 256;
  float v = (j < NE) ? W2[((size_t)l * 832 + c) * NE + j] : 0.f;
  o[i] = __float2bfloat16(v);
}

__global__ __launch_bounds__(256) void k_prep_lmT(const float* __restrict__ Wlm,
                                                  __hip_bfloat16* __restrict__ o) {
  int i = blockIdx.x * 256 + threadIdx.x;          // 1536*224 exact
  int c = i % KP;
  int j = i / KP;
  float v = (j < VOCAB && c < NE) ? Wlm[(size_t)c * VOCAB + j] : 0.f;
  o[i] = __float2bfloat16(v);
}

// ---------------- layernorm: one wave per row, bf16 out (ld 224, pads=0) ----
__global__ __launch_bounds__(256) void k_ln_bf(const float* __restrict__ x,
                                               const float* __restrict__ g,
                                               const float* __restrict__ b,
                                               __hip_bfloat16* __restrict__ h) {
  int r = blockIdx.x * 4 + (threadIdx.x >> 6);
  int lane = threadIdx.x & 63;
  const float* row = x + (size_t)r * NE;
  float v[4];
  int cnt = 0;
  float s = 0.f;
  for (int c = lane; c < NE; c += 64) { v[cnt] = row[c]; s += v[cnt]; cnt++; }
  #pragma unroll
  for (int o = 32; o; o >>= 1) s += __shfl_xor(s, o);
  float mu = s * (1.f / NE);
  float q = 0.f;
  for (int i = 0; i < cnt; i++) { float d = v[i] - mu; q += d * d; }
  #pragma unroll
  for (int o = 32; o; o >>= 1) q += __shfl_xor(q, o);
  float inv = rsqrtf(q * (1.f / NE) + 1e-5f);
  __hip_bfloat16* out = h + (size_t)r * KP;
  int i = 0;
  for (int c = lane; c < KP; c += 64, i++) {
    float o = (c < NE) ? (v[i] - mu) * inv * g[c] + b[c] : 0.f;
    out[c] = __float2bfloat16(o);
  }
}

// ---------------- bf16 MFMA GEMM (128x128 tile, 4 waves, 16x16x32) ----------
template <bool RELU, bool RESID, bool BIAS, bool OUTBF>
__global__ __launch_bounds__(256) void k_mgemm(const __hip_bfloat16* __restrict__ A, int lda,
                                               const __hip_bfloat16* __restrict__ BT, int ldb,
                                               const float* __restrict__ bias,
                                               const float* __restrict__ resid,
                                               void* __restrict__ Cout, int ldc,
                                               int N, int K) {
  __shared__ __hip_bfloat16 As[128][40];
  __shared__ __hip_bfloat16 Bs[128][40];
  const int bm = blockIdx.y * 128, bn = blockIdx.x * 128;
  const int tid = threadIdx.x;
  const int wave = tid >> 6, lane = tid & 63;
  const int wr = (wave >> 1) * 64, wc = (wave & 1) * 64;
  const int l15 = lane & 15, l4 = lane >> 4;
  f32x4 acc[4][4] = {};
  const int sr = tid >> 2, sg = (tid & 3) * 8;
  for (int k0 = 0; k0 < K; k0 += 32) {
    #pragma unroll
    for (int p = 0; p < 2; p++) {
      int row = sr + p * 64;
      i32x4 av = *(const i32x4*)(A + (size_t)(bm + row) * lda + k0 + sg);
      *(i32x4*)&As[row][sg] = av;
      i32x4 bv = *(const i32x4*)(BT + (size_t)(bn + row) * ldb + k0 + sg);
      *(i32x4*)&Bs[row][sg] = bv;
    }
    __syncthreads();
    bf16x8 af[4], bfr[4];
    #pragma unroll
    for (int m = 0; m < 4; m++)
      af[m] = *(const bf16x8*)&As[wr + m * 16 + l15][l4 * 8];
    #pragma unroll
    for (int n = 0; n < 4; n++)
      bfr[n] = *(const bf16x8*)&Bs[wc + n * 16 + l15][l4 * 8];
    #pragma unroll
    for (int m = 0; m < 4; m++)
      #pragma unroll
      for (int n = 0; n < 4; n++)
        acc[m][n] = __builtin_amdgcn_mfma_f32_16x16x32_bf16(af[m], bfr[n], acc[m][n], 0, 0, 0);
    __syncthreads();
  }
  #pragma unroll
  for (int m = 0; m < 4; m++) {
    #pragma unroll
    for (int n = 0; n < 4; n++) {
      int col = bn + wc + n * 16 + l15;
      if (col < N) {
        float bv = BIAS ? bias[col] : 0.f;
        #pragma unroll
        for (int j = 0; j < 4; j++) {
          int row = bm + wr + m * 16 + l4 * 4 + j;
          float v = acc[m][n][j] + bv;
          if (RELU) v = fmaxf(v, 0.f);
          size_t off = (size_t)row * ldc + col;
          if (RESID) v += resid[off];
          if (OUTBF) ((__hip_bfloat16*)Cout)[off] = __float2bfloat16(v);
          else       ((float*)Cout)[off] = v;
        }
      }
    }
  }
}

// ---------------- MFMA flash attention: one block per (b,h), 4 waves -------
// qkv (bf16): row n=(b*TT+t), 624 cols: [q|k|v] each h*HD+d.
// out: bf16 h-buffer ld KP (cols 208..223 untouched: LN zeroed them).
// Swapped QK^T: S^T = mfma(K, Q) so lane holds P[q=n*16+l15][key=l4*4+j],
// which is exactly the B-fragment of mfma_f32_16x16x16f16 for PV (no bounce).
#define KSTRIDE 72    // bf16: 144B rows -> 16B-aligned b128 reads, bank-balanced
#define VSTRIDE 260   // f16: 520B rows -> 8B-aligned b64 reads
__global__ __launch_bounds__(256) void k_attn_mfma(const __hip_bfloat16* __restrict__ qkv,
                                                   __hip_bfloat16* __restrict__ o) {
  __shared__ __hip_bfloat16 Ks[256 * KSTRIDE];   // 36864 B
  __shared__ _Float16      Vt[64 * VSTRIDE];     // 33280 B
  const int bh = blockIdx.x, b = bh >> 2, h = bh & 3;
  const __hip_bfloat16* base = qkv + (size_t)b * TT * 624;
  const int tid = threadIdx.x;
  // stage K: Ks[key][d], d 0..63 (>=52 zeroed)
  #pragma unroll
  for (int it = 0; it < 16; it++) {
    int u = it * 256 + tid;
    int t = u >> 4, d4 = (u & 15) * 4;
    s16x4 v = {};
    if (d4 < 52) v = *(const s16x4*)(base + t * 624 + 208 + h * HD + d4);
    *(s16x4*)&Ks[t * KSTRIDE + d4] = v;
  }
  // stage V transposed: Vt[d][t] as f16 (d>=52 zeroed)
  #pragma unroll 4
  for (int it = 0; it < 64; it++) {
    int u = it * 256 + tid;
    int d = u & 63, t = u >> 6;
    float v = (d < 52) ? __bfloat162float(base[t * 624 + 416 + h * HD + d]) : 0.f;
    Vt[d * VSTRIDE + t] = (_Float16)v;
  }
  __syncthreads();

  const int w = tid >> 6, lane = tid & 63, l15 = lane & 15, l4 = lane >> 4;
  const int q0 = w * 64;
  const float scale = 0.06933752453f;  // NE**-0.5 (reference scales by n_embed)
  // Q fragments from global (B-operand: row q=l15, k=l4*8+i), zero-pad >=52
  bf16x8 qf[4][2];
  #pragma unroll
  for (int n = 0; n < 4; n++) {
    const __hip_bfloat16* qrow = base + (q0 + n * 16 + l15) * 624 + h * HD;
    #pragma unroll
    for (int ks = 0; ks < 2; ks++) {
      int s = ks * 32 + l4 * 8;
      union { s16x4 h2[2]; bf16x8 v; } u;
      u.h2[0] = (s <= 48) ? *(const s16x4*)(qrow + s) : (s16x4){};
      u.h2[1] = (s <= 44) ? *(const s16x4*)(qrow + s + 4) : (s16x4){};
      qf[n][ks] = u.v;
    }
  }
  f32x4 oacc[4][4] = {};     // [m over d][n over q], C layout col=l15=q
  float mrun[4] = {-1e30f, -1e30f, -1e30f, -1e30f};
  float lrun[4] = {0.f, 0.f, 0.f, 0.f};
  const int nch = 4 * (w + 1);
  for (int c = 0; c < nch; c++) {
    const int kb = c * 16;
    const bf16x8 kf0 = *(const bf16x8*)&Ks[(kb + l15) * KSTRIDE + l4 * 8];
    const bf16x8 kf1 = *(const bf16x8*)&Ks[(kb + l15) * KSTRIDE + 32 + l4 * 8];
    #pragma unroll
    for (int n = 0; n < 4; n++) {
      if (kb > q0 + n * 16 + 15) continue;   // tile fully masked (uniform)
      f32x4 s4 = __builtin_amdgcn_mfma_f32_16x16x32_bf16(kf0, qf[n][0],
                                                         (f32x4){0.f, 0.f, 0.f, 0.f}, 0, 0, 0);
      s4 = __builtin_amdgcn_mfma_f32_16x16x32_bf16(kf1, qf[n][1], s4, 0, 0, 0);
      const int q = q0 + n * 16 + l15;
      float pv[4];
      float pmax = -1e30f;
      #pragma unroll
      for (int j = 0; j < 4; j++) {
        int key = kb + l4 * 4 + j;
        float s = s4[j] * scale;
        pv[j] = (key <= q) ? s : -1e30f;
        pmax = fmaxf(pmax, pv[j]);
      }
      pmax = fmaxf(pmax, __shfl_xor(pmax, 16));
      pmax = fmaxf(pmax, __shfl_xor(pmax, 32));
      const float newm = fmaxf(mrun[n], pmax);
      const float r = __expf(mrun[n] - newm);
      float psum = 0.f;
      f16x4 pb;
      #pragma unroll
      for (int j = 0; j < 4; j++) {
        float e = __expf(pv[j] - newm);
        psum += e;
        pb[j] = (_Float16)e;
      }
      psum += __shfl_xor(psum, 16);
      psum += __shfl_xor(psum, 32);
      lrun[n] = lrun[n] * r + psum;
      mrun[n] = newm;
      #pragma unroll
      for (int m = 0; m < 4; m++) {
        oacc[m][n][0] *= r; oacc[m][n][1] *= r;
        oacc[m][n][2] *= r; oacc[m][n][3] *= r;
      }
      #pragma unroll
      for (int m = 0; m < 4; m++) {
        f16x4 vf = *(const f16x4*)&Vt[(m * 16 + l15) * VSTRIDE + kb + l4 * 4];
        oacc[m][n] = __builtin_amdgcn_mfma_f32_16x16x16f16(vf, pb, oacc[m][n], 0, 0, 0);
      }
    }
  }
  #pragma unroll
  for (int n = 0; n < 4; n++) {
    const float inv = 1.f / lrun[n];
    __hip_bfloat16* orow = o + (size_t)(b * TT + q0 + n * 16 + l15) * KP + h * HD;
    #pragma unroll
    for (int m = 0; m < 4; m++)
      #pragma unroll
      for (int j = 0; j < 4; j++) {
        int d = m * 16 + l4 * 4 + j;
        if (d < HD) orow[d] = __float2bfloat16(oacc[m][n][j] * inv);
      }
  }
}

// ---------------- loss: per-row LSE - logit[target] ----------------
__global__ __launch_bounds__(256) void k_loss_rows(const float* __restrict__ logits,
                                                   const int* __restrict__ targets,
                                                   float* __restrict__ row_loss) {
  int r = blockIdx.x * 4 + (threadIdx.x >> 6);
  int lane = threadIdx.x & 63;
  const float* row = logits + (size_t)r * VOCAB;
  float vals[24];
  int cnt = 0;
  float m = -1e30f;
  for (int c = lane; c < VOCAB; c += 64) { float v = row[c]; vals[cnt++] = v; m = fmaxf(m, v); }
  #pragma unroll
  for (int o = 32; o; o >>= 1) m = fmaxf(m, __shfl_xor(m, o));
  float sum = 0.f;
  for (int i = 0; i < cnt; i++) sum += __expf(vals[i] - m);
  #pragma unroll
  for (int o = 32; o; o >>= 1) sum += __shfl_xor(sum, o);
  if (lane == 0) row_loss[r] = (__logf(sum) + m) - row[targets[r]];
}

__global__ __launch_bounds__(256) void k_loss_reduce(const float* __restrict__ row_loss,
                                                     float* __restrict__ out_loss) {
  __shared__ float sh[256];
  float s = 0.f;
  for (int i = threadIdx.x; i < NTOK; i += 256) s += row_loss[i];
  sh[threadIdx.x] = s;
  __syncthreads();
  for (int k = 128; k; k >>= 1) {
    if (threadIdx.x < k) sh[threadIdx.x] += sh[threadIdx.x + k];
    __syncthreads();
  }
  if (threadIdx.x == 0) *out_loss = sh[0] * (1.f / NTOK);
}

extern "C" void kernel_launch(void* const* d_in, const int* in_sizes, int n_in,
                              void* d_out, int out_size, void* d_ws, size_t ws_size,
                              hipStream_t stream) {
  const int*   idx     = (const int*)d_in[0];
  const int*   targets = (const int*)d_in[1];
  const float* tok     = (const float*)d_in[2];
  const float* pos     = (const float*)d_in[3];
  const float* Wq      = (const float*)d_in[4];
  const float* Wk      = (const float*)d_in[5];
  const float* Wv      = (const float*)d_in[6];
  const float* Wo      = (const float*)d_in[7];
  const float* bo      = (const float*)d_in[8];
  const float* ln1g    = (const float*)d_in[9];
  const float* ln1b    = (const float*)d_in[10];
  const float* W1      = (const float*)d_in[11];
  const float* b1      = (const float*)d_in[12];
  const float* W2      = (const float*)d_in[13];
  const float* b2      = (const float*)d_in[14];
  const float* ln2g    = (const float*)d_in[15];
  const float* ln2b    = (const float*)d_in[16];
  const float* lnfg    = (const float*)d_in[17];
  const float* lnfb    = (const float*)d_in[18];
  const float* Wlm     = (const float*)d_in[19];
  const float* blm     = (const float*)d_in[20];
  float* out = (float*)d_out;

  char* w = (char*)d_ws;
  float* x = (float*)w;                    w += (size_t)NTOK * NE * 4;
  __hip_bfloat16* qkv = (__hip_bfloat16*)w; w += (size_t)NTOK * 624 * 2;
  __hip_bfloat16* hbf = (__hip_bfloat16*)w; w += (size_t)NTOK * KP * 2;
  __hip_bfloat16* act = (__hip_bfloat16*)w; w += (size_t)NTOK * 832 * 2;
  __hip_bfloat16* WqkvT = (__hip_bfloat16*)w; w += (size_t)NL * 640 * KP * 2;
  __hip_bfloat16* WoT   = (__hip_bfloat16*)w; w += (size_t)NL * 256 * KP * 2;
  __hip_bfloat16* W1T   = (__hip_bfloat16*)w; w += (size_t)NL * 896 * KP * 2;
  __hip_bfloat16* W2T   = (__hip_bfloat16*)w; w += (size_t)NL * 256 * 832 * 2;
  __hip_bfloat16* WlmT  = (__hip_bfloat16*)w; w += (size_t)1536 * KP * 2;
  float* row_loss = (float*)w;

  k_prep_qkvT<<<NL * 640 * KP / 256, 256, 0, stream>>>(Wq, Wk, Wv, WqkvT);
  k_prep_oT<<<NL * 256 * KP / 256, 256, 0, stream>>>(Wo, WoT);
  k_prep_1T<<<NL * 896 * KP / 256, 256, 0, stream>>>(W1, W1T);
  k_prep_2T<<<NL * 256 * 832 / 256, 256, 0, stream>>>(W2, W2T);
  k_prep_lmT<<<1536 * KP / 256, 256, 0, stream>>>(Wlm, WlmT);
  k_embed<<<NTOK * NE / 256, 256, 0, stream>>>(idx, tok, pos, x);

  for (int l = 0; l < NL; l++) {
    k_ln_bf<<<NTOK / 4, 256, 0, stream>>>(x, ln1g + l * NE, ln1b + l * NE, hbf);
    k_mgemm<false, false, false, true><<<dim3(5, 512), 256, 0, stream>>>(
        hbf, KP, WqkvT + (size_t)l * 640 * KP, KP, nullptr, nullptr, qkv, 624, 624, KP);
    k_attn_mfma<<<BBATCH * NHD, 256, 0, stream>>>(qkv, hbf);
    k_mgemm<false, true, true, false><<<dim3(2, 512), 256, 0, stream>>>(
        hbf, KP, WoT + (size_t)l * 256 * KP, KP, bo + l * NE, x, x, NE, NE, KP);
    k_ln_bf<<<NTOK / 4, 256, 0, stream>>>(x, ln2g + l * NE, ln2b + l * NE, hbf);
    k_mgemm<true, false, true, true><<<dim3(7, 512), 256, 0, stream>>>(
        hbf, KP, W1T + (size_t)l * 896 * KP, KP, b1 + l * 832, nullptr, act, 832, 832, KP);
    k_mgemm<false, true, true, false><<<dim3(2, 512), 256, 0, stream>>>(
        act, 832, W2T + (size_t)l * 256 * 832, 832, b2 + l * NE, x, x, NE, NE, 832);
  }

  k_ln_bf<<<NTOK / 4, 256, 0, stream>>>(x, lnfg, lnfb, hbf);
  k_mgemm<false, false, true, false><<<dim3(12, 512), 256, 0, stream>>>(
      hbf, KP, WlmT, KP, blm, nullptr, out, VOCAB, VOCAB, KP);

  k_loss_rows<<<NTOK / 4, 256, 0, stream>>>(out, targets, row_loss);
  k_loss_reduce<<<1, 256, 0, stream>>>(row_loss, out + ((size_t)out_size - 1));
}

// Round 4
// 3730.443 us; speedup vs baseline: 3.6499x; 1.0134x over previous
//
#include <hip/hip_runtime.h>
#include <hip/hip_bf16.h>
#include <math.h>

#define VOCAB 1500
#define NE    208
#define TT    256
#define NHD   4
#define HD    52
#define NL    8
#define BBATCH 256
#define NTOK  (BBATCH * TT)   // 65536
#define KP    224             // NE padded to multiple of 32

typedef __attribute__((ext_vector_type(8))) short bf16x8;
typedef __attribute__((ext_vector_type(4))) short s16x4;
typedef __attribute__((ext_vector_type(4))) float f32x4;
typedef __attribute__((ext_vector_type(4))) int i32x4;
typedef __attribute__((ext_vector_type(4))) _Float16 f16x4;

__device__ __forceinline__ void gload16(const void* g, void* l) {
  __builtin_amdgcn_global_load_lds(
      (const __attribute__((address_space(1))) unsigned int*)g,
      (__attribute__((address_space(3))) unsigned int*)l, 16, 0, 0);
}

// ---------------- embedding: x = tok_emb[idx] + pos_emb ----------------
__global__ __launch_bounds__(256) void k_embed(const int* __restrict__ idx,
                                               const float* __restrict__ tok,
                                               const float* __restrict__ pos,
                                               float* __restrict__ x) {
  int i = blockIdx.x * 256 + threadIdx.x;          // over NTOK*NE, exact grid
  int n = i / NE, c = i - n * NE;
  int t = n & (TT - 1);
  x[i] = tok[idx[n] * NE + c] + pos[t * NE + c];
}

// ---------- weight prep: transposed + K-padded bf16 copies ----------
__global__ __launch_bounds__(256) void k_prep_qkvT(const float* __restrict__ Wq,
                                                   const float* __restrict__ Wk,
                                                   const float* __restrict__ Wv,
                                                   __hip_bfloat16* __restrict__ o) {
  int i = blockIdx.x * 256 + threadIdx.x;          // NL*640*224 exact
  int c = i % KP;
  int jl = i / KP;
  int j = jl % 640, l = jl / 640;
  float v = 0.f;
  if (j < 624 && c < NE) {
    int sel = j / NE, hd = j - sel * NE;
    int h = hd / HD, d = hd - h * HD;
    const float* W = (sel == 0) ? Wq : (sel == 1) ? Wk : Wv;
    v = W[(((size_t)l * NHD + h) * NE + c) * HD + d];
  }
  o[i] = __float2bfloat16(v);
}

__global__ __launch_bounds__(256) void k_prep_oT(const float* __restrict__ Wo,
                                                 __hip_bfloat16* __restrict__ o) {
  int i = blockIdx.x * 256 + threadIdx.x;          // NL*256*224 exact
  int c = i % KP;
  int jl = i / KP;
  int j = jl % 256, l = jl / 256;
  float v = (j < NE && c < NE) ? Wo[((size_t)l * NE + c) * NE + j] : 0.f;
  o[i] = __float2bfloat16(v);
}

__global__ __launch_bounds__(256) void k_prep_1T(const float* __restrict__ W1,
                                                 __hip_bfloat16* __restrict__ o) {
  int i = blockIdx.x * 256 + threadIdx.x;          // NL*896*224 exact
  int c = i % KP;
  int jl = i / KP;
  int j = jl % 896, l = jl / 896;
  float v = (j < 832 && c < NE) ? W1[((size_t)l * NE + c) * 832 + j] : 0.f;
  o[i] = __float2bfloat16(v);
}

__global__ __launch_bounds__(256) void k_prep_2T(const float* __restrict__ W2,
                                                 __hip_bfloat16* __restrict__ o) {
  int i = blockIdx.x * 256 + threadIdx.x;          // NL*256*832 exact
  int c = i % 832;
  int jl = i / 832;
  int j = jl % 256, l = jl / 256;
  float v = (j < NE) ? W2[((size_t)l * 832 + c) * NE + j] : 0.f;
  o[i] = __float2bfloat16(v);
}

__global__ __launch_bounds__(256) void k_prep_lmT(const float* __restrict__ Wlm,
                                                  __hip_bfloat16* __restrict__ o) {
  int i = blockIdx.x * 256 + threadIdx.x;          // 1536*224 exact
  int c = i % KP;
  int j = i / KP;
  float v = (j < VOCAB && c < NE) ? Wlm[(size_t)c * VOCAB + j] : 0.f;
  o[i] = __float2bfloat16(v);
}

// ---------------- layernorm: one wave per row, bf16 out (ld 224, pads=0) ----
__global__ __launch_bounds__(256) void k_ln_bf(const float* __restrict__ x,
                                               const float* __restrict__ g,
                                               const float* __restrict__ b,
                                               __hip_bfloat16* __restrict__ h) {
  int r = blockIdx.x * 4 + (threadIdx.x >> 6);
  int lane = threadIdx.x & 63;
  const float* row = x + (size_t)r * NE;
  float v[4];
  int cnt = 0;
  float s = 0.f;
  for (int c = lane; c < NE; c += 64) { v[cnt] = row[c]; s += v[cnt]; cnt++; }
  #pragma unroll
  for (int o = 32; o; o >>= 1) s += __shfl_xor(s, o);
  float mu = s * (1.f / NE);
  float q = 0.f;
  for (int i = 0; i < cnt; i++) { float d = v[i] - mu; q += d * d; }
  #pragma unroll
  for (int o = 32; o; o >>= 1) q += __shfl_xor(q, o);
  float inv = rsqrtf(q * (1.f / NE) + 1e-5f);
  __hip_bfloat16* out = h + (size_t)r * KP;
  int i = 0;
  for (int c = lane; c < KP; c += 64, i++) {
    float o = (c < NE) ? (v[i] - mu) * inv * g[c] + b[c] : 0.f;
    out[c] = __float2bfloat16(o);
  }
}

// ---------------- bf16 MFMA GEMM (m97 structure: gload_lds, linear LDS) -----
// A [M x K] bf16 row-major (lda), BT [>=N x K] bf16 row-major (ldb).
// 128x128 tile, 4 waves of 64x64, 16x16x32 MFMA, BK=32.
template <bool RELU, bool RESID, bool BIAS, bool OUTBF>
__global__ __launch_bounds__(256) void k_mgemm(const __hip_bfloat16* __restrict__ A, int lda,
                                               const __hip_bfloat16* __restrict__ BT, int ldb,
                                               const float* __restrict__ bias,
                                               const float* __restrict__ resid,
                                               void* __restrict__ Cout, int ldc,
                                               int N, int K) {
  __shared__ __hip_bfloat16 As[128 * 32];   // linear: gload_lds dest must be unpadded
  __shared__ __hip_bfloat16 Bs[128 * 32];
  const int bm = blockIdx.y * 128, bn = blockIdx.x * 128;
  const int tid = threadIdx.x;
  const int wave = tid >> 6, lane = tid & 63;
  const int wr = (wave >> 1) * 64, wc = (wave & 1) * 64;
  const int l15 = lane & 15, l4 = lane >> 4;
  f32x4 acc[4][4] = {};
  for (int k0 = 0; k0 < K; k0 += 32) {
    #pragma unroll
    for (int q = 0; q < 2; q++) {
      int s = q * 256 + tid;          // 16B slot id; wave-contiguous in LDS
      int row = s >> 2, grp = (s & 3) * 8;
      gload16(A + (size_t)(bm + row) * lda + k0 + grp, &As[s * 8]);
      gload16(BT + (size_t)(bn + row) * ldb + k0 + grp, &Bs[s * 8]);
    }
    __syncthreads();
    bf16x8 af[4], bfr[4];
    #pragma unroll
    for (int m = 0; m < 4; m++)
      af[m] = *(const bf16x8*)&As[(wr + m * 16 + l15) * 32 + l4 * 8];
    #pragma unroll
    for (int n = 0; n < 4; n++)
      bfr[n] = *(const bf16x8*)&Bs[(wc + n * 16 + l15) * 32 + l4 * 8];
    #pragma unroll
    for (int m = 0; m < 4; m++)
      #pragma unroll
      for (int n = 0; n < 4; n++)
        acc[m][n] = __builtin_amdgcn_mfma_f32_16x16x32_bf16(af[m], bfr[n], acc[m][n], 0, 0, 0);
    __syncthreads();
  }
  #pragma unroll
  for (int m = 0; m < 4; m++) {
    #pragma unroll
    for (int n = 0; n < 4; n++) {
      int col = bn + wc + n * 16 + l15;
      if (col < N) {
        float bv = BIAS ? bias[col] : 0.f;
        #pragma unroll
        for (int j = 0; j < 4; j++) {
          int row = bm + wr + m * 16 + l4 * 4 + j;
          float v = acc[m][n][j] + bv;
          if (RELU) v = fmaxf(v, 0.f);
          size_t off = (size_t)row * ldc + col;
          if (RESID) v += resid[off];
          if (OUTBF) ((__hip_bfloat16*)Cout)[off] = __float2bfloat16(v);
          else       ((float*)Cout)[off] = v;
        }
      }
    }
  }
}

// ---------------- MFMA flash attention: one block per (b,h), 4 waves -------
#define KSTRIDE 72    // bf16: 144B rows -> 16B-aligned b128 reads, bank-balanced
#define VSTRIDE 260   // f16: 520B rows -> 8B-aligned b64 reads
__global__ __launch_bounds__(256) void k_attn_mfma(const __hip_bfloat16* __restrict__ qkv,
                                                   __hip_bfloat16* __restrict__ o) {
  __shared__ __hip_bfloat16 Ks[256 * KSTRIDE];   // 36864 B
  __shared__ _Float16      Vt[64 * VSTRIDE];     // 33280 B
  const int bh = blockIdx.x, b = bh >> 2, h = bh & 3;
  const __hip_bfloat16* base = qkv + (size_t)b * TT * 624;
  const int tid = threadIdx.x;
  #pragma unroll
  for (int it = 0; it < 16; it++) {
    int u = it * 256 + tid;
    int t = u >> 4, d4 = (u & 15) * 4;
    s16x4 v = {};
    if (d4 < 52) v = *(const s16x4*)(base + t * 624 + 208 + h * HD + d4);
    *(s16x4*)&Ks[t * KSTRIDE + d4] = v;
  }
  #pragma unroll 4
  for (int it = 0; it < 64; it++) {
    int u = it * 256 + tid;
    int d = u & 63, t = u >> 6;
    float v = (d < 52) ? __bfloat162float(base[t * 624 + 416 + h * HD + d]) : 0.f;
    Vt[d * VSTRIDE + t] = (_Float16)v;
  }
  __syncthreads();

  const int w = tid >> 6, lane = tid & 63, l15 = lane & 15, l4 = lane >> 4;
  const int q0 = w * 64;
  const float scale = 0.06933752453f;  // NE**-0.5 (reference scales by n_embed)
  bf16x8 qf[4][2];
  #pragma unroll
  for (int n = 0; n < 4; n++) {
    const __hip_bfloat16* qrow = base + (q0 + n * 16 + l15) * 624 + h * HD;
    #pragma unroll
    for (int ks = 0; ks < 2; ks++) {
      int s = ks * 32 + l4 * 8;
      union { s16x4 h2[2]; bf16x8 v; } u;
      u.h2[0] = (s <= 48) ? *(const s16x4*)(qrow + s) : (s16x4){};
      u.h2[1] = (s <= 44) ? *(const s16x4*)(qrow + s + 4) : (s16x4){};
      qf[n][ks] = u.v;
    }
  }
  f32x4 oacc[4][4] = {};
  float mrun[4] = {-1e30f, -1e30f, -1e30f, -1e30f};
  float lrun[4] = {0.f, 0.f, 0.f, 0.f};
  const int nch = 4 * (w + 1);
  for (int c = 0; c < nch; c++) {
    const int kb = c * 16;
    const bf16x8 kf0 = *(const bf16x8*)&Ks[(kb + l15) * KSTRIDE + l4 * 8];
    const bf16x8 kf1 = *(const bf16x8*)&Ks[(kb + l15) * KSTRIDE + 32 + l4 * 8];
    #pragma unroll
    for (int n = 0; n < 4; n++) {
      if (kb > q0 + n * 16 + 15) continue;   // tile fully masked (uniform)
      f32x4 s4 = __builtin_amdgcn_mfma_f32_16x16x32_bf16(kf0, qf[n][0],
                                                         (f32x4){0.f, 0.f, 0.f, 0.f}, 0, 0, 0);
      s4 = __builtin_amdgcn_mfma_f32_16x16x32_bf16(kf1, qf[n][1], s4, 0, 0, 0);
      const int q = q0 + n * 16 + l15;
      float pv[4];
      float pmax = -1e30f;
      #pragma unroll
      for (int j = 0; j < 4; j++) {
        int key = kb + l4 * 4 + j;
        float s = s4[j] * scale;
        pv[j] = (key <= q) ? s : -1e30f;
        pmax = fmaxf(pmax, pv[j]);
      }
      pmax = fmaxf(pmax, __shfl_xor(pmax, 16));
      pmax = fmaxf(pmax, __shfl_xor(pmax, 32));
      const float newm = fmaxf(mrun[n], pmax);
      const float r = __expf(mrun[n] - newm);
      float psum = 0.f;
      f16x4 pb;
      #pragma unroll
      for (int j = 0; j < 4; j++) {
        float e = __expf(pv[j] - newm);
        psum += e;
        pb[j] = (_Float16)e;
      }
      psum += __shfl_xor(psum, 16);
      psum += __shfl_xor(psum, 32);
      lrun[n] = lrun[n] * r + psum;
      mrun[n] = newm;
      #pragma unroll
      for (int m = 0; m < 4; m++) {
        oacc[m][n][0] *= r; oacc[m][n][1] *= r;
        oacc[m][n][2] *= r; oacc[m][n][3] *= r;
      }
      #pragma unroll
      for (int m = 0; m < 4; m++) {
        f16x4 vf = *(const f16x4*)&Vt[(m * 16 + l15) * VSTRIDE + kb + l4 * 4];
        oacc[m][n] = __builtin_amdgcn_mfma_f32_16x16x16f16(vf, pb, oacc[m][n], 0, 0, 0);
      }
    }
  }
  #pragma unroll
  for (int n = 0; n < 4; n++) {
    const float inv = 1.f / lrun[n];
    __hip_bfloat16* orow = o + (size_t)(b * TT + q0 + n * 16 + l15) * KP + h * HD;
    #pragma unroll
    for (int m = 0; m < 4; m++)
      #pragma unroll
      for (int j = 0; j < 4; j++) {
        int d = m * 16 + l4 * 4 + j;
        if (d < HD) orow[d] = __float2bfloat16(oacc[m][n][j] * inv);
      }
  }
}

// ---------------- loss: per-row LSE - logit[target] ----------------
__global__ __launch_bounds__(256) void k_loss_rows(const float* __restrict__ logits,
                                                   const int* __restrict__ targets,
                                                   float* __restrict__ row_loss) {
  int r = blockIdx.x * 4 + (threadIdx.x >> 6);
  int lane = threadIdx.x & 63;
  const float* row = logits + (size_t)r * VOCAB;
  float vals[24];
  int cnt = 0;
  float m = -1e30f;
  for (int c = lane; c < VOCAB; c += 64) { float v = row[c]; vals[cnt++] = v; m = fmaxf(m, v); }
  #pragma unroll
  for (int o = 32; o; o >>= 1) m = fmaxf(m, __shfl_xor(m, o));
  float sum = 0.f;
  for (int i = 0; i < cnt; i++) sum += __expf(vals[i] - m);
  #pragma unroll
  for (int o = 32; o; o >>= 1) sum += __shfl_xor(sum, o);
  if (lane == 0) row_loss[r] = (__logf(sum) + m) - row[targets[r]];
}

__global__ __launch_bounds__(256) void k_loss_reduce(const float* __restrict__ row_loss,
                                                     float* __restrict__ out_loss) {
  __shared__ float sh[256];
  float s = 0.f;
  for (int i = threadIdx.x; i < NTOK; i += 256) s += row_loss[i];
  sh[threadIdx.x] = s;
  __syncthreads();
  for (int k = 128; k; k >>= 1) {
    if (threadIdx.x < k) sh[threadIdx.x] += sh[threadIdx.x + k];
    __syncthreads();
  }
  if (threadIdx.x == 0) *out_loss = sh[0] * (1.f / NTOK);
}

extern "C" void kernel_launch(void* const* d_in, const int* in_sizes, int n_in,
                              void* d_out, int out_size, void* d_ws, size_t ws_size,
                              hipStream_t stream) {
  const int*   idx     = (const int*)d_in[0];
  const int*   targets = (const int*)d_in[1];
  const float* tok     = (const float*)d_in[2];
  const float* pos     = (const float*)d_in[3];
  const float* Wq      = (const float*)d_in[4];
  const float* Wk      = (const float*)d_in[5];
  const float* Wv      = (const float*)d_in[6];
  const float* Wo      = (const float*)d_in[7];
  const float* bo      = (const float*)d_in[8];
  const float* ln1g    = (const float*)d_in[9];
  const float* ln1b    = (const float*)d_in[10];
  const float* W1      = (const float*)d_in[11];
  const float* b1      = (const float*)d_in[12];
  const float* W2      = (const float*)d_in[13];
  const float* b2      = (const float*)d_in[14];
  const float* ln2g    = (const float*)d_in[15];
  const float* ln2b    = (const float*)d_in[16];
  const float* lnfg    = (const float*)d_in[17];
  const float* lnfb    = (const float*)d_in[18];
  const float* Wlm     = (const float*)d_in[19];
  const float* blm     = (const float*)d_in[20];
  float* out = (float*)d_out;

  char* w = (char*)d_ws;
  float* x = (float*)w;                    w += (size_t)NTOK * NE * 4;
  __hip_bfloat16* qkv = (__hip_bfloat16*)w; w += (size_t)NTOK * 624 * 2;
  __hip_bfloat16* hbf = (__hip_bfloat16*)w; w += (size_t)NTOK * KP * 2;
  __hip_bfloat16* act = (__hip_bfloat16*)w; w += (size_t)NTOK * 832 * 2;
  __hip_bfloat16* WqkvT = (__hip_bfloat16*)w; w += (size_t)NL * 640 * KP * 2;
  __hip_bfloat16* WoT   = (__hip_bfloat16*)w; w += (size_t)NL * 256 * KP * 2;
  __hip_bfloat16* W1T   = (__hip_bfloat16*)w; w += (size_t)NL * 896 * KP * 2;
  __hip_bfloat16* W2T   = (__hip_bfloat16*)w; w += (size_t)NL * 256 * 832 * 2;
  __hip_bfloat16* WlmT  = (__hip_bfloat16*)w; w += (size_t)1536 * KP * 2;
  float* row_loss = (float*)w;

  k_prep_qkvT<<<NL * 640 * KP / 256, 256, 0, stream>>>(Wq, Wk, Wv, WqkvT);
  k_prep_oT<<<NL * 256 * KP / 256, 256, 0, stream>>>(Wo, WoT);
  k_prep_1T<<<NL * 896 * KP / 256, 256, 0, stream>>>(W1, W1T);
  k_prep_2T<<<NL * 256 * 832 / 256, 256, 0, stream>>>(W2, W2T);
  k_prep_lmT<<<1536 * KP / 256, 256, 0, stream>>>(Wlm, WlmT);
  k_embed<<<NTOK * NE / 256, 256, 0, stream>>>(idx, tok, pos, x);

  for (int l = 0; l < NL; l++) {
    k_ln_bf<<<NTOK / 4, 256, 0, stream>>>(x, ln1g + l * NE, ln1b + l * NE, hbf);
    k_mgemm<false, false, false, true><<<dim3(5, 512), 256, 0, stream>>>(
        hbf, KP, WqkvT + (size_t)l * 640 * KP, KP, nullptr, nullptr, qkv, 624, 624, KP);
    k_attn_mfma<<<BBATCH * NHD, 256, 0, stream>>>(qkv, hbf);
    k_mgemm<false, true, true, false><<<dim3(2, 512), 256, 0, stream>>>(
        hbf, KP, WoT + (size_t)l * 256 * KP, KP, bo + l * NE, x, x, NE, NE, KP);
    k_ln_bf<<<NTOK / 4, 256, 0, stream>>>(x, ln2g + l * NE, ln2b + l * NE, hbf);
    k_mgemm<true, false, true, true><<<dim3(7, 512), 256, 0, stream>>>(
        hbf, KP, W1T + (size_t)l * 896 * KP, KP, b1 + l * 832, nullptr, act, 832, 832, KP);
    k_mgemm<false, true, true, false><<<dim3(2, 512), 256, 0, stream>>>(
        act, 832, W2T + (size_t)l * 256 * 832, 832, b2 + l * NE, x, x, NE, NE, 832);
  }

  k_ln_bf<<<NTOK / 4, 256, 0, stream>>>(x, lnfg, lnfb, hbf);
  k_mgemm<false, false, true, false><<<dim3(12, 512), 256, 0, stream>>>(
      hbf, KP, WlmT, KP, blm, nullptr, out, VOCAB, VOCAB, KP);

  k_loss_rows<<<NTOK / 4, 256, 0, stream>>>(out, targets, row_loss);
  k_loss_reduce<<<1, 256, 0, stream>>>(row_loss, out + ((size_t)out_size - 1));
}

// Round 5
// 3219.871 us; speedup vs baseline: 4.2286x; 1.1586x over previous
//
#include <hip/hip_runtime.h>
#include <hip/hip_bf16.h>
#include <math.h>

#define VOCAB 1500
#define NE    208
#define TT    256
#define NHD   4
#define HD    52
#define NL    8
#define BBATCH 256
#define NTOK  (BBATCH * TT)   // 65536
#define KP    224             // NE padded to multiple of 32

typedef __attribute__((ext_vector_type(8))) short bf16x8;
typedef __attribute__((ext_vector_type(4))) short s16x4;
typedef __attribute__((ext_vector_type(4))) float f32x4;
typedef __attribute__((ext_vector_type(4))) int i32x4;
typedef __attribute__((ext_vector_type(4))) _Float16 f16x4;

__device__ __forceinline__ void gload16(const void* g, void* l) {
  __builtin_amdgcn_global_load_lds(
      (const __attribute__((address_space(1))) unsigned int*)g,
      (__attribute__((address_space(3))) unsigned int*)l, 16, 0, 0);
}

// ---------------- embedding: x = tok_emb[idx] + pos_emb (bf16 out) ---------
__global__ __launch_bounds__(256) void k_embed(const int* __restrict__ idx,
                                               const float* __restrict__ tok,
                                               const float* __restrict__ pos,
                                               __hip_bfloat16* __restrict__ x) {
  int i = blockIdx.x * 256 + threadIdx.x;          // over NTOK*NE, exact grid
  int n = i / NE, c = i - n * NE;
  int t = n & (TT - 1);
  x[i] = __float2bfloat16(tok[idx[n] * NE + c] + pos[t * NE + c]);
}

// ---------- weight prep: transposed + K-padded bf16 copies ----------
__global__ __launch_bounds__(256) void k_prep_qkvT(const float* __restrict__ Wq,
                                                   const float* __restrict__ Wk,
                                                   const float* __restrict__ Wv,
                                                   __hip_bfloat16* __restrict__ o) {
  int i = blockIdx.x * 256 + threadIdx.x;          // NL*640*224 exact
  int c = i % KP;
  int jl = i / KP;
  int j = jl % 640, l = jl / 640;
  float v = 0.f;
  if (j < 624 && c < NE) {
    int sel = j / NE, hd = j - sel * NE;
    int h = hd / HD, d = hd - h * HD;
    const float* W = (sel == 0) ? Wq : (sel == 1) ? Wk : Wv;
    v = W[(((size_t)l * NHD + h) * NE + c) * HD + d];
  }
  o[i] = __float2bfloat16(v);
}

__global__ __launch_bounds__(256) void k_prep_oT(const float* __restrict__ Wo,
                                                 __hip_bfloat16* __restrict__ o) {
  int i = blockIdx.x * 256 + threadIdx.x;          // NL*256*224 exact
  int c = i % KP;
  int jl = i / KP;
  int j = jl % 256, l = jl / 256;
  float v = (j < NE && c < NE) ? Wo[((size_t)l * NE + c) * NE + j] : 0.f;
  o[i] = __float2bfloat16(v);
}

__global__ __launch_bounds__(256) void k_prep_1T(const float* __restrict__ W1,
                                                 __hip_bfloat16* __restrict__ o) {
  int i = blockIdx.x * 256 + threadIdx.x;          // NL*896*224 exact
  int c = i % KP;
  int jl = i / KP;
  int j = jl % 896, l = jl / 896;
  float v = (j < 832 && c < NE) ? W1[((size_t)l * NE + c) * 832 + j] : 0.f;
  o[i] = __float2bfloat16(v);
}

__global__ __launch_bounds__(256) void k_prep_2T(const float* __restrict__ W2,
                                                 __hip_bfloat16* __restrict__ o) {
  int i = blockIdx.x * 256 + threadIdx.x;          // NL*256*832 exact
  int c = i % 832;
  int jl = i / 832;
  int j = jl % 256, l = jl / 256;
  float v = (j < NE) ? W2[((size_t)l * 832 + c) * NE + j] : 0.f;
  o[i] = __float2bfloat16(v);
}

__global__ __launch_bounds__(256) void k_prep_lmT(const float* __restrict__ Wlm,
                                                  __hip_bfloat16* __restrict__ o) {
  int i = blockIdx.x * 256 + threadIdx.x;          // 1536*224 exact
  int c = i % KP;
  int j = i / KP;
  float v = (j < VOCAB && c < NE) ? Wlm[(size_t)c * VOCAB + j] : 0.f;
  o[i] = __float2bfloat16(v);
}

// ------- layernorm: bf16 in (ld 208), bf16 out (ld 224, pads=0), 1 wave/row -
__global__ __launch_bounds__(256) void k_ln_bf(const __hip_bfloat16* __restrict__ x,
                                               const float* __restrict__ g,
                                               const float* __restrict__ b,
                                               __hip_bfloat16* __restrict__ h) {
  int r = blockIdx.x * 4 + (threadIdx.x >> 6);
  int lane = threadIdx.x & 63;
  const int c0 = lane * 4;
  float v[4] = {0.f, 0.f, 0.f, 0.f};
  float s = 0.f;
  if (lane < 52) {
    s16x4 raw = *(const s16x4*)(x + (size_t)r * NE + c0);
    #pragma unroll
    for (int i = 0; i < 4; i++) {
      union { unsigned int u; float f; } cv;
      cv.u = ((unsigned int)(unsigned short)raw[i]) << 16;
      v[i] = cv.f;
      s += cv.f;
    }
  }
  #pragma unroll
  for (int o = 32; o; o >>= 1) s += __shfl_xor(s, o);
  float mu = s * (1.f / NE);
  float q = 0.f;
  if (lane < 52) {
    #pragma unroll
    for (int i = 0; i < 4; i++) { float d = v[i] - mu; q += d * d; }
  }
  #pragma unroll
  for (int o = 32; o; o >>= 1) q += __shfl_xor(q, o);
  float inv = rsqrtf(q * (1.f / NE) + 1e-5f);
  if (lane < 56) {
    s16x4 outv = {};
    if (lane < 52) {
      #pragma unroll
      for (int i = 0; i < 4; i++) {
        float o = (v[i] - mu) * inv * g[c0 + i] + b[c0 + i];
        outv[i] = (short)__bfloat16_as_ushort(__float2bfloat16(o));
      }
    }
    *(s16x4*)(h + (size_t)r * KP + c0) = outv;
  }
}

// ------- bf16 MFMA GEMM, 2-phase double-buffered prefetch (T3-minimum) -----
// A [M x K] bf16 row-major (lda), BT [>=N x K] bf16 row-major (ldb).
// 128x128 tile, 4 waves of 64x64, 16x16x32 MFMA, BK=32.
template <bool RELU, bool RESID, bool BIAS, bool OUTBF>
__global__ __launch_bounds__(256) void k_mgemm(const __hip_bfloat16* __restrict__ A, int lda,
                                               const __hip_bfloat16* __restrict__ BT, int ldb,
                                               const float* __restrict__ bias,
                                               const __hip_bfloat16* __restrict__ resid,
                                               void* __restrict__ Cout, int ldc,
                                               int N, int K) {
  __shared__ __hip_bfloat16 As[2][128 * 32];   // linear: gload_lds dest constraint
  __shared__ __hip_bfloat16 Bs[2][128 * 32];
  const int bm = blockIdx.y * 128, bn = blockIdx.x * 128;
  const int tid = threadIdx.x;
  const int wave = tid >> 6, lane = tid & 63;
  const int wr = (wave >> 1) * 64, wc = (wave & 1) * 64;
  const int l15 = lane & 15, l4 = lane >> 4;
  const int srow = tid >> 2, sgrp = (tid & 3) * 8;      // 16B slot per thread
  const int srow2 = srow + 64;
  f32x4 acc[4][4] = {};
  const int nt = K / 32;
  // prologue: stage tile 0 into buf 0
  {
    gload16(A + (size_t)(bm + srow) * lda + sgrp, &As[0][tid * 8]);
    gload16(BT + (size_t)(bn + srow) * ldb + sgrp, &Bs[0][tid * 8]);
    gload16(A + (size_t)(bm + srow2) * lda + sgrp, &As[0][(256 + tid) * 8]);
    gload16(BT + (size_t)(bn + srow2) * ldb + sgrp, &Bs[0][(256 + tid) * 8]);
  }
  __syncthreads();
  int cur = 0;
  for (int t = 0; t < nt; t++) {
    if (t + 1 < nt) {            // issue next-tile prefetch BEFORE compute
      int k1 = (t + 1) * 32;
      gload16(A + (size_t)(bm + srow) * lda + k1 + sgrp, &As[cur ^ 1][tid * 8]);
      gload16(BT + (size_t)(bn + srow) * ldb + k1 + sgrp, &Bs[cur ^ 1][tid * 8]);
      gload16(A + (size_t)(bm + srow2) * lda + k1 + sgrp, &As[cur ^ 1][(256 + tid) * 8]);
      gload16(BT + (size_t)(bn + srow2) * ldb + k1 + sgrp, &Bs[cur ^ 1][(256 + tid) * 8]);
    }
    bf16x8 af[4], bfr[4];
    #pragma unroll
    for (int m = 0; m < 4; m++)
      af[m] = *(const bf16x8*)&As[cur][(wr + m * 16 + l15) * 32 + l4 * 8];
    #pragma unroll
    for (int n = 0; n < 4; n++)
      bfr[n] = *(const bf16x8*)&Bs[cur][(wc + n * 16 + l15) * 32 + l4 * 8];
    #pragma unroll
    for (int m = 0; m < 4; m++)
      #pragma unroll
      for (int n = 0; n < 4; n++)
        acc[m][n] = __builtin_amdgcn_mfma_f32_16x16x32_bf16(af[m], bfr[n], acc[m][n], 0, 0, 0);
    if (t + 1 < nt) __syncthreads();   // drains prefetch vmcnt + lds reads
    cur ^= 1;
  }
  #pragma unroll
  for (int m = 0; m < 4; m++) {
    #pragma unroll
    for (int n = 0; n < 4; n++) {
      int col = bn + wc + n * 16 + l15;
      if (col < N) {
        float bv = BIAS ? bias[col] : 0.f;
        #pragma unroll
        for (int j = 0; j < 4; j++) {
          int row = bm + wr + m * 16 + l4 * 4 + j;
          float v = acc[m][n][j] + bv;
          if (RELU) v = fmaxf(v, 0.f);
          size_t off = (size_t)row * ldc + col;
          if (RESID) v += __bfloat162float(resid[off]);
          if (OUTBF) ((__hip_bfloat16*)Cout)[off] = __float2bfloat16(v);
          else       ((float*)Cout)[off] = v;
        }
      }
    }
  }
}

// ---------------- MFMA flash attention: one block per (b,h), 4 waves -------
#define KSTRIDE 72    // bf16: 144B rows -> 16B-aligned b128 reads, bank-balanced
#define VSTRIDE 260   // f16: 520B rows -> 8B-aligned b64 reads
__global__ __launch_bounds__(256) void k_attn_mfma(const __hip_bfloat16* __restrict__ qkv,
                                                   __hip_bfloat16* __restrict__ o) {
  __shared__ __hip_bfloat16 Ks[256 * KSTRIDE];   // 36864 B
  __shared__ _Float16      Vt[64 * VSTRIDE];     // 33280 B
  const int bh = blockIdx.x, b = bh >> 2, h = bh & 3;
  const __hip_bfloat16* base = qkv + (size_t)b * TT * 624;
  const int tid = threadIdx.x;
  #pragma unroll
  for (int it = 0; it < 16; it++) {
    int u = it * 256 + tid;
    int t = u >> 4, d4 = (u & 15) * 4;
    s16x4 v = {};
    if (d4 < 52) v = *(const s16x4*)(base + t * 624 + 208 + h * HD + d4);
    *(s16x4*)&Ks[t * KSTRIDE + d4] = v;
  }
  #pragma unroll 4
  for (int it = 0; it < 64; it++) {
    int u = it * 256 + tid;
    int d = u & 63, t = u >> 6;
    float v = (d < 52) ? __bfloat162float(base[t * 624 + 416 + h * HD + d]) : 0.f;
    Vt[d * VSTRIDE + t] = (_Float16)v;
  }
  __syncthreads();

  const int w = tid >> 6, lane = tid & 63, l15 = lane & 15, l4 = lane >> 4;
  const int q0 = w * 64;
  const float scale = 0.06933752453f;  // NE**-0.5 (reference scales by n_embed)
  bf16x8 qf[4][2];
  #pragma unroll
  for (int n = 0; n < 4; n++) {
    const __hip_bfloat16* qrow = base + (q0 + n * 16 + l15) * 624 + h * HD;
    #pragma unroll
    for (int ks = 0; ks < 2; ks++) {
      int s = ks * 32 + l4 * 8;
      union { s16x4 h2[2]; bf16x8 v; } u;
      u.h2[0] = (s <= 48) ? *(const s16x4*)(qrow + s) : (s16x4){};
      u.h2[1] = (s <= 44) ? *(const s16x4*)(qrow + s + 4) : (s16x4){};
      qf[n][ks] = u.v;
    }
  }
  f32x4 oacc[4][4] = {};
  float mrun[4] = {-1e30f, -1e30f, -1e30f, -1e30f};
  float lrun[4] = {0.f, 0.f, 0.f, 0.f};
  const int nch = 4 * (w + 1);
  for (int c = 0; c < nch; c++) {
    const int kb = c * 16;
    const bf16x8 kf0 = *(const bf16x8*)&Ks[(kb + l15) * KSTRIDE + l4 * 8];
    const bf16x8 kf1 = *(const bf16x8*)&Ks[(kb + l15) * KSTRIDE + 32 + l4 * 8];
    #pragma unroll
    for (int n = 0; n < 4; n++) {
      if (kb > q0 + n * 16 + 15) continue;   // tile fully masked (uniform)
      f32x4 s4 = __builtin_amdgcn_mfma_f32_16x16x32_bf16(kf0, qf[n][0],
                                                         (f32x4){0.f, 0.f, 0.f, 0.f}, 0, 0, 0);
      s4 = __builtin_amdgcn_mfma_f32_16x16x32_bf16(kf1, qf[n][1], s4, 0, 0, 0);
      const int q = q0 + n * 16 + l15;
      float pv[4];
      float pmax = -1e30f;
      #pragma unroll
      for (int j = 0; j < 4; j++) {
        int key = kb + l4 * 4 + j;
        float s = s4[j] * scale;
        pv[j] = (key <= q) ? s : -1e30f;
        pmax = fmaxf(pmax, pv[j]);
      }
      pmax = fmaxf(pmax, __shfl_xor(pmax, 16));
      pmax = fmaxf(pmax, __shfl_xor(pmax, 32));
      const float newm = fmaxf(mrun[n], pmax);
      const float r = __expf(mrun[n] - newm);
      float psum = 0.f;
      f16x4 pb;
      #pragma unroll
      for (int j = 0; j < 4; j++) {
        float e = __expf(pv[j] - newm);
        psum += e;
        pb[j] = (_Float16)e;
      }
      psum += __shfl_xor(psum, 16);
      psum += __shfl_xor(psum, 32);
      lrun[n] = lrun[n] * r + psum;
      mrun[n] = newm;
      #pragma unroll
      for (int m = 0; m < 4; m++) {
        oacc[m][n][0] *= r; oacc[m][n][1] *= r;
        oacc[m][n][2] *= r; oacc[m][n][3] *= r;
      }
      #pragma unroll
      for (int m = 0; m < 4; m++) {
        f16x4 vf = *(const f16x4*)&Vt[(m * 16 + l15) * VSTRIDE + kb + l4 * 4];
        oacc[m][n] = __builtin_amdgcn_mfma_f32_16x16x16f16(vf, pb, oacc[m][n], 0, 0, 0);
      }
    }
  }
  #pragma unroll
  for (int n = 0; n < 4; n++) {
    const float inv = 1.f / lrun[n];
    __hip_bfloat16* orow = o + (size_t)(b * TT + q0 + n * 16 + l15) * KP + h * HD;
    #pragma unroll
    for (int m = 0; m < 4; m++)
      #pragma unroll
      for (int j = 0; j < 4; j++) {
        int d = m * 16 + l4 * 4 + j;
        if (d < HD) orow[d] = __float2bfloat16(oacc[m][n][j] * inv);
      }
  }
}

// ---------------- loss: per-row LSE - logit[target] ----------------
__global__ __launch_bounds__(256) void k_loss_rows(const float* __restrict__ logits,
                                                   const int* __restrict__ targets,
                                                   float* __restrict__ row_loss) {
  int r = blockIdx.x * 4 + (threadIdx.x >> 6);
  int lane = threadIdx.x & 63;
  const float* row = logits + (size_t)r * VOCAB;
  float vals[24];
  int cnt = 0;
  float m = -1e30f;
  for (int c = lane * 4; c < VOCAB; c += 256) {   // 1500 % 4 == 0: exact float4s
    float4 v = *(const float4*)(row + c);
    vals[cnt++] = v.x; vals[cnt++] = v.y; vals[cnt++] = v.z; vals[cnt++] = v.w;
    m = fmaxf(m, fmaxf(fmaxf(v.x, v.y), fmaxf(v.z, v.w)));
  }
  #pragma unroll
  for (int o = 32; o; o >>= 1) m = fmaxf(m, __shfl_xor(m, o));
  float sum = 0.f;
  for (int i = 0; i < cnt; i++) sum += __expf(vals[i] - m);
  #pragma unroll
  for (int o = 32; o; o >>= 1) sum += __shfl_xor(sum, o);
  if (lane == 0) row_loss[r] = (__logf(sum) + m) - row[targets[r]];
}

__global__ __launch_bounds__(256) void k_loss_reduce(const float* __restrict__ row_loss,
                                                     float* __restrict__ out_loss) {
  __shared__ float sh[256];
  float s = 0.f;
  for (int i = threadIdx.x; i < NTOK; i += 256) s += row_loss[i];
  sh[threadIdx.x] = s;
  __syncthreads();
  for (int k = 128; k; k >>= 1) {
    if (threadIdx.x < k) sh[threadIdx.x] += sh[threadIdx.x + k];
    __syncthreads();
  }
  if (threadIdx.x == 0) *out_loss = sh[0] * (1.f / NTOK);
}

extern "C" void kernel_launch(void* const* d_in, const int* in_sizes, int n_in,
                              void* d_out, int out_size, void* d_ws, size_t ws_size,
                              hipStream_t stream) {
  const int*   idx     = (const int*)d_in[0];
  const int*   targets = (const int*)d_in[1];
  const float* tok     = (const float*)d_in[2];
  const float* pos     = (const float*)d_in[3];
  const float* Wq      = (const float*)d_in[4];
  const float* Wk      = (const float*)d_in[5];
  const float* Wv      = (const float*)d_in[6];
  const float* Wo      = (const float*)d_in[7];
  const float* bo      = (const float*)d_in[8];
  const float* ln1g    = (const float*)d_in[9];
  const float* ln1b    = (const float*)d_in[10];
  const float* W1      = (const float*)d_in[11];
  const float* b1      = (const float*)d_in[12];
  const float* W2      = (const float*)d_in[13];
  const float* b2      = (const float*)d_in[14];
  const float* ln2g    = (const float*)d_in[15];
  const float* ln2b    = (const float*)d_in[16];
  const float* lnfg    = (const float*)d_in[17];
  const float* lnfb    = (const float*)d_in[18];
  const float* Wlm     = (const float*)d_in[19];
  const float* blm     = (const float*)d_in[20];
  float* out = (float*)d_out;

  char* w = (char*)d_ws;
  __hip_bfloat16* x   = (__hip_bfloat16*)w; w += (size_t)NTOK * NE * 2;
  __hip_bfloat16* qkv = (__hip_bfloat16*)w; w += (size_t)NTOK * 624 * 2;
  __hip_bfloat16* hbf = (__hip_bfloat16*)w; w += (size_t)NTOK * KP * 2;
  __hip_bfloat16* act = (__hip_bfloat16*)w; w += (size_t)NTOK * 832 * 2;
  __hip_bfloat16* WqkvT = (__hip_bfloat16*)w; w += (size_t)NL * 640 * KP * 2;
  __hip_bfloat16* WoT   = (__hip_bfloat16*)w; w += (size_t)NL * 256 * KP * 2;
  __hip_bfloat16* W1T   = (__hip_bfloat16*)w; w += (size_t)NL * 896 * KP * 2;
  __hip_bfloat16* W2T   = (__hip_bfloat16*)w; w += (size_t)NL * 256 * 832 * 2;
  __hip_bfloat16* WlmT  = (__hip_bfloat16*)w; w += (size_t)1536 * KP * 2;
  float* row_loss = (float*)w;

  k_prep_qkvT<<<NL * 640 * KP / 256, 256, 0, stream>>>(Wq, Wk, Wv, WqkvT);
  k_prep_oT<<<NL * 256 * KP / 256, 256, 0, stream>>>(Wo, WoT);
  k_prep_1T<<<NL * 896 * KP / 256, 256, 0, stream>>>(W1, W1T);
  k_prep_2T<<<NL * 256 * 832 / 256, 256, 0, stream>>>(W2, W2T);
  k_prep_lmT<<<1536 * KP / 256, 256, 0, stream>>>(Wlm, WlmT);
  k_embed<<<NTOK * NE / 256, 256, 0, stream>>>(idx, tok, pos, x);

  for (int l = 0; l < NL; l++) {
    k_ln_bf<<<NTOK / 4, 256, 0, stream>>>(x, ln1g + l * NE, ln1b + l * NE, hbf);
    k_mgemm<false, false, false, true><<<dim3(5, 512), 256, 0, stream>>>(
        hbf, KP, WqkvT + (size_t)l * 640 * KP, KP, nullptr, nullptr, qkv, 624, 624, KP);
    k_attn_mfma<<<BBATCH * NHD, 256, 0, stream>>>(qkv, hbf);
    k_mgemm<false, true, true, true><<<dim3(2, 512), 256, 0, stream>>>(
        hbf, KP, WoT + (size_t)l * 256 * KP, KP, bo + l * NE, x, x, NE, NE, KP);
    k_ln_bf<<<NTOK / 4, 256, 0, stream>>>(x, ln2g + l * NE, ln2b + l * NE, hbf);
    k_mgemm<true, false, true, true><<<dim3(7, 512), 256, 0, stream>>>(
        hbf, KP, W1T + (size_t)l * 896 * KP, KP, b1 + l * 832, nullptr, act, 832, 832, KP);
    k_mgemm<false, true, true, true><<<dim3(2, 512), 256, 0, stream>>>(
        act, 832, W2T + (size_t)l * 256 * 832, 832, b2 + l * NE, x, x, NE, NE, 832);
  }

  k_ln_bf<<<NTOK / 4, 256, 0, stream>>>(x, lnfg, lnfb, hbf);
  k_mgemm<false, false, true, false><<<dim3(12, 512), 256, 0, stream>>>(
      hbf, KP, WlmT, KP, blm, nullptr, out, VOCAB, VOCAB, KP);

  k_loss_rows<<<NTOK / 4, 256, 0, stream>>>(out, targets, row_loss);
  k_loss_reduce<<<1, 256, 0, stream>>>(row_loss, out + ((size_t)out_size - 1));
}

// Round 6
// 3207.968 us; speedup vs baseline: 4.2443x; 1.0037x over previous
//
#include <hip/hip_runtime.h>
#include <hip/hip_bf16.h>
#include <math.h>

#define VOCAB 1500
#define NE    208
#define TT    256
#define NHD   4
#define HD    52
#define NL    8
#define BBATCH 256
#define NTOK  (BBATCH * TT)   // 65536
#define KP    224             // NE padded to multiple of 32

typedef __attribute__((ext_vector_type(8))) short bf16x8;
typedef __attribute__((ext_vector_type(4))) short s16x4;
typedef __attribute__((ext_vector_type(4))) float f32x4;
typedef __attribute__((ext_vector_type(4))) int i32x4;
typedef __attribute__((ext_vector_type(4))) _Float16 f16x4;

__device__ __forceinline__ void gload16(const void* g, void* l) {
  __builtin_amdgcn_global_load_lds(
      (const __attribute__((address_space(1))) unsigned int*)g,
      (__attribute__((address_space(3))) unsigned int*)l, 16, 0, 0);
}

// ---------------- embedding: x = tok_emb[idx] + pos_emb (bf16 out) ---------
__global__ __launch_bounds__(256) void k_embed(const int* __restrict__ idx,
                                               const float* __restrict__ tok,
                                               const float* __restrict__ pos,
                                               __hip_bfloat16* __restrict__ x) {
  int i = blockIdx.x * 256 + threadIdx.x;          // over NTOK*NE, exact grid
  int n = i / NE, c = i - n * NE;
  int t = n & (TT - 1);
  x[i] = __float2bfloat16(tok[idx[n] * NE + c] + pos[t * NE + c]);
}

// ---------- weight prep: transposed + K-padded bf16 copies ----------
__global__ __launch_bounds__(256) void k_prep_qkvT(const float* __restrict__ Wq,
                                                   const float* __restrict__ Wk,
                                                   const float* __restrict__ Wv,
                                                   __hip_bfloat16* __restrict__ o) {
  int i = blockIdx.x * 256 + threadIdx.x;          // NL*640*224 exact
  int c = i % KP;
  int jl = i / KP;
  int j = jl % 640, l = jl / 640;
  float v = 0.f;
  if (j < 624 && c < NE) {
    int sel = j / NE, hd = j - sel * NE;
    int h = hd / HD, d = hd - h * HD;
    const float* W = (sel == 0) ? Wq : (sel == 1) ? Wk : Wv;
    v = W[(((size_t)l * NHD + h) * NE + c) * HD + d];
  }
  o[i] = __float2bfloat16(v);
}

__global__ __launch_bounds__(256) void k_prep_oT(const float* __restrict__ Wo,
                                                 __hip_bfloat16* __restrict__ o) {
  int i = blockIdx.x * 256 + threadIdx.x;          // NL*256*224 exact
  int c = i % KP;
  int jl = i / KP;
  int j = jl % 256, l = jl / 256;
  float v = (j < NE && c < NE) ? Wo[((size_t)l * NE + c) * NE + j] : 0.f;
  o[i] = __float2bfloat16(v);
}

__global__ __launch_bounds__(256) void k_prep_1T(const float* __restrict__ W1,
                                                 __hip_bfloat16* __restrict__ o) {
  int i = blockIdx.x * 256 + threadIdx.x;          // NL*896*224 exact
  int c = i % KP;
  int jl = i / KP;
  int j = jl % 896, l = jl / 896;
  float v = (j < 832 && c < NE) ? W1[((size_t)l * NE + c) * 832 + j] : 0.f;
  o[i] = __float2bfloat16(v);
}

__global__ __launch_bounds__(256) void k_prep_2T(const float* __restrict__ W2,
                                                 __hip_bfloat16* __restrict__ o) {
  int i = blockIdx.x * 256 + threadIdx.x;          // NL*256*832 exact
  int c = i % 832;
  int jl = i / 832;
  int j = jl % 256, l = jl / 256;
  float v = (j < NE) ? W2[((size_t)l * 832 + c) * NE + j] : 0.f;
  o[i] = __float2bfloat16(v);
}

__global__ __launch_bounds__(256) void k_prep_lmT(const float* __restrict__ Wlm,
                                                  __hip_bfloat16* __restrict__ o) {
  int i = blockIdx.x * 256 + threadIdx.x;          // 1536*224 exact
  int c = i % KP;
  int j = i / KP;
  float v = (j < VOCAB && c < NE) ? Wlm[(size_t)c * VOCAB + j] : 0.f;
  o[i] = __float2bfloat16(v);
}

// ------- layernorm: bf16 in (ld 208), bf16 out (ld 224, pads=0), 1 wave/row -
__global__ __launch_bounds__(256) void k_ln_bf(const __hip_bfloat16* __restrict__ x,
                                               const float* __restrict__ g,
                                               const float* __restrict__ b,
                                               __hip_bfloat16* __restrict__ h) {
  int r = blockIdx.x * 4 + (threadIdx.x >> 6);
  int lane = threadIdx.x & 63;
  const int c0 = lane * 4;
  float v[4] = {0.f, 0.f, 0.f, 0.f};
  float s = 0.f;
  if (lane < 52) {
    s16x4 raw = *(const s16x4*)(x + (size_t)r * NE + c0);
    #pragma unroll
    for (int i = 0; i < 4; i++) {
      union { unsigned int u; float f; } cv;
      cv.u = ((unsigned int)(unsigned short)raw[i]) << 16;
      v[i] = cv.f;
      s += cv.f;
    }
  }
  #pragma unroll
  for (int o = 32; o; o >>= 1) s += __shfl_xor(s, o);
  float mu = s * (1.f / NE);
  float q = 0.f;
  if (lane < 52) {
    #pragma unroll
    for (int i = 0; i < 4; i++) { float d = v[i] - mu; q += d * d; }
  }
  #pragma unroll
  for (int o = 32; o; o >>= 1) q += __shfl_xor(q, o);
  float inv = rsqrtf(q * (1.f / NE) + 1e-5f);
  if (lane < 56) {
    s16x4 outv = {};
    if (lane < 52) {
      #pragma unroll
      for (int i = 0; i < 4; i++) {
        float o = (v[i] - mu) * inv * g[c0 + i] + b[c0 + i];
        outv[i] = (short)__bfloat16_as_ushort(__float2bfloat16(o));
      }
    }
    *(s16x4*)(h + (size_t)r * KP + c0) = outv;
  }
}

// ------- bf16 MFMA GEMM: dbuf + counted vmcnt + raw barriers (T4) ----------
// A [M x K] bf16 row-major (lda), BT [>=N x K] bf16 row-major (ldb).
// 128x128 tile, 4 waves of 64x64, 16x16x32 MFMA, BK=32.
// Per K-step: issue prefetch(t+1) -> vmcnt(4) waits ONLY tile t's 4 loads
// (prefetch stays in flight across the barrier) -> s_barrier -> ds_read+MFMA
// (compiler inserts lgkmcnt) -> s_barrier (reads done before DMA overwrites).
template <bool RELU, bool RESID, bool BIAS, bool OUTBF>
__global__ __launch_bounds__(256) void k_mgemm(const __hip_bfloat16* __restrict__ A, int lda,
                                               const __hip_bfloat16* __restrict__ BT, int ldb,
                                               const float* __restrict__ bias,
                                               const __hip_bfloat16* __restrict__ resid,
                                               void* __restrict__ Cout, int ldc,
                                               int N, int K) {
  __shared__ __hip_bfloat16 As[2][128 * 32];   // linear: gload_lds dest constraint
  __shared__ __hip_bfloat16 Bs[2][128 * 32];
  const int bm = blockIdx.y * 128, bn = blockIdx.x * 128;
  const int tid = threadIdx.x;
  const int wave = tid >> 6, lane = tid & 63;
  const int wr = (wave >> 1) * 64, wc = (wave & 1) * 64;
  const int l15 = lane & 15, l4 = lane >> 4;
  const int srow = tid >> 2, sgrp = (tid & 3) * 8;      // 16B slot per thread
  const int srow2 = srow + 64;
  f32x4 acc[4][4] = {};
  const int nt = K / 32;
  // prologue: stage tile 0 into buf 0 (4 loads/thread)
  gload16(A + (size_t)(bm + srow) * lda + sgrp, &As[0][tid * 8]);
  gload16(BT + (size_t)(bn + srow) * ldb + sgrp, &Bs[0][tid * 8]);
  gload16(A + (size_t)(bm + srow2) * lda + sgrp, &As[0][(256 + tid) * 8]);
  gload16(BT + (size_t)(bn + srow2) * ldb + sgrp, &Bs[0][(256 + tid) * 8]);
  int cur = 0;
  for (int t = 0; t < nt; t++) {
    if (t + 1 < nt) {            // prefetch next tile; stays in flight past barrier
      int k1 = (t + 1) * 32;
      gload16(A + (size_t)(bm + srow) * lda + k1 + sgrp, &As[cur ^ 1][tid * 8]);
      gload16(BT + (size_t)(bn + srow) * ldb + k1 + sgrp, &Bs[cur ^ 1][tid * 8]);
      gload16(A + (size_t)(bm + srow2) * lda + k1 + sgrp, &As[cur ^ 1][(256 + tid) * 8]);
      gload16(BT + (size_t)(bn + srow2) * ldb + k1 + sgrp, &Bs[cur ^ 1][(256 + tid) * 8]);
      asm volatile("s_waitcnt vmcnt(4)" ::: "memory");   // only tile t's loads
    } else {
      asm volatile("s_waitcnt vmcnt(0)" ::: "memory");
    }
    __builtin_amdgcn_s_barrier();
    bf16x8 af[4], bfr[4];
    #pragma unroll
    for (int m = 0; m < 4; m++)
      af[m] = *(const bf16x8*)&As[cur][(wr + m * 16 + l15) * 32 + l4 * 8];
    #pragma unroll
    for (int n = 0; n < 4; n++)
      bfr[n] = *(const bf16x8*)&Bs[cur][(wc + n * 16 + l15) * 32 + l4 * 8];
    #pragma unroll
    for (int m = 0; m < 4; m++)
      #pragma unroll
      for (int n = 0; n < 4; n++)
        acc[m][n] = __builtin_amdgcn_mfma_f32_16x16x32_bf16(af[m], bfr[n], acc[m][n], 0, 0, 0);
    if (t + 1 < nt) __builtin_amdgcn_s_barrier();  // reads of buf[cur] done before
    cur ^= 1;                                      // next iter's DMA overwrites it
  }
  #pragma unroll
  for (int m = 0; m < 4; m++) {
    #pragma unroll
    for (int n = 0; n < 4; n++) {
      int col = bn + wc + n * 16 + l15;
      if (col < N) {
        float bv = BIAS ? bias[col] : 0.f;
        #pragma unroll
        for (int j = 0; j < 4; j++) {
          int row = bm + wr + m * 16 + l4 * 4 + j;
          float v = acc[m][n][j] + bv;
          if (RELU) v = fmaxf(v, 0.f);
          size_t off = (size_t)row * ldc + col;
          if (RESID) v += __bfloat162float(resid[off]);
          if (OUTBF) ((__hip_bfloat16*)Cout)[off] = __float2bfloat16(v);
          else       ((float*)Cout)[off] = v;
        }
      }
    }
  }
}

// ---------------- MFMA flash attention: one block per (b,h), 4 waves -------
#define KSTRIDE 72    // bf16: 144B rows -> 16B-aligned b128 reads, bank-balanced
#define VSTRIDE 260   // f16: 520B rows -> 8B-aligned b64 reads
__global__ __launch_bounds__(256) void k_attn_mfma(const __hip_bfloat16* __restrict__ qkv,
                                                   __hip_bfloat16* __restrict__ o) {
  __shared__ __hip_bfloat16 Ks[256 * KSTRIDE];   // 36864 B
  __shared__ _Float16      Vt[64 * VSTRIDE];     // 33280 B
  const int bh = blockIdx.x, b = bh >> 2, h = bh & 3;
  const __hip_bfloat16* base = qkv + (size_t)b * TT * 624;
  const int tid = threadIdx.x;
  #pragma unroll
  for (int it = 0; it < 16; it++) {
    int u = it * 256 + tid;
    int t = u >> 4, d4 = (u & 15) * 4;
    s16x4 v = {};
    if (d4 < 52) v = *(const s16x4*)(base + t * 624 + 208 + h * HD + d4);
    *(s16x4*)&Ks[t * KSTRIDE + d4] = v;
  }
  #pragma unroll 4
  for (int it = 0; it < 64; it++) {
    int u = it * 256 + tid;
    int d = u & 63, t = u >> 6;
    float v = (d < 52) ? __bfloat162float(base[t * 624 + 416 + h * HD + d]) : 0.f;
    Vt[d * VSTRIDE + t] = (_Float16)v;
  }
  __syncthreads();

  const int w = tid >> 6, lane = tid & 63, l15 = lane & 15, l4 = lane >> 4;
  const int q0 = w * 64;
  const float scale = 0.06933752453f;  // NE**-0.5 (reference scales by n_embed)
  bf16x8 qf[4][2];
  #pragma unroll
  for (int n = 0; n < 4; n++) {
    const __hip_bfloat16* qrow = base + (q0 + n * 16 + l15) * 624 + h * HD;
    #pragma unroll
    for (int ks = 0; ks < 2; ks++) {
      int s = ks * 32 + l4 * 8;
      union { s16x4 h2[2]; bf16x8 v; } u;
      u.h2[0] = (s <= 48) ? *(const s16x4*)(qrow + s) : (s16x4){};
      u.h2[1] = (s <= 44) ? *(const s16x4*)(qrow + s + 4) : (s16x4){};
      qf[n][ks] = u.v;
    }
  }
  f32x4 oacc[4][4] = {};
  float mrun[4] = {-1e30f, -1e30f, -1e30f, -1e30f};
  float lrun[4] = {0.f, 0.f, 0.f, 0.f};
  const int nch = 4 * (w + 1);
  for (int c = 0; c < nch; c++) {
    const int kb = c * 16;
    const bf16x8 kf0 = *(const bf16x8*)&Ks[(kb + l15) * KSTRIDE + l4 * 8];
    const bf16x8 kf1 = *(const bf16x8*)&Ks[(kb + l15) * KSTRIDE + 32 + l4 * 8];
    #pragma unroll
    for (int n = 0; n < 4; n++) {
      if (kb > q0 + n * 16 + 15) continue;   // tile fully masked (uniform)
      f32x4 s4 = __builtin_amdgcn_mfma_f32_16x16x32_bf16(kf0, qf[n][0],
                                                         (f32x4){0.f, 0.f, 0.f, 0.f}, 0, 0, 0);
      s4 = __builtin_amdgcn_mfma_f32_16x16x32_bf16(kf1, qf[n][1], s4, 0, 0, 0);
      const int q = q0 + n * 16 + l15;
      float pv[4];
      float pmax = -1e30f;
      #pragma unroll
      for (int j = 0; j < 4; j++) {
        int key = kb + l4 * 4 + j;
        float s = s4[j] * scale;
        pv[j] = (key <= q) ? s : -1e30f;
        pmax = fmaxf(pmax, pv[j]);
      }
      pmax = fmaxf(pmax, __shfl_xor(pmax, 16));
      pmax = fmaxf(pmax, __shfl_xor(pmax, 32));
      const float newm = fmaxf(mrun[n], pmax);
      const float r = __expf(mrun[n] - newm);
      float psum = 0.f;
      f16x4 pb;
      #pragma unroll
      for (int j = 0; j < 4; j++) {
        float e = __expf(pv[j] - newm);
        psum += e;
        pb[j] = (_Float16)e;
      }
      psum += __shfl_xor(psum, 16);
      psum += __shfl_xor(psum, 32);
      lrun[n] = lrun[n] * r + psum;
      mrun[n] = newm;
      #pragma unroll
      for (int m = 0; m < 4; m++) {
        oacc[m][n][0] *= r; oacc[m][n][1] *= r;
        oacc[m][n][2] *= r; oacc[m][n][3] *= r;
      }
      #pragma unroll
      for (int m = 0; m < 4; m++) {
        f16x4 vf = *(const f16x4*)&Vt[(m * 16 + l15) * VSTRIDE + kb + l4 * 4];
        oacc[m][n] = __builtin_amdgcn_mfma_f32_16x16x16f16(vf, pb, oacc[m][n], 0, 0, 0);
      }
    }
  }
  #pragma unroll
  for (int n = 0; n < 4; n++) {
    const float inv = 1.f / lrun[n];
    __hip_bfloat16* orow = o + (size_t)(b * TT + q0 + n * 16 + l15) * KP + h * HD;
    #pragma unroll
    for (int m = 0; m < 4; m++)
      #pragma unroll
      for (int j = 0; j < 4; j++) {
        int d = m * 16 + l4 * 4 + j;
        if (d < HD) orow[d] = __float2bfloat16(oacc[m][n][j] * inv);
      }
  }
}

// ---------------- loss: per-row LSE - logit[target] ----------------
__global__ __launch_bounds__(256) void k_loss_rows(const float* __restrict__ logits,
                                                   const int* __restrict__ targets,
                                                   float* __restrict__ row_loss) {
  int r = blockIdx.x * 4 + (threadIdx.x >> 6);
  int lane = threadIdx.x & 63;
  const float* row = logits + (size_t)r * VOCAB;
  float vals[24];
  int cnt = 0;
  float m = -1e30f;
  for (int c = lane * 4; c < VOCAB; c += 256) {   // 1500 % 4 == 0: exact float4s
    float4 v = *(const float4*)(row + c);
    vals[cnt++] = v.x; vals[cnt++] = v.y; vals[cnt++] = v.z; vals[cnt++] = v.w;
    m = fmaxf(m, fmaxf(fmaxf(v.x, v.y), fmaxf(v.z, v.w)));
  }
  #pragma unroll
  for (int o = 32; o; o >>= 1) m = fmaxf(m, __shfl_xor(m, o));
  float sum = 0.f;
  for (int i = 0; i < cnt; i++) sum += __expf(vals[i] - m);
  #pragma unroll
  for (int o = 32; o; o >>= 1) sum += __shfl_xor(sum, o);
  if (lane == 0) row_loss[r] = (__logf(sum) + m) - row[targets[r]];
}

__global__ __launch_bounds__(256) void k_loss_reduce(const float* __restrict__ row_loss,
                                                     float* __restrict__ out_loss) {
  __shared__ float sh[256];
  float s = 0.f;
  for (int i = threadIdx.x; i < NTOK; i += 256) s += row_loss[i];
  sh[threadIdx.x] = s;
  __syncthreads();
  for (int k = 128; k; k >>= 1) {
    if (threadIdx.x < k) sh[threadIdx.x] += sh[threadIdx.x + k];
    __syncthreads();
  }
  if (threadIdx.x == 0) *out_loss = sh[0] * (1.f / NTOK);
}

extern "C" void kernel_launch(void* const* d_in, const int* in_sizes, int n_in,
                              void* d_out, int out_size, void* d_ws, size_t ws_size,
                              hipStream_t stream) {
  const int*   idx     = (const int*)d_in[0];
  const int*   targets = (const int*)d_in[1];
  const float* tok     = (const float*)d_in[2];
  const float* pos     = (const float*)d_in[3];
  const float* Wq      = (const float*)d_in[4];
  const float* Wk      = (const float*)d_in[5];
  const float* Wv      = (const float*)d_in[6];
  const float* Wo      = (const float*)d_in[7];
  const float* bo      = (const float*)d_in[8];
  const float* ln1g    = (const float*)d_in[9];
  const float* ln1b    = (const float*)d_in[10];
  const float* W1      = (const float*)d_in[11];
  const float* b1      = (const float*)d_in[12];
  const float* W2      = (const float*)d_in[13];
  const float* b2      = (const float*)d_in[14];
  const float* ln2g    = (const float*)d_in[15];
  const float* ln2b    = (const float*)d_in[16];
  const float* lnfg    = (const float*)d_in[17];
  const float* lnfb    = (const float*)d_in[18];
  const float* Wlm     = (const float*)d_in[19];
  const float* blm     = (const float*)d_in[20];
  float* out = (float*)d_out;

  char* w = (char*)d_ws;
  __hip_bfloat16* x   = (__hip_bfloat16*)w; w += (size_t)NTOK * NE * 2;
  __hip_bfloat16* qkv = (__hip_bfloat16*)w; w += (size_t)NTOK * 624 * 2;
  __hip_bfloat16* hbf = (__hip_bfloat16*)w; w += (size_t)NTOK * KP * 2;
  __hip_bfloat16* act = (__hip_bfloat16*)w; w += (size_t)NTOK * 832 * 2;
  __hip_bfloat16* WqkvT = (__hip_bfloat16*)w; w += (size_t)NL * 640 * KP * 2;
  __hip_bfloat16* WoT   = (__hip_bfloat16*)w; w += (size_t)NL * 256 * KP * 2;
  __hip_bfloat16* W1T   = (__hip_bfloat16*)w; w += (size_t)NL * 896 * KP * 2;
  __hip_bfloat16* W2T   = (__hip_bfloat16*)w; w += (size_t)NL * 256 * 832 * 2;
  __hip_bfloat16* WlmT  = (__hip_bfloat16*)w; w += (size_t)1536 * KP * 2;
  float* row_loss = (float*)w;

  k_prep_qkvT<<<NL * 640 * KP / 256, 256, 0, stream>>>(Wq, Wk, Wv, WqkvT);
  k_prep_oT<<<NL * 256 * KP / 256, 256, 0, stream>>>(Wo, WoT);
  k_prep_1T<<<NL * 896 * KP / 256, 256, 0, stream>>>(W1, W1T);
  k_prep_2T<<<NL * 256 * 832 / 256, 256, 0, stream>>>(W2, W2T);
  k_prep_lmT<<<1536 * KP / 256, 256, 0, stream>>>(Wlm, WlmT);
  k_embed<<<NTOK * NE / 256, 256, 0, stream>>>(idx, tok, pos, x);

  for (int l = 0; l < NL; l++) {
    k_ln_bf<<<NTOK / 4, 256, 0, stream>>>(x, ln1g + l * NE, ln1b + l * NE, hbf);
    k_mgemm<false, false, false, true><<<dim3(5, 512), 256, 0, stream>>>(
        hbf, KP, WqkvT + (size_t)l * 640 * KP, KP, nullptr, nullptr, qkv, 624, 624, KP);
    k_attn_mfma<<<BBATCH * NHD, 256, 0, stream>>>(qkv, hbf);
    k_mgemm<false, true, true, true><<<dim3(2, 512), 256, 0, stream>>>(
        hbf, KP, WoT + (size_t)l * 256 * KP, KP, bo + l * NE, x, x, NE, NE, KP);
    k_ln_bf<<<NTOK / 4, 256, 0, stream>>>(x, ln2g + l * NE, ln2b + l * NE, hbf);
    k_mgemm<true, false, true, true><<<dim3(7, 512), 256, 0, stream>>>(
        hbf, KP, W1T + (size_t)l * 896 * KP, KP, b1 + l * 832, nullptr, act, 832, 832, KP);
    k_mgemm<false, true, true, true><<<dim3(2, 512), 256, 0, stream>>>(
        act, 832, W2T + (size_t)l * 256 * 832, 832, b2 + l * NE, x, x, NE, NE, 832);
  }

  k_ln_bf<<<NTOK / 4, 256, 0, stream>>>(x, lnfg, lnfb, hbf);
  k_mgemm<false, false, true, false><<<dim3(12, 512), 256, 0, stream>>>(
      hbf, KP, WlmT, KP, blm, nullptr, out, VOCAB, VOCAB, KP);

  k_loss_rows<<<NTOK / 4, 256, 0, stream>>>(out, targets, row_loss);
  k_loss_reduce<<<1, 256, 0, stream>>>(row_loss, out + ((size_t)out_size - 1));
}

// Round 7
// 2859.532 us; speedup vs baseline: 4.7615x; 1.1219x over previous
//
#include <hip/hip_runtime.h>
#include <hip/hip_bf16.h>
#include <math.h>

#define VOCAB 1500
#define NE    208
#define TT    256
#define NHD   4
#define HD    52
#define NL    8
#define BBATCH 256
#define NTOK  (BBATCH * TT)   // 65536
#define KP    224             // NE padded to multiple of 32

typedef __attribute__((ext_vector_type(8))) short bf16x8;
typedef __attribute__((ext_vector_type(4))) short s16x4;
typedef __attribute__((ext_vector_type(4))) float f32x4;
typedef __attribute__((ext_vector_type(4))) _Float16 f16x4;

__device__ __forceinline__ void gload16(const void* g, void* l) {
  __builtin_amdgcn_global_load_lds(
      (const __attribute__((address_space(1))) unsigned int*)g,
      (__attribute__((address_space(3))) unsigned int*)l, 16, 0, 0);
}
__device__ __forceinline__ float bf2f(short u) {
  union { unsigned int i; float f; } cv;
  cv.i = ((unsigned int)(unsigned short)u) << 16;
  return cv.f;
}

// ---------------- embedding: x = tok_emb[idx] + pos_emb (bf16 out) ---------
__global__ __launch_bounds__(256) void k_embed(const int* __restrict__ idx,
                                               const float* __restrict__ tok,
                                               const float* __restrict__ pos,
                                               __hip_bfloat16* __restrict__ x) {
  int i = blockIdx.x * 256 + threadIdx.x;
  int n = i / NE, c = i - n * NE;
  int t = n & (TT - 1);
  x[i] = __float2bfloat16(tok[idx[n] * NE + c] + pos[t * NE + c]);
}

// ---------- weight prep: transposed + K-padded bf16 copies ----------
__global__ __launch_bounds__(256) void k_prep_qkvT(const float* __restrict__ Wq,
                                                   const float* __restrict__ Wk,
                                                   const float* __restrict__ Wv,
                                                   __hip_bfloat16* __restrict__ o) {
  int i = blockIdx.x * 256 + threadIdx.x;          // NL*640*224 exact
  int c = i % KP;
  int jl = i / KP;
  int j = jl % 640, l = jl / 640;
  float v = 0.f;
  if (j < 624 && c < NE) {
    int sel = j / NE, hd = j - sel * NE;
    int h = hd / HD, d = hd - h * HD;
    const float* W = (sel == 0) ? Wq : (sel == 1) ? Wk : Wv;
    v = W[(((size_t)l * NHD + h) * NE + c) * HD + d];
  }
  o[i] = __float2bfloat16(v);
}

__global__ __launch_bounds__(256) void k_prep_oT(const float* __restrict__ Wo,
                                                 __hip_bfloat16* __restrict__ o) {
  int i = blockIdx.x * 256 + threadIdx.x;          // NL*256*224 exact
  int c = i % KP;
  int jl = i / KP;
  int j = jl % 256, l = jl / 256;
  float v = (j < NE && c < NE) ? Wo[((size_t)l * NE + c) * NE + j] : 0.f;
  o[i] = __float2bfloat16(v);
}

__global__ __launch_bounds__(256) void k_prep_1T(const float* __restrict__ W1,
                                                 __hip_bfloat16* __restrict__ o) {
  int i = blockIdx.x * 256 + threadIdx.x;          // NL*896*224 exact
  int c = i % KP;
  int jl = i / KP;
  int j = jl % 896, l = jl / 896;
  float v = (j < 832 && c < NE) ? W1[((size_t)l * NE + c) * 832 + j] : 0.f;
  o[i] = __float2bfloat16(v);
}

__global__ __launch_bounds__(256) void k_prep_2T(const float* __restrict__ W2,
                                                 __hip_bfloat16* __restrict__ o) {
  int i = blockIdx.x * 256 + threadIdx.x;          // NL*256*832 exact
  int c = i % 832;
  int jl = i / 832;
  int j = jl % 256, l = jl / 256;
  float v = (j < NE) ? W2[((size_t)l * 832 + c) * NE + j] : 0.f;
  o[i] = __float2bfloat16(v);
}

__global__ __launch_bounds__(256) void k_prep_lmT(const float* __restrict__ Wlm,
                                                  __hip_bfloat16* __restrict__ o) {
  int i = blockIdx.x * 256 + threadIdx.x;          // 1536*224 exact
  int c = i % KP;
  int j = i / KP;
  float v = (j < VOCAB && c < NE) ? Wlm[(size_t)c * VOCAB + j] : 0.f;
  o[i] = __float2bfloat16(v);
}

// ------- layernorm (used once after embed): bf16 in/out -------
__global__ __launch_bounds__(256) void k_ln_bf(const __hip_bfloat16* __restrict__ x,
                                               const float* __restrict__ g,
                                               const float* __restrict__ b,
                                               __hip_bfloat16* __restrict__ h) {
  int r = blockIdx.x * 4 + (threadIdx.x >> 6);
  int lane = threadIdx.x & 63;
  const int c0 = lane * 4;
  float v[4] = {0.f, 0.f, 0.f, 0.f};
  float s = 0.f;
  if (lane < 52) {
    s16x4 raw = *(const s16x4*)(x + (size_t)r * NE + c0);
    #pragma unroll
    for (int i = 0; i < 4; i++) { v[i] = bf2f(raw[i]); s += v[i]; }
  }
  #pragma unroll
  for (int o = 32; o; o >>= 1) s += __shfl_xor(s, o);
  float mu = s * (1.f / NE);
  float q = 0.f;
  if (lane < 52) {
    #pragma unroll
    for (int i = 0; i < 4; i++) { float d = v[i] - mu; q += d * d; }
  }
  #pragma unroll
  for (int o = 32; o; o >>= 1) q += __shfl_xor(q, o);
  float inv = rsqrtf(q * (1.f / NE) + 1e-5f);
  if (lane < 56) {
    s16x4 outv = {};
    if (lane < 52) {
      #pragma unroll
      for (int i = 0; i < 4; i++) {
        float o = (v[i] - mu) * inv * g[c0 + i] + b[c0 + i];
        outv[i] = (short)__bfloat16_as_ushort(__float2bfloat16(o));
      }
    }
    *(s16x4*)(h + (size_t)r * KP + c0) = outv;
  }
}

// ------- bf16 MFMA GEMM: dbuf + counted vmcnt + raw barriers ----------
template <bool RELU, bool RESID, bool BIAS, bool OUTBF>
__global__ __launch_bounds__(256) void k_mgemm(const __hip_bfloat16* __restrict__ A, int lda,
                                               const __hip_bfloat16* __restrict__ BT, int ldb,
                                               const float* __restrict__ bias,
                                               const __hip_bfloat16* __restrict__ resid,
                                               void* __restrict__ Cout, int ldc,
                                               int N, int K) {
  __shared__ __hip_bfloat16 As[2][128 * 32];
  __shared__ __hip_bfloat16 Bs[2][128 * 32];
  const int bm = blockIdx.y * 128, bn = blockIdx.x * 128;
  const int tid = threadIdx.x;
  const int wave = tid >> 6, lane = tid & 63;
  const int wr = (wave >> 1) * 64, wc = (wave & 1) * 64;
  const int l15 = lane & 15, l4 = lane >> 4;
  const int srow = tid >> 2, sgrp = (tid & 3) * 8;
  const int srow2 = srow + 64;
  f32x4 acc[4][4] = {};
  const int nt = K / 32;
  gload16(A + (size_t)(bm + srow) * lda + sgrp, &As[0][tid * 8]);
  gload16(BT + (size_t)(bn + srow) * ldb + sgrp, &Bs[0][tid * 8]);
  gload16(A + (size_t)(bm + srow2) * lda + sgrp, &As[0][(256 + tid) * 8]);
  gload16(BT + (size_t)(bn + srow2) * ldb + sgrp, &Bs[0][(256 + tid) * 8]);
  int cur = 0;
  for (int t = 0; t < nt; t++) {
    if (t + 1 < nt) {
      int k1 = (t + 1) * 32;
      gload16(A + (size_t)(bm + srow) * lda + k1 + sgrp, &As[cur ^ 1][tid * 8]);
      gload16(BT + (size_t)(bn + srow) * ldb + k1 + sgrp, &Bs[cur ^ 1][tid * 8]);
      gload16(A + (size_t)(bm + srow2) * lda + k1 + sgrp, &As[cur ^ 1][(256 + tid) * 8]);
      gload16(BT + (size_t)(bn + srow2) * ldb + k1 + sgrp, &Bs[cur ^ 1][(256 + tid) * 8]);
      asm volatile("s_waitcnt vmcnt(4)" ::: "memory");
    } else {
      asm volatile("s_waitcnt vmcnt(0)" ::: "memory");
    }
    __builtin_amdgcn_s_barrier();
    bf16x8 af[4], bfr[4];
    #pragma unroll
    for (int m = 0; m < 4; m++)
      af[m] = *(const bf16x8*)&As[cur][(wr + m * 16 + l15) * 32 + l4 * 8];
    #pragma unroll
    for (int n = 0; n < 4; n++)
      bfr[n] = *(const bf16x8*)&Bs[cur][(wc + n * 16 + l15) * 32 + l4 * 8];
    #pragma unroll
    for (int m = 0; m < 4; m++)
      #pragma unroll
      for (int n = 0; n < 4; n++)
        acc[m][n] = __builtin_amdgcn_mfma_f32_16x16x32_bf16(af[m], bfr[n], acc[m][n], 0, 0, 0);
    if (t + 1 < nt) __builtin_amdgcn_s_barrier();
    cur ^= 1;
  }
  #pragma unroll
  for (int m = 0; m < 4; m++) {
    #pragma unroll
    for (int n = 0; n < 4; n++) {
      int col = bn + wc + n * 16 + l15;
      if (col < N) {
        float bv = BIAS ? bias[col] : 0.f;
        #pragma unroll
        for (int j = 0; j < 4; j++) {
          int row = bm + wr + m * 16 + l4 * 4 + j;
          float v = acc[m][n][j] + bv;
          if (RELU) v = fmaxf(v, 0.f);
          size_t off = (size_t)row * ldc + col;
          if (RESID) v += __bfloat162float(resid[off]);
          if (OUTBF) ((__hip_bfloat16*)Cout)[off] = __float2bfloat16(v);
          else       ((float*)Cout)[off] = v;
        }
      }
    }
  }
}

// ------- GEMM (N=208 in one block-col) + residual + fused LayerNorm --------
// x' = resid + A@B + bias; xout = x' (bf16 ld NE); hout = LN(x')*g+b (ld KP).
// BM=128, BN=256 (B rows 208..255 are zero-padded), 8 waves (512 thr).
__global__ __launch_bounds__(512) void k_mgemm_ln(const __hip_bfloat16* __restrict__ A, int lda,
                                                  const __hip_bfloat16* __restrict__ BT, int ldb,
                                                  const float* __restrict__ bias,
                                                  const __hip_bfloat16* __restrict__ resid,
                                                  const float* __restrict__ g,
                                                  const float* __restrict__ bb,
                                                  __hip_bfloat16* __restrict__ xout,
                                                  __hip_bfloat16* __restrict__ hout,
                                                  int K) {
  __shared__ __hip_bfloat16 As[2][128 * 32];
  __shared__ __hip_bfloat16 Bs[2][256 * 32];
  __shared__ float red[128][4];   // {sum_w0, sq_w0, sum_w1, sq_w1}
  const int bm = blockIdx.x * 128;
  const int tid = threadIdx.x;
  const int wid = tid >> 6, lane = tid & 63;
  const int wr = (wid >> 1) * 32, wc = (wid & 1) * 128;
  const int l15 = lane & 15, l4 = lane >> 4;
  const int srow = tid >> 2, sgrp = (tid & 3) * 8;
  f32x4 acc[2][8] = {};
  const int nt = K / 32;
  // prologue: 3 loads/thread
  gload16(A + (size_t)(bm + srow) * lda + sgrp, &As[0][tid * 8]);
  gload16(BT + (size_t)srow * ldb + sgrp, &Bs[0][tid * 8]);
  gload16(BT + (size_t)(128 + srow) * ldb + sgrp, &Bs[0][(512 + tid) * 8]);
  int cur = 0;
  for (int t = 0; t < nt; t++) {
    if (t + 1 < nt) {
      int k1 = (t + 1) * 32;
      gload16(A + (size_t)(bm + srow) * lda + k1 + sgrp, &As[cur ^ 1][tid * 8]);
      gload16(BT + (size_t)srow * ldb + k1 + sgrp, &Bs[cur ^ 1][tid * 8]);
      gload16(BT + (size_t)(128 + srow) * ldb + k1 + sgrp, &Bs[cur ^ 1][(512 + tid) * 8]);
      asm volatile("s_waitcnt vmcnt(3)" ::: "memory");
    } else {
      asm volatile("s_waitcnt vmcnt(0)" ::: "memory");
    }
    __builtin_amdgcn_s_barrier();
    bf16x8 af[2], bfr[8];
    #pragma unroll
    for (int m = 0; m < 2; m++)
      af[m] = *(const bf16x8*)&As[cur][(wr + m * 16 + l15) * 32 + l4 * 8];
    #pragma unroll
    for (int n = 0; n < 8; n++)
      bfr[n] = *(const bf16x8*)&Bs[cur][(wc + n * 16 + l15) * 32 + l4 * 8];
    #pragma unroll
    for (int m = 0; m < 2; m++)
      #pragma unroll
      for (int n = 0; n < 8; n++)
        acc[m][n] = __builtin_amdgcn_mfma_f32_16x16x32_bf16(af[m], bfr[n], acc[m][n], 0, 0, 0);
    if (t + 1 < nt) __builtin_amdgcn_s_barrier();
    cur ^= 1;
  }
  // epilogue: v = acc + bias + resid (cols<208), LN stats, dual store
  #pragma unroll
  for (int m = 0; m < 2; m++)
    #pragma unroll
    for (int n = 0; n < 8; n++) {
      int col = wc + n * 16 + l15;
      #pragma unroll
      for (int j = 0; j < 4; j++) {
        int row = bm + wr + m * 16 + l4 * 4 + j;
        float v = 0.f;
        if (col < NE)
          v = acc[m][n][j] + bias[col] + __bfloat162float(resid[(size_t)row * NE + col]);
        acc[m][n][j] = v;
      }
    }
  #pragma unroll
  for (int m = 0; m < 2; m++)
    #pragma unroll
    for (int j = 0; j < 4; j++) {
      float s = 0.f, q = 0.f;
      #pragma unroll
      for (int n = 0; n < 8; n++) { float v = acc[m][n][j]; s += v; q += v * v; }
      #pragma unroll
      for (int off = 1; off < 16; off <<= 1) {
        s += __shfl_xor(s, off);
        q += __shfl_xor(q, off);
      }
      if (l15 == 0) {
        int row = wr + m * 16 + l4 * 4 + j;
        red[row][(wid & 1) * 2 + 0] = s;
        red[row][(wid & 1) * 2 + 1] = q;
      }
    }
  __syncthreads();
  #pragma unroll
  for (int m = 0; m < 2; m++)
    #pragma unroll
    for (int j = 0; j < 4; j++) {
      int lrow = wr + m * 16 + l4 * 4 + j;
      float s = red[lrow][0] + red[lrow][2];
      float q = red[lrow][1] + red[lrow][3];
      float mu = s * (1.f / NE);
      float var = q * (1.f / NE) - mu * mu;
      float inv = rsqrtf(var + 1e-5f);
      size_t row = bm + lrow;
      #pragma unroll
      for (int n = 0; n < 8; n++) {
        int col = wc + n * 16 + l15;
        if (col < NE) {
          float v = acc[m][n][j];
          xout[row * NE + col] = __float2bfloat16(v);
          hout[row * KP + col] = __float2bfloat16((v - mu) * inv * g[col] + bb[col]);
        } else if (col < KP) {
          hout[row * KP + col] = __float2bfloat16(0.f);
        }
      }
    }
}

// -------- MFMA flash attention: one block per (b,h), balanced waves --------
// wave w owns q-tiles {w, 7-w, 8+w, 15-w}: exactly 34 chunk-visits per wave.
#define KSTRIDE 72
#define VSTRIDE 260
__global__ __launch_bounds__(256) void k_attn_mfma(const __hip_bfloat16* __restrict__ qkv,
                                                   __hip_bfloat16* __restrict__ o) {
  __shared__ __hip_bfloat16 Ks[256 * KSTRIDE];
  __shared__ _Float16      Vt[64 * VSTRIDE];
  const int bh = blockIdx.x, b = bh >> 2, h = bh & 3;
  const __hip_bfloat16* base = qkv + (size_t)b * TT * 624;
  const int tid = threadIdx.x;
  #pragma unroll
  for (int it = 0; it < 16; it++) {
    int u = it * 256 + tid;
    int t = u >> 4, d4 = (u & 15) * 4;
    s16x4 v = {};
    if (d4 < 52) v = *(const s16x4*)(base + t * 624 + 208 + h * HD + d4);
    *(s16x4*)&Ks[t * KSTRIDE + d4] = v;
  }
  #pragma unroll
  for (int it = 0; it < 13; it++) {            // V transposed, vectorized reads
    int u = it * 256 + tid;
    int d4g = u >> 8, t = u & 255;             // d4g 0..12 (13*4 = 52 exact)
    s16x4 kv = *(const s16x4*)(base + t * 624 + 416 + h * HD + d4g * 4);
    #pragma unroll
    for (int i = 0; i < 4; i++)
      Vt[(d4g * 4 + i) * VSTRIDE + t] = (_Float16)bf2f(kv[i]);
  }
  #pragma unroll
  for (int it = 0; it < 12; it++)              // zero pad rows 52..63
    Vt[(52 + it) * VSTRIDE + tid] = (_Float16)0.f;
  __syncthreads();

  const int w = tid >> 6, lane = tid & 63, l15 = lane & 15, l4 = lane >> 4;
  const float scale = 0.06933752453f;  // NE**-0.5 (reference scales by n_embed)
  const int qts[4] = {w, 7 - w, 8 + w, 15 - w};
  bf16x8 qf[4][2];
  #pragma unroll
  for (int i = 0; i < 4; i++) {
    const __hip_bfloat16* qrow = base + (qts[i] * 16 + l15) * 624 + h * HD;
    #pragma unroll
    for (int ks = 0; ks < 2; ks++) {
      int s = ks * 32 + l4 * 8;
      union { s16x4 h2[2]; bf16x8 v; } u;
      u.h2[0] = (s <= 48) ? *(const s16x4*)(qrow + s) : (s16x4){};
      u.h2[1] = (s <= 44) ? *(const s16x4*)(qrow + s + 4) : (s16x4){};
      qf[i][ks] = u.v;
    }
  }
  f32x4 oacc[4][4] = {};     // [m over d][i over q-tiles]
  float mrun[4] = {-1e30f, -1e30f, -1e30f, -1e30f};
  float lrun[4] = {0.f, 0.f, 0.f, 0.f};
  const int cmax = 15 - w;   // max(qts)
  for (int c = 0; c <= cmax; c++) {
    const int kb = c * 16;
    const bf16x8 kf0 = *(const bf16x8*)&Ks[(kb + l15) * KSTRIDE + l4 * 8];
    const bf16x8 kf1 = *(const bf16x8*)&Ks[(kb + l15) * KSTRIDE + 32 + l4 * 8];
    #pragma unroll
    for (int i = 0; i < 4; i++) {
      if (qts[i] < c) continue;               // wave-uniform
      f32x4 s4 = __builtin_amdgcn_mfma_f32_16x16x32_bf16(kf0, qf[i][0],
                                                         (f32x4){0.f, 0.f, 0.f, 0.f}, 0, 0, 0);
      s4 = __builtin_amdgcn_mfma_f32_16x16x32_bf16(kf1, qf[i][1], s4, 0, 0, 0);
      const int q = qts[i] * 16 + l15;
      float pv[4];
      float pmax = -1e30f;
      #pragma unroll
      for (int j = 0; j < 4; j++) {
        int key = kb + l4 * 4 + j;
        float s = s4[j] * scale;
        pv[j] = (key <= q) ? s : -1e30f;
        pmax = fmaxf(pmax, pv[j]);
      }
      pmax = fmaxf(pmax, __shfl_xor(pmax, 16));
      pmax = fmaxf(pmax, __shfl_xor(pmax, 32));
      const float newm = fmaxf(mrun[i], pmax);
      const float r = __expf(mrun[i] - newm);
      float psum = 0.f;
      f16x4 pb;
      #pragma unroll
      for (int j = 0; j < 4; j++) {
        float e = __expf(pv[j] - newm);
        psum += e;
        pb[j] = (_Float16)e;
      }
      psum += __shfl_xor(psum, 16);
      psum += __shfl_xor(psum, 32);
      lrun[i] = lrun[i] * r + psum;
      mrun[i] = newm;
      #pragma unroll
      for (int m = 0; m < 4; m++) {
        oacc[m][i][0] *= r; oacc[m][i][1] *= r;
        oacc[m][i][2] *= r; oacc[m][i][3] *= r;
      }
      #pragma unroll
      for (int m = 0; m < 4; m++) {
        f16x4 vf = *(const f16x4*)&Vt[(m * 16 + l15) * VSTRIDE + kb + l4 * 4];
        oacc[m][i] = __builtin_amdgcn_mfma_f32_16x16x16f16(vf, pb, oacc[m][i], 0, 0, 0);
      }
    }
  }
  #pragma unroll
  for (int i = 0; i < 4; i++) {
    const float inv = 1.f / lrun[i];
    __hip_bfloat16* orow = o + (size_t)(b * TT + qts[i] * 16 + l15) * KP + h * HD;
    #pragma unroll
    for (int m = 0; m < 4; m++)
      #pragma unroll
      for (int j = 0; j < 4; j++) {
        int d = m * 16 + l4 * 4 + j;
        if (d < HD) orow[d] = __float2bfloat16(oacc[m][i][j] * inv);
      }
  }
}

// ---------------- loss ----------------
__global__ __launch_bounds__(256) void k_loss_rows(const float* __restrict__ logits,
                                                   const int* __restrict__ targets,
                                                   float* __restrict__ row_loss) {
  int r = blockIdx.x * 4 + (threadIdx.x >> 6);
  int lane = threadIdx.x & 63;
  const float* row = logits + (size_t)r * VOCAB;
  float vals[24];
  int cnt = 0;
  float m = -1e30f;
  for (int c = lane * 4; c < VOCAB; c += 256) {
    float4 v = *(const float4*)(row + c);
    vals[cnt++] = v.x; vals[cnt++] = v.y; vals[cnt++] = v.z; vals[cnt++] = v.w;
    m = fmaxf(m, fmaxf(fmaxf(v.x, v.y), fmaxf(v.z, v.w)));
  }
  #pragma unroll
  for (int o = 32; o; o >>= 1) m = fmaxf(m, __shfl_xor(m, o));
  float sum = 0.f;
  for (int i = 0; i < cnt; i++) sum += __expf(vals[i] - m);
  #pragma unroll
  for (int o = 32; o; o >>= 1) sum += __shfl_xor(sum, o);
  if (lane == 0) row_loss[r] = (__logf(sum) + m) - row[targets[r]];
}

__global__ __launch_bounds__(256) void k_loss_reduce(const float* __restrict__ row_loss,
                                                     float* __restrict__ out_loss) {
  __shared__ float sh[256];
  float s = 0.f;
  for (int i = threadIdx.x; i < NTOK; i += 256) s += row_loss[i];
  sh[threadIdx.x] = s;
  __syncthreads();
  for (int k = 128; k; k >>= 1) {
    if (threadIdx.x < k) sh[threadIdx.x] += sh[threadIdx.x + k];
    __syncthreads();
  }
  if (threadIdx.x == 0) *out_loss = sh[0] * (1.f / NTOK);
}

extern "C" void kernel_launch(void* const* d_in, const int* in_sizes, int n_in,
                              void* d_out, int out_size, void* d_ws, size_t ws_size,
                              hipStream_t stream) {
  const int*   idx     = (const int*)d_in[0];
  const int*   targets = (const int*)d_in[1];
  const float* tok     = (const float*)d_in[2];
  const float* pos     = (const float*)d_in[3];
  const float* Wq      = (const float*)d_in[4];
  const float* Wk      = (const float*)d_in[5];
  const float* Wv      = (const float*)d_in[6];
  const float* Wo      = (const float*)d_in[7];
  const float* bo      = (const float*)d_in[8];
  const float* ln1g    = (const float*)d_in[9];
  const float* ln1b    = (const float*)d_in[10];
  const float* W1      = (const float*)d_in[11];
  const float* b1      = (const float*)d_in[12];
  const float* W2      = (const float*)d_in[13];
  const float* b2      = (const float*)d_in[14];
  const float* ln2g    = (const float*)d_in[15];
  const float* ln2b    = (const float*)d_in[16];
  const float* lnfg    = (const float*)d_in[17];
  const float* lnfb    = (const float*)d_in[18];
  const float* Wlm     = (const float*)d_in[19];
  const float* blm     = (const float*)d_in[20];
  float* out = (float*)d_out;

  char* w = (char*)d_ws;
  __hip_bfloat16* x   = (__hip_bfloat16*)w; w += (size_t)NTOK * NE * 2;
  __hip_bfloat16* qkv = (__hip_bfloat16*)w; w += (size_t)NTOK * 624 * 2;
  __hip_bfloat16* hbf = (__hip_bfloat16*)w; w += (size_t)NTOK * KP * 2;
  __hip_bfloat16* act = (__hip_bfloat16*)w; w += (size_t)NTOK * 832 * 2;
  __hip_bfloat16* WqkvT = (__hip_bfloat16*)w; w += (size_t)NL * 640 * KP * 2;
  __hip_bfloat16* WoT   = (__hip_bfloat16*)w; w += (size_t)NL * 256 * KP * 2;
  __hip_bfloat16* W1T   = (__hip_bfloat16*)w; w += (size_t)NL * 896 * KP * 2;
  __hip_bfloat16* W2T   = (__hip_bfloat16*)w; w += (size_t)NL * 256 * 832 * 2;
  __hip_bfloat16* WlmT  = (__hip_bfloat16*)w; w += (size_t)1536 * KP * 2;
  float* row_loss = (float*)w;

  k_prep_qkvT<<<NL * 640 * KP / 256, 256, 0, stream>>>(Wq, Wk, Wv, WqkvT);
  k_prep_oT<<<NL * 256 * KP / 256, 256, 0, stream>>>(Wo, WoT);
  k_prep_1T<<<NL * 896 * KP / 256, 256, 0, stream>>>(W1, W1T);
  k_prep_2T<<<NL * 256 * 832 / 256, 256, 0, stream>>>(W2, W2T);
  k_prep_lmT<<<1536 * KP / 256, 256, 0, stream>>>(Wlm, WlmT);
  k_embed<<<NTOK * NE / 256, 256, 0, stream>>>(idx, tok, pos, x);
  k_ln_bf<<<NTOK / 4, 256, 0, stream>>>(x, ln1g, ln1b, hbf);

  for (int l = 0; l < NL; l++) {
    k_mgemm<false, false, false, true><<<dim3(5, 512), 256, 0, stream>>>(
        hbf, KP, WqkvT + (size_t)l * 640 * KP, KP, nullptr, nullptr, qkv, 624, 624, KP);
    k_attn_mfma<<<BBATCH * NHD, 256, 0, stream>>>(qkv, hbf);
    k_mgemm_ln<<<512, 512, 0, stream>>>(
        hbf, KP, WoT + (size_t)l * 256 * KP, KP, bo + l * NE, x,
        ln2g + l * NE, ln2b + l * NE, x, hbf, KP);
    k_mgemm<true, false, true, true><<<dim3(7, 512), 256, 0, stream>>>(
        hbf, KP, W1T + (size_t)l * 896 * KP, KP, b1 + l * 832, nullptr, act, 832, 832, KP);
    const float* gn = (l < NL - 1) ? (ln1g + (l + 1) * NE) : lnfg;
    const float* bn = (l < NL - 1) ? (ln1b + (l + 1) * NE) : lnfb;
    k_mgemm_ln<<<512, 512, 0, stream>>>(
        act, 832, W2T + (size_t)l * 256 * 832, 832, b2 + l * NE, x,
        gn, bn, x, hbf, 832);
  }

  k_mgemm<false, false, true, false><<<dim3(12, 512), 256, 0, stream>>>(
      hbf, KP, WlmT, KP, blm, nullptr, out, VOCAB, VOCAB, KP);

  k_loss_rows<<<NTOK / 4, 256, 0, stream>>>(out, targets, row_loss);
  k_loss_reduce<<<1, 256, 0, stream>>>(row_loss, out + ((size_t)out_size - 1));
}

// Round 8
// 2520.858 us; speedup vs baseline: 5.4012x; 1.1343x over previous
//
#include <hip/hip_runtime.h>
#include <hip/hip_bf16.h>
#include <math.h>

#define VOCAB 1500
#define NE    208
#define TT    256
#define NHD   4
#define HD    52
#define NL    8
#define BBATCH 256
#define NTOK  (BBATCH * TT)   // 65536
#define KP    224             // NE padded to multiple of 32

typedef __attribute__((ext_vector_type(8))) short bf16x8;
typedef __attribute__((ext_vector_type(4))) short s16x4;
typedef __attribute__((ext_vector_type(4))) float f32x4;
typedef __attribute__((ext_vector_type(4))) _Float16 f16x4;

__device__ __forceinline__ void gload16(const void* g, void* l) {
  __builtin_amdgcn_global_load_lds(
      (const __attribute__((address_space(1))) unsigned int*)g,
      (__attribute__((address_space(3))) unsigned int*)l, 16, 0, 0);
}
__device__ __forceinline__ float bf2f(short u) {
  union { unsigned int i; float f; } cv;
  cv.i = ((unsigned int)(unsigned short)u) << 16;
  return cv.f;
}

// ---------- merged weight prep: all transposed/padded bf16 copies ----------
#define P_QKV 1146880            // NL*640*KP
#define P_O   458752             // NL*256*KP
#define P_1   1605632            // NL*896*KP
#define P_2   1703936            // NL*256*832
#define P_LM  344064             // 1536*KP
__global__ __launch_bounds__(256) void k_prep_all(const float* __restrict__ Wq,
                                                  const float* __restrict__ Wk,
                                                  const float* __restrict__ Wv,
                                                  const float* __restrict__ Wo,
                                                  const float* __restrict__ W1,
                                                  const float* __restrict__ W2,
                                                  const float* __restrict__ Wlm,
                                                  __hip_bfloat16* __restrict__ qkvT,
                                                  __hip_bfloat16* __restrict__ oT,
                                                  __hip_bfloat16* __restrict__ t1,
                                                  __hip_bfloat16* __restrict__ t2,
                                                  __hip_bfloat16* __restrict__ lmT) {
  int gi = blockIdx.x * 256 + threadIdx.x;
  if (gi < P_QKV) {
    int i = gi;
    int c = i % KP;
    int jl = i / KP;
    int j = jl % 640, l = jl / 640;
    float v = 0.f;
    if (j < 624 && c < NE) {
      int sel = j / NE, hd = j - sel * NE;
      int h = hd / HD, d = hd - h * HD;
      const float* W = (sel == 0) ? Wq : (sel == 1) ? Wk : Wv;
      v = W[(((size_t)l * NHD + h) * NE + c) * HD + d];
    }
    qkvT[i] = __float2bfloat16(v);
  } else if (gi < P_QKV + P_O) {
    int i = gi - P_QKV;
    int c = i % KP;
    int jl = i / KP;
    int j = jl % 256, l = jl / 256;
    float v = (j < NE && c < NE) ? Wo[((size_t)l * NE + c) * NE + j] : 0.f;
    oT[i] = __float2bfloat16(v);
  } else if (gi < P_QKV + P_O + P_1) {
    int i = gi - (P_QKV + P_O);
    int c = i % KP;
    int jl = i / KP;
    int j = jl % 896, l = jl / 896;
    float v = (j < 832 && c < NE) ? W1[((size_t)l * NE + c) * 832 + j] : 0.f;
    t1[i] = __float2bfloat16(v);
  } else if (gi < P_QKV + P_O + P_1 + P_2) {
    int i = gi - (P_QKV + P_O + P_1);
    int c = i % 832;
    int jl = i / 832;
    int j = jl % 256, l = jl / 256;
    float v = (j < NE) ? W2[((size_t)l * 832 + c) * NE + j] : 0.f;
    t2[i] = __float2bfloat16(v);
  } else {
    int i = gi - (P_QKV + P_O + P_1 + P_2);
    int c = i % KP;
    int j = i / KP;
    float v = (j < VOCAB && c < NE) ? Wlm[(size_t)c * VOCAB + j] : 0.f;
    lmT[i] = __float2bfloat16(v);
  }
}

// ------- fused embedding + LayerNorm1: x (bf16 ld NE) and hbf = LN(x) ------
__global__ __launch_bounds__(256) void k_embed_ln(const int* __restrict__ idx,
                                                  const float* __restrict__ tok,
                                                  const float* __restrict__ pos,
                                                  const float* __restrict__ g,
                                                  const float* __restrict__ b,
                                                  __hip_bfloat16* __restrict__ x,
                                                  __hip_bfloat16* __restrict__ h) {
  int r = blockIdx.x * 4 + (threadIdx.x >> 6);
  int lane = threadIdx.x & 63;
  const int c0 = lane * 4;
  const int t = r & (TT - 1);
  float v[4] = {0.f, 0.f, 0.f, 0.f};
  float s = 0.f;
  if (lane < 52) {
    float4 tv = *(const float4*)(tok + (size_t)idx[r] * NE + c0);
    float4 pv = *(const float4*)(pos + (size_t)t * NE + c0);
    v[0] = tv.x + pv.x; v[1] = tv.y + pv.y;
    v[2] = tv.z + pv.z; v[3] = tv.w + pv.w;
    s = v[0] + v[1] + v[2] + v[3];
  }
  #pragma unroll
  for (int o = 32; o; o >>= 1) s += __shfl_xor(s, o);
  float mu = s * (1.f / NE);
  float q = 0.f;
  if (lane < 52) {
    #pragma unroll
    for (int i = 0; i < 4; i++) { float d = v[i] - mu; q += d * d; }
  }
  #pragma unroll
  for (int o = 32; o; o >>= 1) q += __shfl_xor(q, o);
  float inv = rsqrtf(q * (1.f / NE) + 1e-5f);
  if (lane < 52) {
    s16x4 xv;
    #pragma unroll
    for (int i = 0; i < 4; i++)
      xv[i] = (short)__bfloat16_as_ushort(__float2bfloat16(v[i]));
    *(s16x4*)(x + (size_t)r * NE + c0) = xv;
  }
  if (lane < 56) {
    s16x4 outv = {};
    if (lane < 52) {
      #pragma unroll
      for (int i = 0; i < 4; i++) {
        float o = (v[i] - mu) * inv * g[c0 + i] + b[c0 + i];
        outv[i] = (short)__bfloat16_as_ushort(__float2bfloat16(o));
      }
    }
    *(s16x4*)(h + (size_t)r * KP + c0) = outv;
  }
}

// ------- bf16 MFMA GEMM: dbuf prefetch + XCD-swizzled grid ----------
// Optional EXPSUM: per-row partial sums of exp(C) into esum[row][2*gridDim.x].
template <bool RELU, bool RESID, bool BIAS, bool OUTBF, bool EXPSUM>
__global__ __launch_bounds__(256) void k_mgemm(const __hip_bfloat16* __restrict__ A, int lda,
                                               const __hip_bfloat16* __restrict__ BT, int ldb,
                                               const float* __restrict__ bias,
                                               const __hip_bfloat16* __restrict__ resid,
                                               void* __restrict__ Cout, int ldc,
                                               int N, int K,
                                               float* __restrict__ esum) {
  __shared__ __hip_bfloat16 As[2][128 * 32];
  __shared__ __hip_bfloat16 Bs[2][128 * 32];
  // XCD-aware remap (T1): give each XCD a contiguous y-range, x-major order,
  // so the gridDim.x blocks sharing an A-panel are consecutive on one XCD.
  const int gx = gridDim.x;
  const int id = blockIdx.x + gx * blockIdx.y;
  const int qq = (gx * gridDim.y) >> 3;          // nwg % 8 == 0 (gridDim.y=512)
  const int wid2 = (id & 7) * qq + (id >> 3);
  const int by = wid2 / gx, bx = wid2 - by * gx;
  const int bm = by * 128, bn = bx * 128;
  const int tid = threadIdx.x;
  const int wave = tid >> 6, lane = tid & 63;
  const int wr = (wave >> 1) * 64, wc = (wave & 1) * 64;
  const int l15 = lane & 15, l4 = lane >> 4;
  const int srow = tid >> 2, sgrp = (tid & 3) * 8;
  const int srow2 = srow + 64;
  f32x4 acc[4][4] = {};
  const int nt = K / 32;
  gload16(A + (size_t)(bm + srow) * lda + sgrp, &As[0][tid * 8]);
  gload16(BT + (size_t)(bn + srow) * ldb + sgrp, &Bs[0][tid * 8]);
  gload16(A + (size_t)(bm + srow2) * lda + sgrp, &As[0][(256 + tid) * 8]);
  gload16(BT + (size_t)(bn + srow2) * ldb + sgrp, &Bs[0][(256 + tid) * 8]);
  int cur = 0;
  for (int t = 0; t < nt; t++) {
    if (t + 1 < nt) {
      int k1 = (t + 1) * 32;
      gload16(A + (size_t)(bm + srow) * lda + k1 + sgrp, &As[cur ^ 1][tid * 8]);
      gload16(BT + (size_t)(bn + srow) * ldb + k1 + sgrp, &Bs[cur ^ 1][tid * 8]);
      gload16(A + (size_t)(bm + srow2) * lda + k1 + sgrp, &As[cur ^ 1][(256 + tid) * 8]);
      gload16(BT + (size_t)(bn + srow2) * ldb + k1 + sgrp, &Bs[cur ^ 1][(256 + tid) * 8]);
      asm volatile("s_waitcnt vmcnt(4)" ::: "memory");
    } else {
      asm volatile("s_waitcnt vmcnt(0)" ::: "memory");
    }
    __builtin_amdgcn_s_barrier();
    bf16x8 af[4], bfr[4];
    #pragma unroll
    for (int m = 0; m < 4; m++)
      af[m] = *(const bf16x8*)&As[cur][(wr + m * 16 + l15) * 32 + l4 * 8];
    #pragma unroll
    for (int n = 0; n < 4; n++)
      bfr[n] = *(const bf16x8*)&Bs[cur][(wc + n * 16 + l15) * 32 + l4 * 8];
    #pragma unroll
    for (int m = 0; m < 4; m++)
      #pragma unroll
      for (int n = 0; n < 4; n++)
        acc[m][n] = __builtin_amdgcn_mfma_f32_16x16x32_bf16(af[m], bfr[n], acc[m][n], 0, 0, 0);
    if (t + 1 < nt) __builtin_amdgcn_s_barrier();
    cur ^= 1;
  }
  float es[4][4];
  if (EXPSUM) {
    #pragma unroll
    for (int m = 0; m < 4; m++)
      #pragma unroll
      for (int j = 0; j < 4; j++) es[m][j] = 0.f;
  }
  #pragma unroll
  for (int m = 0; m < 4; m++) {
    #pragma unroll
    for (int n = 0; n < 4; n++) {
      int col = bn + wc + n * 16 + l15;
      if (col < N) {
        float bv = BIAS ? bias[col] : 0.f;
        #pragma unroll
        for (int j = 0; j < 4; j++) {
          int row = bm + wr + m * 16 + l4 * 4 + j;
          float v = acc[m][n][j] + bv;
          if (RELU) v = fmaxf(v, 0.f);
          size_t off = (size_t)row * ldc + col;
          if (RESID) v += __bfloat162float(resid[off]);
          if (OUTBF) ((__hip_bfloat16*)Cout)[off] = __float2bfloat16(v);
          else       ((float*)Cout)[off] = v;
          if (EXPSUM) es[m][j] += __expf(v);   // |v| small: no-max exp is safe
        }
      }
    }
  }
  if (EXPSUM) {
    #pragma unroll
    for (int m = 0; m < 4; m++)
      #pragma unroll
      for (int j = 0; j < 4; j++) {
        float e = es[m][j];
        #pragma unroll
        for (int off = 1; off < 16; off <<= 1) e += __shfl_xor(e, off);
        if (l15 == 0) {
          int row = bm + wr + m * 16 + l4 * 4 + j;
          esum[(size_t)row * 24 + bx * 2 + (wave & 1)] = e;
        }
      }
  }
}

// ------- GEMM (N=208 in one block-col) + residual + fused LayerNorm --------
__global__ __launch_bounds__(512) void k_mgemm_ln(const __hip_bfloat16* __restrict__ A, int lda,
                                                  const __hip_bfloat16* __restrict__ BT, int ldb,
                                                  const float* __restrict__ bias,
                                                  const __hip_bfloat16* __restrict__ resid,
                                                  const float* __restrict__ g,
                                                  const float* __restrict__ bb,
                                                  __hip_bfloat16* __restrict__ xout,
                                                  __hip_bfloat16* __restrict__ hout,
                                                  int K) {
  __shared__ __hip_bfloat16 As[2][128 * 32];
  __shared__ __hip_bfloat16 Bs[2][256 * 32];
  __shared__ float red[128][4];
  const int bm = blockIdx.x * 128;
  const int tid = threadIdx.x;
  const int wid = tid >> 6, lane = tid & 63;
  const int wr = (wid >> 1) * 32, wc = (wid & 1) * 128;
  const int l15 = lane & 15, l4 = lane >> 4;
  const int srow = tid >> 2, sgrp = (tid & 3) * 8;
  f32x4 acc[2][8] = {};
  const int nt = K / 32;
  gload16(A + (size_t)(bm + srow) * lda + sgrp, &As[0][tid * 8]);
  gload16(BT + (size_t)srow * ldb + sgrp, &Bs[0][tid * 8]);
  gload16(BT + (size_t)(128 + srow) * ldb + sgrp, &Bs[0][(512 + tid) * 8]);
  int cur = 0;
  for (int t = 0; t < nt; t++) {
    if (t + 1 < nt) {
      int k1 = (t + 1) * 32;
      gload16(A + (size_t)(bm + srow) * lda + k1 + sgrp, &As[cur ^ 1][tid * 8]);
      gload16(BT + (size_t)srow * ldb + k1 + sgrp, &Bs[cur ^ 1][tid * 8]);
      gload16(BT + (size_t)(128 + srow) * ldb + k1 + sgrp, &Bs[cur ^ 1][(512 + tid) * 8]);
      asm volatile("s_waitcnt vmcnt(3)" ::: "memory");
    } else {
      asm volatile("s_waitcnt vmcnt(0)" ::: "memory");
    }
    __builtin_amdgcn_s_barrier();
    bf16x8 af[2], bfr[8];
    #pragma unroll
    for (int m = 0; m < 2; m++)
      af[m] = *(const bf16x8*)&As[cur][(wr + m * 16 + l15) * 32 + l4 * 8];
    #pragma unroll
    for (int n = 0; n < 8; n++)
      bfr[n] = *(const bf16x8*)&Bs[cur][(wc + n * 16 + l15) * 32 + l4 * 8];
    #pragma unroll
    for (int m = 0; m < 2; m++)
      #pragma unroll
      for (int n = 0; n < 8; n++)
        acc[m][n] = __builtin_amdgcn_mfma_f32_16x16x32_bf16(af[m], bfr[n], acc[m][n], 0, 0, 0);
    if (t + 1 < nt) __builtin_amdgcn_s_barrier();
    cur ^= 1;
  }
  #pragma unroll
  for (int m = 0; m < 2; m++)
    #pragma unroll
    for (int n = 0; n < 8; n++) {
      int col = wc + n * 16 + l15;
      #pragma unroll
      for (int j = 0; j < 4; j++) {
        int row = bm + wr + m * 16 + l4 * 4 + j;
        float v = 0.f;
        if (col < NE)
          v = acc[m][n][j] + bias[col] + __bfloat162float(resid[(size_t)row * NE + col]);
        acc[m][n][j] = v;
      }
    }
  #pragma unroll
  for (int m = 0; m < 2; m++)
    #pragma unroll
    for (int j = 0; j < 4; j++) {
      float s = 0.f, q = 0.f;
      #pragma unroll
      for (int n = 0; n < 8; n++) { float v = acc[m][n][j]; s += v; q += v * v; }
      #pragma unroll
      for (int off = 1; off < 16; off <<= 1) {
        s += __shfl_xor(s, off);
        q += __shfl_xor(q, off);
      }
      if (l15 == 0) {
        int row = wr + m * 16 + l4 * 4 + j;
        red[row][(wid & 1) * 2 + 0] = s;
        red[row][(wid & 1) * 2 + 1] = q;
      }
    }
  __syncthreads();
  #pragma unroll
  for (int m = 0; m < 2; m++)
    #pragma unroll
    for (int j = 0; j < 4; j++) {
      int lrow = wr + m * 16 + l4 * 4 + j;
      float s = red[lrow][0] + red[lrow][2];
      float q = red[lrow][1] + red[lrow][3];
      float mu = s * (1.f / NE);
      float var = q * (1.f / NE) - mu * mu;
      float inv = rsqrtf(var + 1e-5f);
      size_t row = bm + lrow;
      #pragma unroll
      for (int n = 0; n < 8; n++) {
        int col = wc + n * 16 + l15;
        if (col < NE) {
          float v = acc[m][n][j];
          xout[row * NE + col] = __float2bfloat16(v);
          hout[row * KP + col] = __float2bfloat16((v - mu) * inv * g[col] + bb[col]);
        } else if (col < KP) {
          hout[row * KP + col] = __float2bfloat16(0.f);
        }
      }
    }
}

// -------- MFMA flash attention: balanced waves + defer-rescale + setprio ---
#define KSTRIDE 72
#define VSTRIDE 260
__global__ __launch_bounds__(256) void k_attn_mfma(const __hip_bfloat16* __restrict__ qkv,
                                                   __hip_bfloat16* __restrict__ o) {
  __shared__ __hip_bfloat16 Ks[256 * KSTRIDE];
  __shared__ _Float16      Vt[64 * VSTRIDE];
  const int bh = blockIdx.x, b = bh >> 2, h = bh & 3;
  const __hip_bfloat16* base = qkv + (size_t)b * TT * 624;
  const int tid = threadIdx.x;
  #pragma unroll
  for (int it = 0; it < 16; it++) {
    int u = it * 256 + tid;
    int t = u >> 4, d4 = (u & 15) * 4;
    s16x4 v = {};
    if (d4 < 52) v = *(const s16x4*)(base + t * 624 + 208 + h * HD + d4);
    *(s16x4*)&Ks[t * KSTRIDE + d4] = v;
  }
  #pragma unroll
  for (int it = 0; it < 13; it++) {
    int u = it * 256 + tid;
    int d4g = u >> 8, t = u & 255;
    s16x4 kv = *(const s16x4*)(base + t * 624 + 416 + h * HD + d4g * 4);
    #pragma unroll
    for (int i = 0; i < 4; i++)
      Vt[(d4g * 4 + i) * VSTRIDE + t] = (_Float16)bf2f(kv[i]);
  }
  #pragma unroll
  for (int it = 0; it < 12; it++)
    Vt[(52 + it) * VSTRIDE + tid] = (_Float16)0.f;
  __syncthreads();

  const int w = tid >> 6, lane = tid & 63, l15 = lane & 15, l4 = lane >> 4;
  const float scale = 0.06933752453f;  // NE**-0.5 (reference scales by n_embed)
  const int qts[4] = {w, 7 - w, 8 + w, 15 - w};
  bf16x8 qf[4][2];
  #pragma unroll
  for (int i = 0; i < 4; i++) {
    const __hip_bfloat16* qrow = base + (qts[i] * 16 + l15) * 624 + h * HD;
    #pragma unroll
    for (int ks = 0; ks < 2; ks++) {
      int s = ks * 32 + l4 * 8;
      union { s16x4 h2[2]; bf16x8 v; } u;
      u.h2[0] = (s <= 48) ? *(const s16x4*)(qrow + s) : (s16x4){};
      u.h2[1] = (s <= 44) ? *(const s16x4*)(qrow + s + 4) : (s16x4){};
      qf[i][ks] = u.v;
    }
  }
  f32x4 oacc[4][4] = {};
  float mrun[4] = {-1e30f, -1e30f, -1e30f, -1e30f};
  float lrun[4] = {0.f, 0.f, 0.f, 0.f};
  const int cmax = 15 - w;
  for (int c = 0; c <= cmax; c++) {
    const int kb = c * 16;
    const bf16x8 kf0 = *(const bf16x8*)&Ks[(kb + l15) * KSTRIDE + l4 * 8];
    const bf16x8 kf1 = *(const bf16x8*)&Ks[(kb + l15) * KSTRIDE + 32 + l4 * 8];
    #pragma unroll
    for (int i = 0; i < 4; i++) {
      if (qts[i] < c) continue;
      __builtin_amdgcn_s_setprio(1);
      f32x4 s4 = __builtin_amdgcn_mfma_f32_16x16x32_bf16(kf0, qf[i][0],
                                                         (f32x4){0.f, 0.f, 0.f, 0.f}, 0, 0, 0);
      s4 = __builtin_amdgcn_mfma_f32_16x16x32_bf16(kf1, qf[i][1], s4, 0, 0, 0);
      __builtin_amdgcn_s_setprio(0);
      const int q = qts[i] * 16 + l15;
      float pv[4];
      float pmax = -1e30f;
      #pragma unroll
      for (int j = 0; j < 4; j++) {
        int key = kb + l4 * 4 + j;
        float s = s4[j] * scale;
        pv[j] = (key <= q) ? s : -1e30f;
        pmax = fmaxf(pmax, pv[j]);
      }
      pmax = fmaxf(pmax, __shfl_xor(pmax, 16));
      pmax = fmaxf(pmax, __shfl_xor(pmax, 32));
      // T13 defer-rescale: only rescale when the running max grows by >8.
      if (!__all(pmax - mrun[i] <= 8.f)) {
        const float newm = fmaxf(mrun[i], pmax);
        const float r = __expf(mrun[i] - newm);
        lrun[i] *= r;
        mrun[i] = newm;
        #pragma unroll
        for (int m = 0; m < 4; m++) {
          oacc[m][i][0] *= r; oacc[m][i][1] *= r;
          oacc[m][i][2] *= r; oacc[m][i][3] *= r;
        }
      }
      float psum = 0.f;
      f16x4 pb;
      #pragma unroll
      for (int j = 0; j < 4; j++) {
        float e = __expf(pv[j] - mrun[i]);   // bounded by e^8
        psum += e;
        pb[j] = (_Float16)e;
      }
      psum += __shfl_xor(psum, 16);
      psum += __shfl_xor(psum, 32);
      lrun[i] += psum;
      __builtin_amdgcn_s_setprio(1);
      #pragma unroll
      for (int m = 0; m < 4; m++) {
        f16x4 vf = *(const f16x4*)&Vt[(m * 16 + l15) * VSTRIDE + kb + l4 * 4];
        oacc[m][i] = __builtin_amdgcn_mfma_f32_16x16x16f16(vf, pb, oacc[m][i], 0, 0, 0);
      }
      __builtin_amdgcn_s_setprio(0);
    }
  }
  #pragma unroll
  for (int i = 0; i < 4; i++) {
    const float inv = 1.f / lrun[i];
    __hip_bfloat16* orow = o + (size_t)(b * TT + qts[i] * 16 + l15) * KP + h * HD;
    #pragma unroll
    for (int m = 0; m < 4; m++)
      #pragma unroll
      for (int j = 0; j < 4; j++) {
        int d = m * 16 + l4 * 4 + j;
        if (d < HD) orow[d] = __float2bfloat16(oacc[m][i][j] * inv);
      }
  }
}

// ---------------- loss from fused exp-sums ----------------
__global__ __launch_bounds__(256) void k_loss_fin(const float* __restrict__ esum,
                                                  const float* __restrict__ logits,
                                                  const int* __restrict__ targets,
                                                  float* __restrict__ row_loss) {
  int r = blockIdx.x * 256 + threadIdx.x;
  const float* e = esum + (size_t)r * 24;
  float s = 0.f;
  #pragma unroll
  for (int i = 0; i < 24; i++) s += e[i];
  row_loss[r] = __logf(s) - logits[(size_t)r * VOCAB + targets[r]];
}

__global__ __launch_bounds__(256) void k_loss_reduce(const float* __restrict__ row_loss,
                                                     float* __restrict__ out_loss) {
  __shared__ float sh[256];
  float s = 0.f;
  for (int i = threadIdx.x; i < NTOK; i += 256) s += row_loss[i];
  sh[threadIdx.x] = s;
  __syncthreads();
  for (int k = 128; k; k >>= 1) {
    if (threadIdx.x < k) sh[threadIdx.x] += sh[threadIdx.x + k];
    __syncthreads();
  }
  if (threadIdx.x == 0) *out_loss = sh[0] * (1.f / NTOK);
}

extern "C" void kernel_launch(void* const* d_in, const int* in_sizes, int n_in,
                              void* d_out, int out_size, void* d_ws, size_t ws_size,
                              hipStream_t stream) {
  const int*   idx     = (const int*)d_in[0];
  const int*   targets = (const int*)d_in[1];
  const float* tok     = (const float*)d_in[2];
  const float* pos     = (const float*)d_in[3];
  const float* Wq      = (const float*)d_in[4];
  const float* Wk      = (const float*)d_in[5];
  const float* Wv      = (const float*)d_in[6];
  const float* Wo      = (const float*)d_in[7];
  const float* bo      = (const float*)d_in[8];
  const float* ln1g    = (const float*)d_in[9];
  const float* ln1b    = (const float*)d_in[10];
  const float* W1      = (const float*)d_in[11];
  const float* b1      = (const float*)d_in[12];
  const float* W2      = (const float*)d_in[13];
  const float* b2      = (const float*)d_in[14];
  const float* ln2g    = (const float*)d_in[15];
  const float* ln2b    = (const float*)d_in[16];
  const float* lnfg    = (const float*)d_in[17];
  const float* lnfb    = (const float*)d_in[18];
  const float* Wlm     = (const float*)d_in[19];
  const float* blm     = (const float*)d_in[20];
  float* out = (float*)d_out;

  char* w = (char*)d_ws;
  __hip_bfloat16* x   = (__hip_bfloat16*)w; w += (size_t)NTOK * NE * 2;
  __hip_bfloat16* qkv = (__hip_bfloat16*)w; w += (size_t)NTOK * 624 * 2;
  __hip_bfloat16* hbf = (__hip_bfloat16*)w; w += (size_t)NTOK * KP * 2;
  __hip_bfloat16* act = (__hip_bfloat16*)w; w += (size_t)NTOK * 832 * 2;
  __hip_bfloat16* WqkvT = (__hip_bfloat16*)w; w += (size_t)P_QKV * 2;
  __hip_bfloat16* WoT   = (__hip_bfloat16*)w; w += (size_t)P_O * 2;
  __hip_bfloat16* W1T   = (__hip_bfloat16*)w; w += (size_t)P_1 * 2;
  __hip_bfloat16* W2T   = (__hip_bfloat16*)w; w += (size_t)P_2 * 2;
  __hip_bfloat16* WlmT  = (__hip_bfloat16*)w; w += (size_t)P_LM * 2;
  float* row_loss = (float*)w;              w += (size_t)NTOK * 4;
  float* esum     = (float*)w;              // NTOK*24*4 = 6.3 MB

  k_prep_all<<<(P_QKV + P_O + P_1 + P_2 + P_LM) / 256, 256, 0, stream>>>(
      Wq, Wk, Wv, Wo, W1, W2, Wlm, WqkvT, WoT, W1T, W2T, WlmT);
  k_embed_ln<<<NTOK / 4, 256, 0, stream>>>(idx, tok, pos, ln1g, ln1b, x, hbf);

  for (int l = 0; l < NL; l++) {
    k_mgemm<false, false, false, true, false><<<dim3(5, 512), 256, 0, stream>>>(
        hbf, KP, WqkvT + (size_t)l * 640 * KP, KP, nullptr, nullptr, qkv, 624, 624, KP, nullptr);
    k_attn_mfma<<<BBATCH * NHD, 256, 0, stream>>>(qkv, hbf);
    k_mgemm_ln<<<512, 512, 0, stream>>>(
        hbf, KP, WoT + (size_t)l * 256 * KP, KP, bo + l * NE, x,
        ln2g + l * NE, ln2b + l * NE, x, hbf, KP);
    k_mgemm<true, false, true, true, false><<<dim3(7, 512), 256, 0, stream>>>(
        hbf, KP, W1T + (size_t)l * 896 * KP, KP, b1 + l * 832, nullptr, act, 832, 832, KP, nullptr);
    const float* gn = (l < NL - 1) ? (ln1g + (l + 1) * NE) : lnfg;
    const float* bn = (l < NL - 1) ? (ln1b + (l + 1) * NE) : lnfb;
    k_mgemm_ln<<<512, 512, 0, stream>>>(
        act, 832, W2T + (size_t)l * 256 * 832, 832, b2 + l * NE, x,
        gn, bn, x, hbf, 832);
  }

  k_mgemm<false, false, true, false, true><<<dim3(12, 512), 256, 0, stream>>>(
      hbf, KP, WlmT, KP, blm, nullptr, out, VOCAB, VOCAB, KP, esum);

  k_loss_fin<<<NTOK / 256, 256, 0, stream>>>(esum, out, targets, row_loss);
  k_loss_reduce<<<1, 256, 0, stream>>>(row_loss, out + ((size_t)out_size - 1));
}

// Round 10
// 2442.253 us; speedup vs baseline: 5.5751x; 1.0322x over previous
//
#include <hip/hip_runtime.h>
#include <hip/hip_bf16.h>
#include <math.h>

#define VOCAB 1500
#define NE    208
#define TT    256
#define NHD   4
#define HD    52
#define NL    8
#define BBATCH 256
#define NTOK  (BBATCH * TT)   // 65536
#define KP    224             // NE padded to multiple of 32

typedef __attribute__((ext_vector_type(8))) short bf16x8;
typedef __attribute__((ext_vector_type(4))) short s16x4;
typedef __attribute__((ext_vector_type(4))) float f32x4;
typedef __attribute__((ext_vector_type(4))) _Float16 f16x4;

__device__ __forceinline__ void gload16(const void* g, void* l) {
  __builtin_amdgcn_global_load_lds(
      (const __attribute__((address_space(1))) unsigned int*)g,
      (__attribute__((address_space(3))) unsigned int*)l, 16, 0, 0);
}
__device__ __forceinline__ float bf2f(short u) {
  union { unsigned int i; float f; } cv;
  cv.i = ((unsigned int)(unsigned short)u) << 16;
  return cv.f;
}

// ---------- merged weight prep: all transposed/padded bf16 copies ----------
#define P_QKV 1146880            // NL*640*KP
#define P_O   458752             // NL*256*KP
#define P_1   1605632            // NL*896*KP
#define P_2   1703936            // NL*256*832
#define P_LM  344064             // 1536*KP
__global__ __launch_bounds__(256) void k_prep_all(const float* __restrict__ Wq,
                                                  const float* __restrict__ Wk,
                                                  const float* __restrict__ Wv,
                                                  const float* __restrict__ Wo,
                                                  const float* __restrict__ W1,
                                                  const float* __restrict__ W2,
                                                  const float* __restrict__ Wlm,
                                                  __hip_bfloat16* __restrict__ qkvT,
                                                  __hip_bfloat16* __restrict__ oT,
                                                  __hip_bfloat16* __restrict__ t1,
                                                  __hip_bfloat16* __restrict__ t2,
                                                  __hip_bfloat16* __restrict__ lmT) {
  int gi = blockIdx.x * 256 + threadIdx.x;
  if (gi < P_QKV) {
    int i = gi;
    int c = i % KP;
    int jl = i / KP;
    int j = jl % 640, l = jl / 640;
    float v = 0.f;
    if (j < 624 && c < NE) {
      int sel = j / NE, hd = j - sel * NE;
      int h = hd / HD, d = hd - h * HD;
      const float* W = (sel == 0) ? Wq : (sel == 1) ? Wk : Wv;
      v = W[(((size_t)l * NHD + h) * NE + c) * HD + d];
    }
    qkvT[i] = __float2bfloat16(v);
  } else if (gi < P_QKV + P_O) {
    int i = gi - P_QKV;
    int c = i % KP;
    int jl = i / KP;
    int j = jl % 256, l = jl / 256;
    float v = (j < NE && c < NE) ? Wo[((size_t)l * NE + c) * NE + j] : 0.f;
    oT[i] = __float2bfloat16(v);
  } else if (gi < P_QKV + P_O + P_1) {
    int i = gi - (P_QKV + P_O);
    int c = i % KP;
    int jl = i / KP;
    int j = jl % 896, l = jl / 896;
    float v = (j < 832 && c < NE) ? W1[((size_t)l * NE + c) * 832 + j] : 0.f;
    t1[i] = __float2bfloat16(v);
  } else if (gi < P_QKV + P_O + P_1 + P_2) {
    int i = gi - (P_QKV + P_O + P_1);
    int c = i % 832;
    int jl = i / 832;
    int j = jl % 256, l = jl / 256;
    float v = (j < NE) ? W2[((size_t)l * 832 + c) * NE + j] : 0.f;
    t2[i] = __float2bfloat16(v);
  } else {
    int i = gi - (P_QKV + P_O + P_1 + P_2);
    int c = i % KP;
    int j = i / KP;
    float v = (j < VOCAB && c < NE) ? Wlm[(size_t)c * VOCAB + j] : 0.f;
    lmT[i] = __float2bfloat16(v);
  }
}

// ------- fused embedding + LayerNorm1: x (bf16 ld NE) and hbf = LN(x) ------
__global__ __launch_bounds__(256) void k_embed_ln(const int* __restrict__ idx,
                                                  const float* __restrict__ tok,
                                                  const float* __restrict__ pos,
                                                  const float* __restrict__ g,
                                                  const float* __restrict__ b,
                                                  __hip_bfloat16* __restrict__ x,
                                                  __hip_bfloat16* __restrict__ h) {
  int r = blockIdx.x * 4 + (threadIdx.x >> 6);
  int lane = threadIdx.x & 63;
  const int c0 = lane * 4;
  const int t = r & (TT - 1);
  float v[4] = {0.f, 0.f, 0.f, 0.f};
  float s = 0.f;
  if (lane < 52) {
    float4 tv = *(const float4*)(tok + (size_t)idx[r] * NE + c0);
    float4 pv = *(const float4*)(pos + (size_t)t * NE + c0);
    v[0] = tv.x + pv.x; v[1] = tv.y + pv.y;
    v[2] = tv.z + pv.z; v[3] = tv.w + pv.w;
    s = v[0] + v[1] + v[2] + v[3];
  }
  #pragma unroll
  for (int o = 32; o; o >>= 1) s += __shfl_xor(s, o);
  float mu = s * (1.f / NE);
  float q = 0.f;
  if (lane < 52) {
    #pragma unroll
    for (int i = 0; i < 4; i++) { float d = v[i] - mu; q += d * d; }
  }
  #pragma unroll
  for (int o = 32; o; o >>= 1) q += __shfl_xor(q, o);
  float inv = rsqrtf(q * (1.f / NE) + 1e-5f);
  if (lane < 52) {
    s16x4 xv;
    #pragma unroll
    for (int i = 0; i < 4; i++)
      xv[i] = (short)__bfloat16_as_ushort(__float2bfloat16(v[i]));
    *(s16x4*)(x + (size_t)r * NE + c0) = xv;
  }
  if (lane < 56) {
    s16x4 outv = {};
    if (lane < 52) {
      #pragma unroll
      for (int i = 0; i < 4; i++) {
        float o = (v[i] - mu) * inv * g[c0 + i] + b[c0 + i];
        outv[i] = (short)__bfloat16_as_ushort(__float2bfloat16(o));
      }
    }
    *(s16x4*)(h + (size_t)r * KP + c0) = outv;
  }
}

// ------- bf16 MFMA GEMM: dbuf prefetch + XCD-swizzled grid ----------
// Optional EXPSUM: per-row partial sums of exp(C) into esum[row][2*gridDim.x].
template <bool RELU, bool RESID, bool BIAS, bool OUTBF, bool EXPSUM>
__global__ __launch_bounds__(256) void k_mgemm(const __hip_bfloat16* __restrict__ A, int lda,
                                               const __hip_bfloat16* __restrict__ BT, int ldb,
                                               const float* __restrict__ bias,
                                               const __hip_bfloat16* __restrict__ resid,
                                               void* __restrict__ Cout, int ldc,
                                               int N, int K,
                                               float* __restrict__ esum) {
  __shared__ __hip_bfloat16 As[2][128 * 32];
  __shared__ __hip_bfloat16 Bs[2][128 * 32];
  // XCD-aware remap (T1): give each XCD a contiguous y-range, x-major order,
  // so the gridDim.x blocks sharing an A-panel are consecutive on one XCD.
  const int gx = gridDim.x;
  const int id = blockIdx.x + gx * blockIdx.y;
  const int qq = (gx * gridDim.y) >> 3;          // nwg % 8 == 0 (gridDim.y=512)
  const int wid2 = (id & 7) * qq + (id >> 3);
  const int by = wid2 / gx, bx = wid2 - by * gx;
  const int bm = by * 128, bn = bx * 128;
  const int tid = threadIdx.x;
  const int wave = tid >> 6, lane = tid & 63;
  const int wr = (wave >> 1) * 64, wc = (wave & 1) * 64;
  const int l15 = lane & 15, l4 = lane >> 4;
  const int srow = tid >> 2, sgrp = (tid & 3) * 8;
  const int srow2 = srow + 64;
  f32x4 acc[4][4] = {};
  const int nt = K / 32;
  gload16(A + (size_t)(bm + srow) * lda + sgrp, &As[0][tid * 8]);
  gload16(BT + (size_t)(bn + srow) * ldb + sgrp, &Bs[0][tid * 8]);
  gload16(A + (size_t)(bm + srow2) * lda + sgrp, &As[0][(256 + tid) * 8]);
  gload16(BT + (size_t)(bn + srow2) * ldb + sgrp, &Bs[0][(256 + tid) * 8]);
  int cur = 0;
  for (int t = 0; t < nt; t++) {
    if (t + 1 < nt) {
      int k1 = (t + 1) * 32;
      gload16(A + (size_t)(bm + srow) * lda + k1 + sgrp, &As[cur ^ 1][tid * 8]);
      gload16(BT + (size_t)(bn + srow) * ldb + k1 + sgrp, &Bs[cur ^ 1][tid * 8]);
      gload16(A + (size_t)(bm + srow2) * lda + k1 + sgrp, &As[cur ^ 1][(256 + tid) * 8]);
      gload16(BT + (size_t)(bn + srow2) * ldb + k1 + sgrp, &Bs[cur ^ 1][(256 + tid) * 8]);
      asm volatile("s_waitcnt vmcnt(4)" ::: "memory");
    } else {
      asm volatile("s_waitcnt vmcnt(0)" ::: "memory");
    }
    __builtin_amdgcn_s_barrier();
    bf16x8 af[4], bfr[4];
    #pragma unroll
    for (int m = 0; m < 4; m++)
      af[m] = *(const bf16x8*)&As[cur][(wr + m * 16 + l15) * 32 + l4 * 8];
    #pragma unroll
    for (int n = 0; n < 4; n++)
      bfr[n] = *(const bf16x8*)&Bs[cur][(wc + n * 16 + l15) * 32 + l4 * 8];
    #pragma unroll
    for (int m = 0; m < 4; m++)
      #pragma unroll
      for (int n = 0; n < 4; n++)
        acc[m][n] = __builtin_amdgcn_mfma_f32_16x16x32_bf16(af[m], bfr[n], acc[m][n], 0, 0, 0);
    if (t + 1 < nt) __builtin_amdgcn_s_barrier();
    cur ^= 1;
  }
  float es[4][4];
  if (EXPSUM) {
    #pragma unroll
    for (int m = 0; m < 4; m++)
      #pragma unroll
      for (int j = 0; j < 4; j++) es[m][j] = 0.f;
  }
  #pragma unroll
  for (int m = 0; m < 4; m++) {
    #pragma unroll
    for (int n = 0; n < 4; n++) {
      int col = bn + wc + n * 16 + l15;
      if (col < N) {
        float bv = BIAS ? bias[col] : 0.f;
        #pragma unroll
        for (int j = 0; j < 4; j++) {
          int row = bm + wr + m * 16 + l4 * 4 + j;
          float v = acc[m][n][j] + bv;
          if (RELU) v = fmaxf(v, 0.f);
          size_t off = (size_t)row * ldc + col;
          if (RESID) v += __bfloat162float(resid[off]);
          if (OUTBF) ((__hip_bfloat16*)Cout)[off] = __float2bfloat16(v);
          else       ((float*)Cout)[off] = v;
          if (EXPSUM) es[m][j] += __expf(v);   // |v| small: no-max exp is safe
        }
      }
    }
  }
  if (EXPSUM) {
    #pragma unroll
    for (int m = 0; m < 4; m++)
      #pragma unroll
      for (int j = 0; j < 4; j++) {
        float e = es[m][j];
        #pragma unroll
        for (int off = 1; off < 16; off <<= 1) e += __shfl_xor(e, off);
        if (l15 == 0) {
          int row = bm + wr + m * 16 + l4 * 4 + j;
          esum[(size_t)row * 24 + bx * 2 + (wave & 1)] = e;
        }
      }
  }
}

// ------- GEMM (N=208 in one block-col) + residual + fused LayerNorm --------
__global__ __launch_bounds__(512) void k_mgemm_ln(const __hip_bfloat16* __restrict__ A, int lda,
                                                  const __hip_bfloat16* __restrict__ BT, int ldb,
                                                  const float* __restrict__ bias,
                                                  const __hip_bfloat16* __restrict__ resid,
                                                  const float* __restrict__ g,
                                                  const float* __restrict__ bb,
                                                  __hip_bfloat16* __restrict__ xout,
                                                  __hip_bfloat16* __restrict__ hout,
                                                  int K) {
  __shared__ __hip_bfloat16 As[2][128 * 32];
  __shared__ __hip_bfloat16 Bs[2][256 * 32];
  __shared__ float red[128][4];
  const int bm = blockIdx.x * 128;
  const int tid = threadIdx.x;
  const int wid = tid >> 6, lane = tid & 63;
  const int wr = (wid >> 1) * 32, wc = (wid & 1) * 128;
  const int l15 = lane & 15, l4 = lane >> 4;
  const int srow = tid >> 2, sgrp = (tid & 3) * 8;
  f32x4 acc[2][8] = {};
  const int nt = K / 32;
  gload16(A + (size_t)(bm + srow) * lda + sgrp, &As[0][tid * 8]);
  gload16(BT + (size_t)srow * ldb + sgrp, &Bs[0][tid * 8]);
  gload16(BT + (size_t)(128 + srow) * ldb + sgrp, &Bs[0][(512 + tid) * 8]);
  int cur = 0;
  for (int t = 0; t < nt; t++) {
    if (t + 1 < nt) {
      int k1 = (t + 1) * 32;
      gload16(A + (size_t)(bm + srow) * lda + k1 + sgrp, &As[cur ^ 1][tid * 8]);
      gload16(BT + (size_t)srow * ldb + k1 + sgrp, &Bs[cur ^ 1][tid * 8]);
      gload16(BT + (size_t)(128 + srow) * ldb + k1 + sgrp, &Bs[cur ^ 1][(512 + tid) * 8]);
      asm volatile("s_waitcnt vmcnt(3)" ::: "memory");
    } else {
      asm volatile("s_waitcnt vmcnt(0)" ::: "memory");
    }
    __builtin_amdgcn_s_barrier();
    bf16x8 af[2], bfr[8];
    #pragma unroll
    for (int m = 0; m < 2; m++)
      af[m] = *(const bf16x8*)&As[cur][(wr + m * 16 + l15) * 32 + l4 * 8];
    #pragma unroll
    for (int n = 0; n < 8; n++)
      bfr[n] = *(const bf16x8*)&Bs[cur][(wc + n * 16 + l15) * 32 + l4 * 8];
    #pragma unroll
    for (int m = 0; m < 2; m++)
      #pragma unroll
      for (int n = 0; n < 8; n++)
        acc[m][n] = __builtin_amdgcn_mfma_f32_16x16x32_bf16(af[m], bfr[n], acc[m][n], 0, 0, 0);
    if (t + 1 < nt) __builtin_amdgcn_s_barrier();
    cur ^= 1;
  }
  #pragma unroll
  for (int m = 0; m < 2; m++)
    #pragma unroll
    for (int n = 0; n < 8; n++) {
      int col = wc + n * 16 + l15;
      #pragma unroll
      for (int j = 0; j < 4; j++) {
        int row = bm + wr + m * 16 + l4 * 4 + j;
        float v = 0.f;
        if (col < NE)
          v = acc[m][n][j] + bias[col] + __bfloat162float(resid[(size_t)row * NE + col]);
        acc[m][n][j] = v;
      }
    }
  #pragma unroll
  for (int m = 0; m < 2; m++)
    #pragma unroll
    for (int j = 0; j < 4; j++) {
      float s = 0.f, q = 0.f;
      #pragma unroll
      for (int n = 0; n < 8; n++) { float v = acc[m][n][j]; s += v; q += v * v; }
      #pragma unroll
      for (int off = 1; off < 16; off <<= 1) {
        s += __shfl_xor(s, off);
        q += __shfl_xor(q, off);
      }
      if (l15 == 0) {
        int row = wr + m * 16 + l4 * 4 + j;
        red[row][(wid & 1) * 2 + 0] = s;
        red[row][(wid & 1) * 2 + 1] = q;
      }
    }
  __syncthreads();
  #pragma unroll
  for (int m = 0; m < 2; m++)
    #pragma unroll
    for (int j = 0; j < 4; j++) {
      int lrow = wr + m * 16 + l4 * 4 + j;
      float s = red[lrow][0] + red[lrow][2];
      float q = red[lrow][1] + red[lrow][3];
      float mu = s * (1.f / NE);
      float var = q * (1.f / NE) - mu * mu;
      float inv = rsqrtf(var + 1e-5f);
      size_t row = bm + lrow;
      #pragma unroll
      for (int n = 0; n < 8; n++) {
        int col = wc + n * 16 + l15;
        if (col < NE) {
          float v = acc[m][n][j];
          xout[row * NE + col] = __float2bfloat16(v);
          hout[row * KP + col] = __float2bfloat16((v - mu) * inv * g[col] + bb[col]);
        } else if (col < KP) {
          hout[row * KP + col] = __float2bfloat16(0.f);
        }
      }
    }
}

// -------- MFMA flash attention: balanced waves, coalesced staging ----------
// Ks rows fully written (zeros at d>=52): uninitialized LDS may hold NaN/Inf
// patterns, and NaN*0 = NaN — "multiplied by zero" is NOT dead (R9 lesson).
#define KSTRIDE 64
#define VSTRIDE 260
__global__ __launch_bounds__(256) void k_attn_mfma(const __hip_bfloat16* __restrict__ qkv,
                                                   __hip_bfloat16* __restrict__ o) {
  __shared__ __hip_bfloat16 Ks[256 * KSTRIDE];
  __shared__ _Float16      Vt[64 * VSTRIDE];
  // XCD swizzle: 4 heads of one b land on the same XCD (L2 K/V co-residency).
  const int bh0 = blockIdx.x;
  const int bh = (bh0 & 7) * 128 + (bh0 >> 3);
  const int b = bh >> 2, h = bh & 3;
  const __hip_bfloat16* base = qkv + (size_t)b * TT * 624;
  const int tid = threadIdx.x;
  // K staging: 16 lanes per row, coalesced; EVERY element written (zeros pad).
  #pragma unroll
  for (int it = 0; it < 16; it++) {
    int u = it * 256 + tid;
    int t = u >> 4, d4 = (u & 15) * 4;
    s16x4 v = {};
    if (d4 < 52) v = *(const s16x4*)(base + t * 624 + 208 + h * HD + d4);
    *(s16x4*)&Ks[t * KSTRIDE + d4] = v;
  }
  // V staging: 13 lanes per row read s16x4 (coalesced within row), then
  // scatter f16 into the transposed [d][t] layout (2 lanes/bank: free).
  #pragma unroll
  for (int it = 0; it < 13; it++) {
    int slot = it * 256 + tid;           // 3328 slots = 256 rows x 13
    int t = slot / 13, dl = (slot - t * 13) * 4;
    s16x4 kv = *(const s16x4*)(base + t * 624 + 416 + h * HD + dl);
    #pragma unroll
    for (int i = 0; i < 4; i++)
      Vt[(dl + i) * VSTRIDE + t] = (_Float16)bf2f(kv[i]);
  }
  #pragma unroll
  for (int it = 0; it < 12; it++)        // zero rows 52..63 (same NaN hazard)
    Vt[(52 + it) * VSTRIDE + tid] = (_Float16)0.f;
  __syncthreads();

  const int w = tid >> 6, lane = tid & 63, l15 = lane & 15, l4 = lane >> 4;
  const float scale = 0.06933752453f;  // NE**-0.5 (reference scales by n_embed)
  const int qts[4] = {w, 7 - w, 8 + w, 15 - w};
  bf16x8 qf[4][2];
  #pragma unroll
  for (int i = 0; i < 4; i++) {
    const __hip_bfloat16* qrow = base + (qts[i] * 16 + l15) * 624 + h * HD;
    #pragma unroll
    for (int ks = 0; ks < 2; ks++) {
      int s = ks * 32 + l4 * 8;
      union { s16x4 h2[2]; bf16x8 v; } u;
      u.h2[0] = (s <= 48) ? *(const s16x4*)(qrow + s) : (s16x4){};
      u.h2[1] = (s <= 44) ? *(const s16x4*)(qrow + s + 4) : (s16x4){};
      qf[i][ks] = u.v;
    }
  }
  f32x4 oacc[4][4] = {};
  float mrun[4] = {-1e30f, -1e30f, -1e30f, -1e30f};
  float lrun[4] = {0.f, 0.f, 0.f, 0.f};
  const int cmax = 15 - w;
  for (int c = 0; c <= cmax; c++) {
    const int kb = c * 16;
    const bf16x8 kf0 = *(const bf16x8*)&Ks[(kb + l15) * KSTRIDE + l4 * 8];
    const bf16x8 kf1 = *(const bf16x8*)&Ks[(kb + l15) * KSTRIDE + 32 + l4 * 8];
    #pragma unroll
    for (int i = 0; i < 4; i++) {
      if (qts[i] < c) continue;
      __builtin_amdgcn_s_setprio(1);
      f32x4 s4 = __builtin_amdgcn_mfma_f32_16x16x32_bf16(kf0, qf[i][0],
                                                         (f32x4){0.f, 0.f, 0.f, 0.f}, 0, 0, 0);
      s4 = __builtin_amdgcn_mfma_f32_16x16x32_bf16(kf1, qf[i][1], s4, 0, 0, 0);
      __builtin_amdgcn_s_setprio(0);
      const int q = qts[i] * 16 + l15;
      float pv[4];
      float pmax = -1e30f;
      #pragma unroll
      for (int j = 0; j < 4; j++) {
        int key = kb + l4 * 4 + j;
        float s = s4[j] * scale;
        pv[j] = (key <= q) ? s : -1e30f;
        pmax = fmaxf(pmax, pv[j]);
      }
      pmax = fmaxf(pmax, __shfl_xor(pmax, 16));
      pmax = fmaxf(pmax, __shfl_xor(pmax, 32));
      // T13 defer-rescale: only rescale when the running max grows by >8.
      if (!__all(pmax - mrun[i] <= 8.f)) {
        const float newm = fmaxf(mrun[i], pmax);
        const float r = __expf(mrun[i] - newm);
        lrun[i] *= r;
        mrun[i] = newm;
        #pragma unroll
        for (int m = 0; m < 4; m++) {
          oacc[m][i][0] *= r; oacc[m][i][1] *= r;
          oacc[m][i][2] *= r; oacc[m][i][3] *= r;
        }
      }
      float psum = 0.f;
      f16x4 pb;
      #pragma unroll
      for (int j = 0; j < 4; j++) {
        float e = __expf(pv[j] - mrun[i]);   // bounded by e^8
        psum += e;
        pb[j] = (_Float16)e;
      }
      psum += __shfl_xor(psum, 16);
      psum += __shfl_xor(psum, 32);
      lrun[i] += psum;
      __builtin_amdgcn_s_setprio(1);
      #pragma unroll
      for (int m = 0; m < 4; m++) {
        f16x4 vf = *(const f16x4*)&Vt[(m * 16 + l15) * VSTRIDE + kb + l4 * 4];
        oacc[m][i] = __builtin_amdgcn_mfma_f32_16x16x16f16(vf, pb, oacc[m][i], 0, 0, 0);
      }
      __builtin_amdgcn_s_setprio(0);
    }
  }
  #pragma unroll
  for (int i = 0; i < 4; i++) {
    const float inv = 1.f / lrun[i];
    __hip_bfloat16* orow = o + (size_t)(b * TT + qts[i] * 16 + l15) * KP + h * HD;
    #pragma unroll
    for (int m = 0; m < 4; m++)
      #pragma unroll
      for (int j = 0; j < 4; j++) {
        int d = m * 16 + l4 * 4 + j;
        if (d < HD) orow[d] = __float2bfloat16(oacc[m][i][j] * inv);
      }
  }
}

// ---------------- loss from fused exp-sums ----------------
__global__ __launch_bounds__(256) void k_loss_fin(const float* __restrict__ esum,
                                                  const float* __restrict__ logits,
                                                  const int* __restrict__ targets,
                                                  float* __restrict__ row_loss) {
  int r = blockIdx.x * 256 + threadIdx.x;
  const float* e = esum + (size_t)r * 24;
  float s = 0.f;
  #pragma unroll
  for (int i = 0; i < 24; i++) s += e[i];
  row_loss[r] = __logf(s) - logits[(size_t)r * VOCAB + targets[r]];
}

__global__ __launch_bounds__(256) void k_loss_reduce(const float* __restrict__ row_loss,
                                                     float* __restrict__ out_loss) {
  __shared__ float sh[256];
  float s = 0.f;
  for (int i = threadIdx.x; i < NTOK; i += 256) s += row_loss[i];
  sh[threadIdx.x] = s;
  __syncthreads();
  for (int k = 128; k; k >>= 1) {
    if (threadIdx.x < k) sh[threadIdx.x] += sh[threadIdx.x + k];
    __syncthreads();
  }
  if (threadIdx.x == 0) *out_loss = sh[0] * (1.f / NTOK);
}

extern "C" void kernel_launch(void* const* d_in, const int* in_sizes, int n_in,
                              void* d_out, int out_size, void* d_ws, size_t ws_size,
                              hipStream_t stream) {
  const int*   idx     = (const int*)d_in[0];
  const int*   targets = (const int*)d_in[1];
  const float* tok     = (const float*)d_in[2];
  const float* pos     = (const float*)d_in[3];
  const float* Wq      = (const float*)d_in[4];
  const float* Wk      = (const float*)d_in[5];
  const float* Wv      = (const float*)d_in[6];
  const float* Wo      = (const float*)d_in[7];
  const float* bo      = (const float*)d_in[8];
  const float* ln1g    = (const float*)d_in[9];
  const float* ln1b    = (const float*)d_in[10];
  const float* W1      = (const float*)d_in[11];
  const float* b1      = (const float*)d_in[12];
  const float* W2      = (const float*)d_in[13];
  const float* b2      = (const float*)d_in[14];
  const float* ln2g    = (const float*)d_in[15];
  const float* ln2b    = (const float*)d_in[16];
  const float* lnfg    = (const float*)d_in[17];
  const float* lnfb    = (const float*)d_in[18];
  const float* Wlm     = (const float*)d_in[19];
  const float* blm     = (const float*)d_in[20];
  float* out = (float*)d_out;

  char* w = (char*)d_ws;
  __hip_bfloat16* x   = (__hip_bfloat16*)w; w += (size_t)NTOK * NE * 2;
  __hip_bfloat16* qkv = (__hip_bfloat16*)w; w += (size_t)NTOK * 624 * 2;
  __hip_bfloat16* hbf = (__hip_bfloat16*)w; w += (size_t)NTOK * KP * 2;
  __hip_bfloat16* act = (__hip_bfloat16*)w; w += (size_t)NTOK * 832 * 2;
  __hip_bfloat16* WqkvT = (__hip_bfloat16*)w; w += (size_t)P_QKV * 2;
  __hip_bfloat16* WoT   = (__hip_bfloat16*)w; w += (size_t)P_O * 2;
  __hip_bfloat16* W1T   = (__hip_bfloat16*)w; w += (size_t)P_1 * 2;
  __hip_bfloat16* W2T   = (__hip_bfloat16*)w; w += (size_t)P_2 * 2;
  __hip_bfloat16* WlmT  = (__hip_bfloat16*)w; w += (size_t)P_LM * 2;
  float* row_loss = (float*)w;              w += (size_t)NTOK * 4;
  float* esum     = (float*)w;              // NTOK*24*4 = 6.3 MB

  k_prep_all<<<(P_QKV + P_O + P_1 + P_2 + P_LM) / 256, 256, 0, stream>>>(
      Wq, Wk, Wv, Wo, W1, W2, Wlm, WqkvT, WoT, W1T, W2T, WlmT);
  k_embed_ln<<<NTOK / 4, 256, 0, stream>>>(idx, tok, pos, ln1g, ln1b, x, hbf);

  for (int l = 0; l < NL; l++) {
    k_mgemm<false, false, false, true, false><<<dim3(5, 512), 256, 0, stream>>>(
        hbf, KP, WqkvT + (size_t)l * 640 * KP, KP, nullptr, nullptr, qkv, 624, 624, KP, nullptr);
    k_attn_mfma<<<BBATCH * NHD, 256, 0, stream>>>(qkv, hbf);
    k_mgemm_ln<<<512, 512, 0, stream>>>(
        hbf, KP, WoT + (size_t)l * 256 * KP, KP, bo + l * NE, x,
        ln2g + l * NE, ln2b + l * NE, x, hbf, KP);
    k_mgemm<true, false, true, true, false><<<dim3(7, 512), 256, 0, stream>>>(
        hbf, KP, W1T + (size_t)l * 896 * KP, KP, b1 + l * 832, nullptr, act, 832, 832, KP, nullptr);
    const float* gn = (l < NL - 1) ? (ln1g + (l + 1) * NE) : lnfg;
    const float* bn = (l < NL - 1) ? (ln1b + (l + 1) * NE) : lnfb;
    k_mgemm_ln<<<512, 512, 0, stream>>>(
        act, 832, W2T + (size_t)l * 256 * 832, 832, b2 + l * NE, x,
        gn, bn, x, hbf, 832);
  }

  k_mgemm<false, false, true, false, true><<<dim3(12, 512), 256, 0, stream>>>(
      hbf, KP, WlmT, KP, blm, nullptr, out, VOCAB, VOCAB, KP, esum);

  k_loss_fin<<<NTOK / 256, 256, 0, stream>>>(esum, out, targets, row_loss);
  k_loss_reduce<<<1, 256, 0, stream>>>(row_loss, out + ((size_t)out_size - 1));
}